// Round 8
// baseline (1641.607 us; speedup 1.0000x reference)
//
#include <hip/hip_runtime.h>
#include <hip/hip_bf16.h>
#include <cstddef>

#define N_  20000
#define E_  320000
#define FI_ 16
#define H_  100
#define T_  5
#define FO_ 20
#define B_  50
#define EPSF 1e-5f
#define PR_  200    // k_pool rows per block

typedef __attribute__((ext_vector_type(8))) short short8;
typedef __attribute__((ext_vector_type(4))) float f32x4;

static __device__ __forceinline__ unsigned short f2bf(float x) {
  unsigned int u = __builtin_bit_cast(unsigned int, x);
  unsigned int r = (u + 0x7FFFu + ((u >> 16) & 1u)) >> 16;   // RNE
  return (unsigned short)r;
}
static __device__ __forceinline__ unsigned int packbf(float a, float b) {
  return (unsigned int)f2bf(a) | ((unsigned int)f2bf(b) << 16);
}
static __device__ __forceinline__ float bf2f_lo(unsigned int u) {
  return __builtin_bit_cast(float, (u & 0xFFFFu) << 16);
}
static __device__ __forceinline__ float bf2f_hi(unsigned int u) {
  return __builtin_bit_cast(float, u & 0xFFFF0000u);
}

// ---------------- graph prep ----------------
__global__ void k_count(const int* __restrict__ dst, int* __restrict__ cnt) {
  int e = blockIdx.x * blockDim.x + threadIdx.x;
  if (e < E_) atomicAdd(&cnt[dst[e]], 1);
}

__global__ __launch_bounds__(1024) void k_scan(const int* __restrict__ cnt, int* __restrict__ rowptr) {
  __shared__ int ls[1024];
  const int tid = threadIdx.x;
  int carry = 0;
  for (int start = 0; start < N_; start += 1024) {
    int i = start + tid;
    int v = (i < N_) ? cnt[i] : 0;
    ls[tid] = v;
    __syncthreads();
    for (int off = 1; off < 1024; off <<= 1) {
      int t = (tid >= off) ? ls[tid - off] : 0;
      __syncthreads();
      ls[tid] += t;
      __syncthreads();
    }
    if (i < N_) rowptr[i] = carry + ls[tid] - v;   // exclusive scan
    carry += ls[1023];
    __syncthreads();
  }
  if (tid == 0) rowptr[N_] = carry;
}

__global__ void k_fill(const int* __restrict__ dst, const int* __restrict__ rowptr,
                       int* __restrict__ cursor, int* __restrict__ cols) {
  int e = blockIdx.x * blockDim.x + threadIdx.x;
  if (e < E_) {
    int v = dst[e];
    int p = atomicAdd(&cursor[v], 1);
    cols[rowptr[v] + p] = e;
  }
}

__global__ void k_sumlog(const int* __restrict__ cnt, float* __restrict__ sumlog) {
  int i = blockIdx.x * blockDim.x + threadIdx.x;
  float v = (i < N_) ? logf((float)cnt[i] + 1.0f) : 0.0f;
  #pragma unroll
  for (int off = 32; off > 0; off >>= 1) v += __shfl_down(v, off);
  __shared__ float red[4];
  if ((threadIdx.x & 63) == 0) red[threadIdx.x >> 6] = v;
  __syncthreads();
  if (threadIdx.x == 0) atomicAdd(sumlog, red[0] + red[1] + red[2] + red[3]);
}

__global__ void k_scal(const int* __restrict__ cnt, const float* __restrict__ sumlog,
                       float* __restrict__ scal) {
  int i = blockIdx.x * blockDim.x + threadIdx.x;
  if (i >= N_) return;
  float c  = (float)cnt[i];
  float d  = fmaxf(c, 1.0f);
  float ld = logf(d + 1.0f);
  float avg_log = sumlog[0] * (1.0f / (float)N_);
  float avg_lin = (float)E_ / (float)N_;
  scal[i*4+0] = 1.0f;
  scal[i*4+1] = ld / avg_log;
  scal[i*4+2] = avg_log / ld;
  scal[i*4+3] = d / avg_lin;
}

// ---------------- per-layer prep ----------------
__global__ void k_edgevec(const float* __restrict__ pw, const float* __restrict__ pb,
                          const float* __restrict__ ew, const float* __restrict__ eb,
                          float* __restrict__ vec_e, float* __restrict__ cst_e, int f, int C) {
  int c = blockIdx.x * blockDim.x + threadIdx.x;
  if (c >= C) return;
  int t = c / f, g = c - t*f;
  const float* wp = pw + (size_t)t*3*f*f + (size_t)2*f*f + g;
  float v = 0.f, s = 0.f;
  for (int ff = 0; ff < f; ++ff) { float wv = wp[(size_t)ff*f]; v += ew[ff]*wv; s += eb[ff]*wv; }
  vec_e[c] = v;
  cst_e[c] = s + pb[c];
}

__global__ void k_pack_pre(const float* __restrict__ pw, float* __restrict__ Bp, int f, int C) {
  int idx = blockIdx.x * blockDim.x + threadIdx.x;
  int tot = f * 2 * C;
  if (idx >= tot) return;
  int k = idx / (2*C);
  int c = idx - k*(2*C);
  int half = c / C;
  int cc = c - half*C;
  int t = cc / f, g = cc - t*f;
  Bp[idx] = pw[(size_t)t*3*f*f + (size_t)(half*f + k)*f + g];
}

// Pack post weights transposed, bf16: W2[t][j=s*20+g][k], k in [0,KP).
__global__ void k_pack_w2(const float* __restrict__ qw, unsigned short* __restrict__ W2,
                          int f, int KP) {
  int tot = T_ * 80 * KP;
  int idx = blockIdx.x * blockDim.x + threadIdx.x;
  if (idx >= tot) return;
  int k = idx % KP;
  int r = idx / KP;
  int j = r % 80;
  int t = r / 80;
  int s = j / 20, g = j - s*20;
  float v = 0.f;
  if (k < 4*f)                 v = qw[((size_t)t*17*f + f + (size_t)s*4*f + k) * FO_ + g];
  else if (k < 5*f && s == 0)  v = qw[((size_t)t*17*f + (k - 4*f)) * FO_ + g];
  W2[idx] = f2bf(v);
}

// ---------------- generic tiled fp32 GEMM: C = A(MxK) @ B(KxNc) (+bias) ----------------
__global__ __launch_bounds__(256) void k_gemm(
    const float* __restrict__ A, const float* __restrict__ Bm,
    const float* __restrict__ bias, float* __restrict__ Cm,
    int M, int K, int Nc)
{
  __shared__ __align__(16) float As[16][68];
  __shared__ __align__(16) float Bs[16][64];
  const int tid = threadIdx.x;
  const int bm = blockIdx.x * 64;
  const int bn = blockIdx.y * 64;
  const int mg = tid & 15;
  const int ng = tid >> 4;
  float acc[4][4];
  #pragma unroll
  for (int i = 0; i < 4; ++i)
    #pragma unroll
    for (int j = 0; j < 4; ++j) acc[i][j] = 0.f;

  for (int k0 = 0; k0 < K; k0 += 16) {
    {
      int kk = tid & 15, mr = tid >> 4;
      #pragma unroll
      for (int p = 0; p < 4; ++p) {
        int m = mr + p*16;
        int gm = bm + m, gk = k0 + kk;
        As[kk][m] = (gm < M && gk < K) ? A[(size_t)gm*K + gk] : 0.f;
      }
      int nn = tid & 63, kr = tid >> 6;
      #pragma unroll
      for (int p = 0; p < 4; ++p) {
        int k = kr + p*4;
        int gk = k0 + k, gn = bn + nn;
        Bs[k][nn] = (gk < K && gn < Nc) ? Bm[(size_t)gk*Nc + gn] : 0.f;
      }
    }
    __syncthreads();
    #pragma unroll
    for (int kk = 0; kk < 16; ++kk) {
      const float4 a = *(const float4*)&As[kk][mg*4];
      const float4 b = *(const float4*)&Bs[kk][ng*4];
      const float av[4] = {a.x, a.y, a.z, a.w};
      const float bv[4] = {b.x, b.y, b.z, b.w};
      #pragma unroll
      for (int i = 0; i < 4; ++i)
        #pragma unroll
        for (int j = 0; j < 4; ++j)
          acc[i][j] = fmaf(av[i], bv[j], acc[i][j]);
    }
    __syncthreads();
  }
  #pragma unroll
  for (int i = 0; i < 4; ++i) {
    int gm = bm + mg*4 + i;
    if (gm >= M) continue;
    #pragma unroll
    for (int j = 0; j < 4; ++j) {
      int gn = bn + ng*4 + j;
      if (gn < Nc) {
        float v = acc[i][j];
        if (bias) v += bias[gn];
        Cm[(size_t)gm*Nc + gn] = v;
      }
    }
  }
}

// ---- variant: split output. gn<split -> fp32 XI; gn>=split -> bf16 XJb tower-major [t][M][f]
__global__ __launch_bounds__(256) void k_gemm2(
    const float* __restrict__ A, const float* __restrict__ Bm,
    float* __restrict__ XI, unsigned short* __restrict__ XJb,
    int M, int K, int Nc, int split)
{
  __shared__ __align__(16) float As[16][68];
  __shared__ __align__(16) float Bs[16][64];
  const int tid = threadIdx.x;
  const int bm = blockIdx.x * 64;
  const int bn = blockIdx.y * 64;
  const int mg = tid & 15;
  const int ng = tid >> 4;
  float acc[4][4];
  #pragma unroll
  for (int i = 0; i < 4; ++i)
    #pragma unroll
    for (int j = 0; j < 4; ++j) acc[i][j] = 0.f;

  for (int k0 = 0; k0 < K; k0 += 16) {
    {
      int kk = tid & 15, mr = tid >> 4;
      #pragma unroll
      for (int p = 0; p < 4; ++p) {
        int m = mr + p*16;
        int gm = bm + m, gk = k0 + kk;
        As[kk][m] = (gm < M && gk < K) ? A[(size_t)gm*K + gk] : 0.f;
      }
      int nn = tid & 63, kr = tid >> 6;
      #pragma unroll
      for (int p = 0; p < 4; ++p) {
        int k = kr + p*4;
        int gk = k0 + k, gn = bn + nn;
        Bs[k][nn] = (gk < K && gn < Nc) ? Bm[(size_t)gk*Nc + gn] : 0.f;
      }
    }
    __syncthreads();
    #pragma unroll
    for (int kk = 0; kk < 16; ++kk) {
      const float4 a = *(const float4*)&As[kk][mg*4];
      const float4 b = *(const float4*)&Bs[kk][ng*4];
      const float av[4] = {a.x, a.y, a.z, a.w};
      const float bv[4] = {b.x, b.y, b.z, b.w};
      #pragma unroll
      for (int i = 0; i < 4; ++i)
        #pragma unroll
        for (int j = 0; j < 4; ++j)
          acc[i][j] = fmaf(av[i], bv[j], acc[i][j]);
    }
    __syncthreads();
  }
  #pragma unroll
  for (int i = 0; i < 4; ++i) {
    int gm = bm + mg*4 + i;
    if (gm >= M) continue;
    #pragma unroll
    for (int j = 0; j < 4; ++j) {
      int gn = bn + ng*4 + j;
      if (gn < Nc) {
        float v = acc[i][j];
        if (gn < split) XI[(size_t)gm*split + gn] = v;
        else {
          int c = gn - split;           // c = t*f + ff (K == f for the pre-GEMM)
          int tt = c / K, ff = c - tt*K;
          XJb[((size_t)tt*M + gm)*K + ff] = f2bf(v);
        }
      }
    }
  }
}

// ---------------- per-node aggregation -> bf16 Apost (tower-major) ----------------
// One wave per (node,tower); 4 waves/block; grid (N/4, T) -> tower-coherent
// dispatch keeps the 4MB XJb tower slice L2-resident on every XCD.
__global__ __launch_bounds__(256) void k_agg(
    const float* __restrict__ XI, const unsigned short* __restrict__ XJb,
    const int* __restrict__ rowptr, const int* __restrict__ cols,
    const int* __restrict__ srcArr, const float* __restrict__ ea,
    const float* __restrict__ vec_e, const float* __restrict__ cst_e,
    const float* __restrict__ xin, unsigned short* __restrict__ Apost,
    int f, int C, int KP)
{
  const int t = blockIdx.y;
  const int n = blockIdx.x * 4 + (threadIdx.x >> 6);
  if (n >= N_) return;
  const int lane = threadIdx.x & 63;
  const int fh = f >> 1;                  // f even
  const bool act = lane < fh;
  const int c0 = t*f + lane*2;
  const float v0 = act ? vec_e[c0]     : 0.f;
  const float v1 = act ? vec_e[c0 + 1] : 0.f;
  const int start = rowptr[n], end = rowptr[n+1];
  const unsigned int* xj_t = (const unsigned int*)XJb + (size_t)t * N_ * fh;
  float s10=0.f, s11=0.f, s20=0.f, s21=0.f;
  float mn0=1e30f, mn1=1e30f, mx0=-1e30f, mx1=-1e30f;
  for (int p = start; p < end; ++p) {
    int e = cols[p];
    int s = srcArr[e];
    float a = ea[e];
    if (act) {
      unsigned int u = xj_t[(size_t)s * fh + lane];
      float y0 = fmaf(a, v0, bf2f_lo(u));
      float y1 = fmaf(a, v1, bf2f_hi(u));
      s10 += y0; s20 = fmaf(y0, y0, s20);
      s11 += y1; s21 = fmaf(y1, y1, s21);
      mn0 = fminf(mn0, y0); mx0 = fmaxf(mx0, y0);
      mn1 = fminf(mn1, y1); mx1 = fmaxf(mx1, y1);
    }
  }
  const int dcnt = end - start;
  unsigned int* arow = (unsigned int*)(Apost + ((size_t)t * N_ + n) * KP);
  if (act) {
    float base0 = XI[(size_t)n*C + c0]     + cst_e[c0];
    float base1 = XI[(size_t)n*C + c0 + 1] + cst_e[c0 + 1];
    float me0, me1, sd0, sd1, lo0, lo1, hi0, hi1;
    if (dcnt > 0) {
      float inv = 1.0f / (float)dcnt;
      float m10 = s10 * inv, m11 = s11 * inv;
      me0 = base0 + m10; me1 = base1 + m11;
      sd0 = sqrtf(fmaxf(s20*inv - m10*m10, 0.f) + EPSF);
      sd1 = sqrtf(fmaxf(s21*inv - m11*m11, 0.f) + EPSF);
      lo0 = base0 + mn0; hi0 = base0 + mx0;
      lo1 = base1 + mn1; hi1 = base1 + mx1;
    } else {
      me0 = me1 = lo0 = lo1 = hi0 = hi1 = 0.f;
      sd0 = sd1 = sqrtf(EPSF);
    }
    arow[lane]          = packbf(me0, me1);   // mean block
    arow[fh + lane]     = packbf(lo0, lo1);   // min block
    arow[f + lane]      = packbf(hi0, hi1);   // max block (2f/2)
    arow[f + fh + lane] = packbf(sd0, sd1);   // std block (3f/2)
  }
  // x copy + zero pad: dwords [2f, KP/2)
  const int rem2 = (KP - 4*f) >> 1;
  for (int idx = lane; idx < rem2; idx += 64) {
    int k = 4*f + idx*2;
    unsigned int val = 0;
    if (k < 5*f) {
      const float* xp = &xin[(size_t)n*f + (k - 4*f)];
      val = packbf(xp[0], xp[1]);
    }
    arow[2*f + idx] = val;
  }
}

// ---------------- post GEMM via MFMA + fused scaler combine ----------------
// grid (ceil(N/128), T). 256 thr = 4 waves; wave w: rows [w*32,w*32+32),
// 2 m-frags x 5 n-frags 16x16, K-step 32. Epilogue: P tile -> LDS -> h.
__global__ __launch_bounds__(256) void k_postmm(
    const unsigned short* __restrict__ Apost, const unsigned short* __restrict__ W2,
    const float* __restrict__ scal, const float* __restrict__ qb,
    float* __restrict__ h, int KP)
{
  const int t    = blockIdx.y;
  const int m0   = blockIdx.x * 128;
  const int tid  = threadIdx.x;
  const int w    = tid >> 6;
  const int lane = tid & 63;
  const int rl   = lane & 15;     // frag row/col
  const int kq   = lane >> 4;     // k-quarter 0..3
  __shared__ __align__(16) unsigned char smem[128*84*4];   // 43008 B, reused
  unsigned short* As = (unsigned short*)smem;              // [128][40]
  unsigned short* Bs = As + 128*40;                        // [80][40]
  f32x4 acc[2][5];
  #pragma unroll
  for (int mf = 0; mf < 2; ++mf)
    #pragma unroll
    for (int nf = 0; nf < 5; ++nf) acc[mf][nf] = (f32x4){0.f,0.f,0.f,0.f};

  const unsigned short* wt = W2 + (size_t)t * 80 * KP;
  const unsigned short* at = Apost + (size_t)t * N_ * KP;

  for (int k0 = 0; k0 < KP; k0 += 32) {
    __syncthreads();
    #pragma unroll
    for (int p = 0; p < 2; ++p) {
      int idx = tid + p*256;
      int row = idx >> 2, q = idx & 3;
      int gm = m0 + row;
      uint4 v = {0u,0u,0u,0u};
      if (gm < N_) v = *(const uint4*)&at[(size_t)gm*KP + k0 + q*8];
      *(uint4*)&As[row*40 + q*8] = v;
    }
    #pragma unroll
    for (int p = 0; p < 2; ++p) {
      int idx = tid + p*256;
      if (idx < 320) {
        int j = idx >> 2, q = idx & 3;
        uint4 v = *(const uint4*)&wt[(size_t)j*KP + k0 + q*8];
        *(uint4*)&Bs[j*40 + q*8] = v;
      }
    }
    __syncthreads();
    short8 af[2], bf[5];
    #pragma unroll
    for (int mf = 0; mf < 2; ++mf)
      af[mf] = *(const short8*)&As[(w*32 + mf*16 + rl)*40 + kq*8];
    #pragma unroll
    for (int nf = 0; nf < 5; ++nf)
      bf[nf] = *(const short8*)&Bs[(nf*16 + rl)*40 + kq*8];
    #pragma unroll
    for (int mf = 0; mf < 2; ++mf)
      #pragma unroll
      for (int nf = 0; nf < 5; ++nf)
        acc[mf][nf] = __builtin_amdgcn_mfma_f32_16x16x32_bf16(af[mf], bf[nf], acc[mf][nf], 0, 0, 0);
  }
  // epilogue: P tile to LDS (C/D layout m89: col=lane&15, row=(lane>>4)*4+r)
  __syncthreads();
  float (*Pl)[84] = (float (*)[84])smem;
  #pragma unroll
  for (int mf = 0; mf < 2; ++mf)
    #pragma unroll
    for (int nf = 0; nf < 5; ++nf)
      #pragma unroll
      for (int r = 0; r < 4; ++r)
        Pl[w*32 + mf*16 + kq*4 + r][nf*16 + rl] = acc[mf][nf][r];
  __syncthreads();
  for (int idx = tid; idx < 128*FO_; idx += 256) {
    int row = idx / FO_, g = idx - row*FO_;
    int n = m0 + row;
    if (n < N_) {
      const float* p = Pl[row];
      float4 sc = *(const float4*)&scal[n*4];
      h[(size_t)n*(T_*FO_) + t*FO_ + g] =
        p[g] + sc.y*p[20+g] + sc.z*p[40+g] + sc.w*p[60+g] + qb[t*FO_+g];
    }
  }
}

// ---------------- batch norm ----------------
__global__ __launch_bounds__(256) void k_bnsum(const float* __restrict__ h2, float* __restrict__ bnsum) {
  const int tid  = threadIdx.x;
  const int c    = tid & 127;
  const int half = tid >> 7;
  if (c >= H_) return;
  float s = 0.f, s2 = 0.f;
  for (int r = blockIdx.x * 2 + half; r < N_; r += 256) {
    float v = h2[(size_t)r * H_ + c];
    s += v; s2 = fmaf(v, v, s2);
  }
  atomicAdd(&bnsum[c], s);
  atomicAdd(&bnsum[H_ + c], s2);
}

__global__ void k_bnapply(const float* __restrict__ h2, const float* __restrict__ bnsum,
                          const float* __restrict__ gam, const float* __restrict__ bet,
                          float* __restrict__ out) {
  size_t i = (size_t)blockIdx.x * blockDim.x + threadIdx.x;
  if (i >= (size_t)N_*H_) return;
  int c = (int)(i % H_);
  const float invn = 1.0f / (float)N_;
  float mu  = bnsum[c] * invn;
  float var = bnsum[H_ + c] * invn - mu*mu;
  float y = (h2[i] - mu) * rsqrtf(var + EPSF) * gam[c] + bet[c];
  out[i] = fmaxf(y, 0.f);
}

// ---------------- pooling + MLP ----------------
__global__ __launch_bounds__(256) void k_pool(const float* __restrict__ xc, const int* __restrict__ batch,
                                              float* __restrict__ gsum) {
  __shared__ float Pl[B_][H_];
  const int tid = threadIdx.x;
  for (int i = tid; i < B_*H_; i += 256) Pl[i / H_][i % H_] = 0.f;
  __syncthreads();
  const int r0 = blockIdx.x * PR_;
  const int rend = (r0 + PR_ < N_) ? r0 + PR_ : N_;
  const int nel = (rend - r0) * H_;
  for (int idx = tid; idx < nel; idx += 256) {
    int rr = idx / H_, c = idx - rr*H_;
    int n = r0 + rr;
    atomicAdd(&Pl[batch[n]][c], xc[(size_t)n*H_ + c]);
  }
  __syncthreads();
  const int blo = batch[r0], bhi = batch[rend-1];
  const int nb = (bhi - blo + 1) * H_;
  for (int idx = tid; idx < nb; idx += 256) {
    int b = blo + idx / H_, c = idx % H_;
    atomicAdd(&gsum[(size_t)b*H_ + c], Pl[b][c]);
  }
}

__global__ void k_gcnt(const int* __restrict__ batch, int* __restrict__ gcnt) {
  int n = blockIdx.x * blockDim.x + threadIdx.x;
  if (n < N_) atomicAdd(&gcnt[batch[n]], 1);
}

__global__ __launch_bounds__(512) void k_mlp(
    const float* __restrict__ gsum, const int* __restrict__ gcnt,
    const float* __restrict__ w1, const float* __restrict__ b1,
    const float* __restrict__ w2, const float* __restrict__ b2,
    const float* __restrict__ w3, const float* __restrict__ b3,
    float* __restrict__ out)
{
  __shared__ float G[B_][H_];
  __shared__ float A1[B_][50];
  __shared__ float A2[B_][25];
  const int tid = threadIdx.x;
  for (int i = tid; i < B_*H_; i += 512) {
    int r = i / H_;
    G[r][i - r*H_] = gsum[i] / fmaxf((float)gcnt[r], 1.0f);
  }
  __syncthreads();
  for (int i = tid; i < B_*50; i += 512) {
    int r = i / 50, c = i - r*50;
    float a = b1[c];
    for (int k = 0; k < H_; ++k) a = fmaf(G[r][k], w1[k*50 + c], a);
    A1[r][c] = fmaxf(a, 0.f);
  }
  __syncthreads();
  for (int i = tid; i < B_*25; i += 512) {
    int r = i / 25, c = i - r*25;
    float a = b2[c];
    for (int k = 0; k < 50; ++k) a = fmaf(A1[r][k], w2[k*25 + c], a);
    A2[r][c] = fmaxf(a, 0.f);
  }
  __syncthreads();
  for (int i = tid; i < B_; i += 512) {
    float a = b3[0];
    for (int k = 0; k < 25; ++k) a = fmaf(A2[i][k], w3[k], a);
    out[i] = a;   // float32 output — reference output dtype is f32
  }
}

// ---------------- host ----------------
extern "C" void kernel_launch(void* const* d_in, const int* in_sizes, int n_in,
                              void* d_out, int out_size, void* d_ws, size_t ws_size,
                              hipStream_t stream)
{
  (void)in_sizes; (void)n_in; (void)out_size;
  const float* x0   = (const float*)d_in[0];
  const int*   eidx = (const int*)  d_in[1];
  const float* ea   = (const float*)d_in[2];
  const int*   batch= (const int*)  d_in[3];
  const float* e0w  = (const float*)d_in[4];
  const float* e0b  = (const float*)d_in[5];
  const float* p0w  = (const float*)d_in[6];
  const float* p0b  = (const float*)d_in[7];
  const float* q0w  = (const float*)d_in[8];
  const float* q0b  = (const float*)d_in[9];
  const float* l0w  = (const float*)d_in[10];
  const float* l0b  = (const float*)d_in[11];
  const float* g0   = (const float*)d_in[12];
  const float* b0   = (const float*)d_in[13];
  const float* eLw  = (const float*)d_in[14];
  const float* eLb  = (const float*)d_in[15];
  const float* pLw  = (const float*)d_in[16];
  const float* pLb  = (const float*)d_in[17];
  const float* qLw  = (const float*)d_in[18];
  const float* qLb  = (const float*)d_in[19];
  const float* lLw  = (const float*)d_in[20];
  const float* lLb  = (const float*)d_in[21];
  const float* gL   = (const float*)d_in[22];
  const float* bL   = (const float*)d_in[23];
  const float* w1   = (const float*)d_in[24];
  const float* b1   = (const float*)d_in[25];
  const float* w2   = (const float*)d_in[26];
  const float* b2   = (const float*)d_in[27];
  const float* w3   = (const float*)d_in[28];
  const float* b3   = (const float*)d_in[29];

  const int* src = eidx;
  const int* dst = eidx + E_;

  char* w = (char*)d_ws;
  size_t off = 0;
  auto take = [&](size_t bytes) -> void* {
    void* p = (void*)(w + off);
    off = (off + bytes + 255) & ~(size_t)255;
    return p;
  };
  int*   cnt    = (int*)  take((size_t)N_*4);
  int*   rowptr = (int*)  take((size_t)(N_+1)*4);
  int*   cursor = (int*)  take((size_t)N_*4);
  int*   cols   = (int*)  take((size_t)E_*4);
  float* scal   = (float*)take((size_t)N_*16);
  float* sumlog = (float*)take(256);
  float* bnsum  = (float*)take((size_t)2*H_*4);
  float* vec_e  = (float*)take((size_t)T_*H_*4);
  float* cst_e  = (float*)take((size_t)T_*H_*4);
  float* Bpre   = (float*)take((size_t)H_*2*T_*H_*4);
  unsigned short* W2 = (unsigned short*)take((size_t)T_*80*512*2);
  float* XI     = (float*)take((size_t)N_*T_*H_*4);          // 40 MB
  unsigned short* XJb = (unsigned short*)take((size_t)N_*T_*H_*2);  // 20 MB tower-major
  unsigned short* Apost = (unsigned short*)take((size_t)N_*T_*512*2);  // 102 MB tower-major
  float* hbuf   = (float*)take((size_t)N_*H_*4);
  float* h2buf  = (float*)take((size_t)N_*H_*4);
  float* xcur   = (float*)take((size_t)N_*H_*4);
  float* gsum   = (float*)take((size_t)B_*H_*4);
  int*   gcnt   = (int*)  take((size_t)B_*4);
  if (off > ws_size) return;   // workspace too small: bail (test fails loudly)

  hipMemsetAsync(cnt,    0, (size_t)N_*4, stream);
  hipMemsetAsync(cursor, 0, (size_t)N_*4, stream);
  hipMemsetAsync(sumlog, 0, 4, stream);
  hipMemsetAsync(gsum,   0, (size_t)B_*H_*4, stream);
  hipMemsetAsync(gcnt,   0, (size_t)B_*4, stream);

  k_count <<<dim3((E_+255)/256), dim3(256), 0, stream>>>(dst, cnt);
  k_scan  <<<dim3(1),            dim3(1024),0, stream>>>(cnt, rowptr);
  k_fill  <<<dim3((E_+255)/256), dim3(256), 0, stream>>>(dst, rowptr, cursor, cols);
  k_sumlog<<<dim3((N_+255)/256), dim3(256), 0, stream>>>(cnt, sumlog);
  k_scal  <<<dim3((N_+255)/256), dim3(256), 0, stream>>>(cnt, sumlog, scal);

  auto layer = [&](const float* xin, int f,
                   const float* ew, const float* eb, const float* pw, const float* pb,
                   const float* qw, const float* qb, const float* lw, const float* lb,
                   const float* bg, const float* bb) {
    const int C  = T_ * f;
    const int KP = ((5*f + 31) / 32) * 32;   // padded per-tower K (f=16:96, f=100:512)
    k_edgevec<<<dim3((C+255)/256), dim3(256), 0, stream>>>(pw, pb, ew, eb, vec_e, cst_e, f, C);
    const int pe = f * 2 * C;
    k_pack_pre<<<dim3((pe+255)/256), dim3(256), 0, stream>>>(pw, Bpre, f, C);
    const int wtot = T_ * 80 * KP;
    k_pack_w2<<<dim3((wtot+255)/256), dim3(256), 0, stream>>>(qw, W2, f, KP);
    k_gemm2<<<dim3((N_+63)/64, (2*C+63)/64), dim3(256), 0, stream>>>(xin, Bpre, XI, XJb, N_, f, 2*C, C);
    k_agg<<<dim3((N_+3)/4, T_), dim3(256), 0, stream>>>(XI, XJb, rowptr, cols, src, ea, vec_e, cst_e, xin, Apost, f, C, KP);
    k_postmm<<<dim3((N_+127)/128, T_), dim3(256), 0, stream>>>(Apost, W2, scal, qb, hbuf, KP);
    k_gemm<<<dim3((N_+63)/64, (H_+63)/64), dim3(256), 0, stream>>>(hbuf, lw, lb, h2buf, N_, H_, H_);
    hipMemsetAsync(bnsum, 0, (size_t)2*H_*4, stream);
    k_bnsum<<<dim3(128), dim3(256), 0, stream>>>(h2buf, bnsum);
    k_bnapply<<<dim3((unsigned)(((size_t)N_*H_+255)/256)), dim3(256), 0, stream>>>(h2buf, bnsum, bg, bb, xcur);
  };

  layer(x0,   FI_, e0w, e0b, p0w, p0b, q0w, q0b, l0w, l0b, g0, b0);
  layer(xcur, H_,  eLw, eLb, pLw, pLb, qLw, qLb, lLw, lLb, gL, bL);
  layer(xcur, H_,  eLw + H_, eLb + H_,
        pLw + (size_t)T_*3*H_*H_, pLb + T_*H_,
        qLw + (size_t)T_*17*H_*FO_, qLb + T_*FO_,
        lLw + H_*H_, lLb + H_, gL + H_, bL + H_);

  k_pool<<<dim3((N_+PR_-1)/PR_), dim3(256), 0, stream>>>(xcur, batch, gsum);
  k_gcnt<<<dim3((N_+255)/256), dim3(256), 0, stream>>>(batch, gcnt);
  k_mlp <<<dim3(1), dim3(512), 0, stream>>>(gsum, gcnt, w1, b1, w2, b2, w3, b3, (float*)d_out);
}

// Round 9
// 1182.627 us; speedup vs baseline: 1.3881x; 1.3881x over previous
//
#include <hip/hip_runtime.h>
#include <hip/hip_bf16.h>
#include <cstddef>

#define N_  20000
#define E_  320000
#define FI_ 16
#define H_  100
#define T_  5
#define FO_ 20
#define B_  50
#define EPSF 1e-5f
#define PR_  200    // k_pool rows per block

typedef __attribute__((ext_vector_type(8))) short short8;
typedef __attribute__((ext_vector_type(4))) float f32x4;

static __device__ __forceinline__ unsigned short f2bf(float x) {
  unsigned int u = __builtin_bit_cast(unsigned int, x);
  unsigned int r = (u + 0x7FFFu + ((u >> 16) & 1u)) >> 16;   // RNE
  return (unsigned short)r;
}
static __device__ __forceinline__ unsigned int packbf(float a, float b) {
  return (unsigned int)f2bf(a) | ((unsigned int)f2bf(b) << 16);
}
static __device__ __forceinline__ float bf2f_lo(unsigned int u) {
  return __builtin_bit_cast(float, (u & 0xFFFFu) << 16);
}
static __device__ __forceinline__ float bf2f_hi(unsigned int u) {
  return __builtin_bit_cast(float, u & 0xFFFF0000u);
}

// ---------------- graph prep ----------------
__global__ void k_count(const int* __restrict__ dst, int* __restrict__ cnt) {
  int e = blockIdx.x * blockDim.x + threadIdx.x;
  if (e < E_) atomicAdd(&cnt[dst[e]], 1);
}

__global__ __launch_bounds__(1024) void k_scan(const int* __restrict__ cnt, int* __restrict__ rowptr) {
  __shared__ int ls[1024];
  const int tid = threadIdx.x;
  int carry = 0;
  for (int start = 0; start < N_; start += 1024) {
    int i = start + tid;
    int v = (i < N_) ? cnt[i] : 0;
    ls[tid] = v;
    __syncthreads();
    for (int off = 1; off < 1024; off <<= 1) {
      int t = (tid >= off) ? ls[tid - off] : 0;
      __syncthreads();
      ls[tid] += t;
      __syncthreads();
    }
    if (i < N_) rowptr[i] = carry + ls[tid] - v;   // exclusive scan
    carry += ls[1023];
    __syncthreads();
  }
  if (tid == 0) rowptr[N_] = carry;
}

__global__ void k_fill(const int* __restrict__ dst, const int* __restrict__ rowptr,
                       int* __restrict__ cursor, int* __restrict__ cols) {
  int e = blockIdx.x * blockDim.x + threadIdx.x;
  if (e < E_) {
    int v = dst[e];
    int p = atomicAdd(&cursor[v], 1);
    cols[rowptr[v] + p] = e;
  }
}

__global__ void k_sumlog(const int* __restrict__ cnt, float* __restrict__ sumlog) {
  int i = blockIdx.x * blockDim.x + threadIdx.x;
  float v = (i < N_) ? logf((float)cnt[i] + 1.0f) : 0.0f;
  #pragma unroll
  for (int off = 32; off > 0; off >>= 1) v += __shfl_down(v, off);
  __shared__ float red[4];
  if ((threadIdx.x & 63) == 0) red[threadIdx.x >> 6] = v;
  __syncthreads();
  if (threadIdx.x == 0) atomicAdd(sumlog, red[0] + red[1] + red[2] + red[3]);
}

__global__ void k_scal(const int* __restrict__ cnt, const float* __restrict__ sumlog,
                       float* __restrict__ scal) {
  int i = blockIdx.x * blockDim.x + threadIdx.x;
  if (i >= N_) return;
  float c  = (float)cnt[i];
  float d  = fmaxf(c, 1.0f);
  float ld = logf(d + 1.0f);
  float avg_log = sumlog[0] * (1.0f / (float)N_);
  float avg_lin = (float)E_ / (float)N_;
  scal[i*4+0] = 1.0f;
  scal[i*4+1] = ld / avg_log;
  scal[i*4+2] = avg_log / ld;
  scal[i*4+3] = d / avg_lin;
}

// ---------------- per-layer prep ----------------
__global__ void k_edgevec(const float* __restrict__ pw, const float* __restrict__ pb,
                          const float* __restrict__ ew, const float* __restrict__ eb,
                          float* __restrict__ vec_e, float* __restrict__ cst_e, int f, int C) {
  int c = blockIdx.x * blockDim.x + threadIdx.x;
  if (c >= C) return;
  int t = c / f, g = c - t*f;
  const float* wp = pw + (size_t)t*3*f*f + (size_t)2*f*f + g;
  float v = 0.f, s = 0.f;
  for (int ff = 0; ff < f; ++ff) { float wv = wp[(size_t)ff*f]; v += ew[ff]*wv; s += eb[ff]*wv; }
  vec_e[c] = v;
  cst_e[c] = s + pb[c];
}

// BpreT[c][KPk] bf16, transposed+padded: c<2C from pw (k<f), else 0.
__global__ void k_pack_preT(const float* __restrict__ pw, unsigned short* __restrict__ Bb,
                            int f, int C, int KPk, int NcPad) {
  int tot = NcPad * KPk;
  int idx = blockIdx.x * blockDim.x + threadIdx.x;
  if (idx >= tot) return;
  int k = idx % KPk, c = idx / KPk;
  float v = 0.f;
  if (c < 2*C && k < f) {
    int half = c / C, cc = c - half*C;
    int t = cc / f, g = cc - t*f;
    v = pw[(size_t)t*3*f*f + (size_t)(half*f + k)*f + g];
  }
  Bb[idx] = f2bf(v);
}

// Pack post weights transposed, bf16: W2[t][j=s*20+g][k], k in [0,KP).
__global__ void k_pack_w2(const float* __restrict__ qw, unsigned short* __restrict__ W2,
                          int f, int KP) {
  int tot = T_ * 80 * KP;
  int idx = blockIdx.x * blockDim.x + threadIdx.x;
  if (idx >= tot) return;
  int k = idx % KP;
  int r = idx / KP;
  int j = r % 80;
  int t = r / 80;
  int s = j / 20, g = j - s*20;
  float v = 0.f;
  if (k < 4*f)                 v = qw[((size_t)t*17*f + f + (size_t)s*4*f + k) * FO_ + g];
  else if (k < 5*f && s == 0)  v = qw[((size_t)t*17*f + (k - 4*f)) * FO_ + g];
  W2[idx] = f2bf(v);
}

// ---------------- generic tiled fp32 GEMM (lin layer only) ----------------
__global__ __launch_bounds__(256) void k_gemm(
    const float* __restrict__ A, const float* __restrict__ Bm,
    const float* __restrict__ bias, float* __restrict__ Cm,
    int M, int K, int Nc)
{
  __shared__ __align__(16) float As[16][68];
  __shared__ __align__(16) float Bs[16][64];
  const int tid = threadIdx.x;
  const int bm = blockIdx.x * 64;
  const int bn = blockIdx.y * 64;
  const int mg = tid & 15;
  const int ng = tid >> 4;
  float acc[4][4];
  #pragma unroll
  for (int i = 0; i < 4; ++i)
    #pragma unroll
    for (int j = 0; j < 4; ++j) acc[i][j] = 0.f;

  for (int k0 = 0; k0 < K; k0 += 16) {
    {
      int kk = tid & 15, mr = tid >> 4;
      #pragma unroll
      for (int p = 0; p < 4; ++p) {
        int m = mr + p*16;
        int gm = bm + m, gk = k0 + kk;
        As[kk][m] = (gm < M && gk < K) ? A[(size_t)gm*K + gk] : 0.f;
      }
      int nn = tid & 63, kr = tid >> 6;
      #pragma unroll
      for (int p = 0; p < 4; ++p) {
        int k = kr + p*4;
        int gk = k0 + k, gn = bn + nn;
        Bs[k][nn] = (gk < K && gn < Nc) ? Bm[(size_t)gk*Nc + gn] : 0.f;
      }
    }
    __syncthreads();
    #pragma unroll
    for (int kk = 0; kk < 16; ++kk) {
      const float4 a = *(const float4*)&As[kk][mg*4];
      const float4 b = *(const float4*)&Bs[kk][ng*4];
      const float av[4] = {a.x, a.y, a.z, a.w};
      const float bv[4] = {b.x, b.y, b.z, b.w};
      #pragma unroll
      for (int i = 0; i < 4; ++i)
        #pragma unroll
        for (int j = 0; j < 4; ++j)
          acc[i][j] = fmaf(av[i], bv[j], acc[i][j]);
    }
    __syncthreads();
  }
  #pragma unroll
  for (int i = 0; i < 4; ++i) {
    int gm = bm + mg*4 + i;
    if (gm >= M) continue;
    #pragma unroll
    for (int j = 0; j < 4; ++j) {
      int gn = bn + ng*4 + j;
      if (gn < Nc) {
        float v = acc[i][j];
        if (bias) v += bias[gn];
        Cm[(size_t)gm*Nc + gn] = v;
      }
    }
  }
}

// ---------------- pre-GEMM via MFMA, split epilogue ----------------
// A fp32 (MxK) -> bf16 on stage; Bb bf16 [NcPad][KPk] j-major.
// grid (ceil(M/128), NcPad/128). 4 waves; wave w: rows w*32..+32, 8 n-frags.
// gn<split -> XI fp32; else XJb bf16 node-major [gm*split + gn-split].
__global__ __launch_bounds__(256) void k_mmsplit(
    const float* __restrict__ A, const unsigned short* __restrict__ Bb,
    float* __restrict__ XI, unsigned short* __restrict__ XJb,
    int M, int K, int KPk, int split)
{
  const int m0 = blockIdx.x * 128;
  const int bn = blockIdx.y * 128;
  const int Nc = 2 * split;
  const int tid = threadIdx.x;
  const int w = tid >> 6, lane = tid & 63;
  const int rl = lane & 15, kq = lane >> 4;
  __shared__ __align__(16) unsigned short As[128*40];
  __shared__ __align__(16) unsigned short Bs[128*40];
  f32x4 acc[2][8];
  #pragma unroll
  for (int mf = 0; mf < 2; ++mf)
    #pragma unroll
    for (int nf = 0; nf < 8; ++nf) acc[mf][nf] = (f32x4){0.f,0.f,0.f,0.f};

  for (int k0 = 0; k0 < KPk; k0 += 32) {
    __syncthreads();
    // stage A: 128 rows x 32 k, fp32 -> bf16 (512 chunks of 8)
    #pragma unroll
    for (int p = 0; p < 2; ++p) {
      int idx = tid + p*256;
      int row = idx >> 2, q = idx & 3;
      int gm = m0 + row;
      int gk = k0 + q*8;
      unsigned int d0 = 0, d1 = 0, d2 = 0, d3 = 0;
      if (gm < M) {
        if (gk + 8 <= K) {
          const float4 v0 = *(const float4*)&A[(size_t)gm*K + gk];
          const float4 v1 = *(const float4*)&A[(size_t)gm*K + gk + 4];
          d0 = packbf(v0.x, v0.y); d1 = packbf(v0.z, v0.w);
          d2 = packbf(v1.x, v1.y); d3 = packbf(v1.z, v1.w);
        } else if (gk < K) {
          float tmp[8];
          #pragma unroll
          for (int e = 0; e < 8; ++e) tmp[e] = (gk + e < K) ? A[(size_t)gm*K + gk + e] : 0.f;
          d0 = packbf(tmp[0], tmp[1]); d1 = packbf(tmp[2], tmp[3]);
          d2 = packbf(tmp[4], tmp[5]); d3 = packbf(tmp[6], tmp[7]);
        }
      }
      uint4 dv = {d0, d1, d2, d3};
      *(uint4*)&As[row*40 + q*8] = dv;
    }
    // stage B: 128 cols x 32 k (padded buffer -> no bounds)
    #pragma unroll
    for (int p = 0; p < 2; ++p) {
      int idx = tid + p*256;
      int j = idx >> 2, q = idx & 3;
      uint4 v = *(const uint4*)&Bb[((size_t)(bn + j))*KPk + k0 + q*8];
      *(uint4*)&Bs[j*40 + q*8] = v;
    }
    __syncthreads();
    short8 af[2], bf[8];
    #pragma unroll
    for (int mf = 0; mf < 2; ++mf)
      af[mf] = *(const short8*)&As[(w*32 + mf*16 + rl)*40 + kq*8];
    #pragma unroll
    for (int nf = 0; nf < 8; ++nf)
      bf[nf] = *(const short8*)&Bs[(nf*16 + rl)*40 + kq*8];
    #pragma unroll
    for (int mf = 0; mf < 2; ++mf)
      #pragma unroll
      for (int nf = 0; nf < 8; ++nf)
        acc[mf][nf] = __builtin_amdgcn_mfma_f32_16x16x32_bf16(af[mf], bf[nf], acc[mf][nf], 0, 0, 0);
  }
  // epilogue: C/D layout (m89): col = lane&15, row = (lane>>4)*4 + r
  #pragma unroll
  for (int mf = 0; mf < 2; ++mf)
    #pragma unroll
    for (int nf = 0; nf < 8; ++nf)
      #pragma unroll
      for (int r = 0; r < 4; ++r) {
        int gm = m0 + w*32 + mf*16 + kq*4 + r;
        int gn = bn + nf*16 + rl;
        if (gm < M && gn < Nc) {
          float v = acc[mf][nf][r];
          if (gn < split) XI[(size_t)gm*split + gn] = v;
          else            XJb[(size_t)gm*split + (gn - split)] = f2bf(v);
        }
      }
}

// ---------------- per-node aggregation -> bf16 Apost rows (round-7 proven) ----------------
__global__ __launch_bounds__(256) void k_agg(
    const float* __restrict__ XI, const unsigned short* __restrict__ XJb,
    const int* __restrict__ rowptr,
    const int* __restrict__ cols, const int* __restrict__ srcArr,
    const float* __restrict__ ea, const float* __restrict__ vec_e,
    const float* __restrict__ cst_e, const float* __restrict__ xin,
    unsigned short* __restrict__ Apost, int f, int C, int KP)
{
  __shared__ float vsh[512];
  const int tid = threadIdx.x;
  for (int c = tid; c < C; c += 256) vsh[c] = vec_e[c];
  __syncthreads();
  const int v = blockIdx.x;
  const int start = rowptr[v], end = rowptr[v+1];
  const int half = C >> 1;                 // C even (T*f, f even)
  const bool act = (tid < half);
  const float v0 = act ? vsh[tid*2]   : 0.f;
  const float v1 = act ? vsh[tid*2+1] : 0.f;
  float s10 = 0.f, s11 = 0.f, s20 = 0.f, s21 = 0.f;
  float mn0 = 1e30f, mn1 = 1e30f, mx0 = -1e30f, mx1 = -1e30f;
  for (int p = start; p < end; ++p) {
    int e = cols[p];
    int s = srcArr[e];
    float a = ea[e];
    if (act) {
      unsigned int u = ((const unsigned int*)(XJb + (size_t)s * C))[tid];
      float y0 = fmaf(a, v0, bf2f_lo(u));
      float y1 = fmaf(a, v1, bf2f_hi(u));
      s10 += y0; s20 = fmaf(y0, y0, s20);
      s11 += y1; s21 = fmaf(y1, y1, s21);
      mn0 = fminf(mn0, y0); mx0 = fmaxf(mx0, y0);
      mn1 = fminf(mn1, y1); mx1 = fmaxf(mx1, y1);
    }
  }
  const int dcnt = end - start;
  if (act) {
    int c0 = tid*2;
    int t = c0 / f, ff = c0 - t*f;          // pair never straddles towers (f even)
    float base0 = XI[(size_t)v*C + c0]     + cst_e[c0];
    float base1 = XI[(size_t)v*C + c0 + 1] + cst_e[c0 + 1];
    float me0, sd0, lo0, hi0, me1, sd1, lo1, hi1;
    if (dcnt > 0) {
      float inv = 1.0f / (float)dcnt;
      float m10 = s10 * inv, m11 = s11 * inv;
      me0 = base0 + m10; me1 = base1 + m11;
      sd0 = sqrtf(fmaxf(s20*inv - m10*m10, 0.f) + EPSF);
      sd1 = sqrtf(fmaxf(s21*inv - m11*m11, 0.f) + EPSF);
      lo0 = base0 + mn0; hi0 = base0 + mx0;
      lo1 = base1 + mn1; hi1 = base1 + mx1;
    } else {
      me0 = me1 = lo0 = lo1 = hi0 = hi1 = 0.f;
      sd0 = sd1 = sqrtf(EPSF);
    }
    unsigned short* o = Apost + ((size_t)v * T_ + t) * KP + ff;
    o[0]     = f2bf(me0); o[1]       = f2bf(me1);
    o[f]     = f2bf(lo0); o[f+1]     = f2bf(lo1);
    o[2*f]   = f2bf(hi0); o[2*f+1]   = f2bf(hi1);
    o[3*f]   = f2bf(sd0); o[3*f+1]   = f2bf(sd1);
  }
  // x copy (shared by all towers) + zero pad
  const int rem = KP - 4*f;
  for (int idx = tid; idx < T_*rem; idx += 256) {
    int t = idx / rem, kk = idx - t*rem;
    int k = 4*f + kk;
    unsigned short val = 0;
    if (k < 5*f) val = f2bf(xin[(size_t)v*f + (k - 4*f)]);
    Apost[((size_t)v * T_ + t) * KP + k] = val;
  }
}

// ---------------- post GEMM via MFMA + fused scaler combine (round-7 proven) ----------------
__global__ __launch_bounds__(256) void k_postmm(
    const unsigned short* __restrict__ Apost, const unsigned short* __restrict__ W2,
    const float* __restrict__ scal, const float* __restrict__ qb,
    float* __restrict__ h, int KP)
{
  const int t    = blockIdx.y;
  const int m0   = blockIdx.x * 128;
  const int tid  = threadIdx.x;
  const int w    = tid >> 6;
  const int lane = tid & 63;
  const int rl   = lane & 15;     // frag row/col
  const int kq   = lane >> 4;     // k-quarter 0..3
  __shared__ __align__(16) unsigned char smem[128*84*4];   // 43008 B, reused
  unsigned short* As = (unsigned short*)smem;              // [128][40]
  unsigned short* Bs = As + 128*40;                        // [80][40]
  f32x4 acc[2][5];
  #pragma unroll
  for (int mf = 0; mf < 2; ++mf)
    #pragma unroll
    for (int nf = 0; nf < 5; ++nf) acc[mf][nf] = (f32x4){0.f,0.f,0.f,0.f};

  const unsigned short* wt = W2 + (size_t)t * 80 * KP;

  for (int k0 = 0; k0 < KP; k0 += 32) {
    __syncthreads();
    #pragma unroll
    for (int p = 0; p < 2; ++p) {
      int idx = tid + p*256;
      int row = idx >> 2, q = idx & 3;
      int gm = m0 + row;
      uint4 v = {0u,0u,0u,0u};
      if (gm < N_) v = *(const uint4*)&Apost[((size_t)gm*T_ + t)*KP + k0 + q*8];
      *(uint4*)&As[row*40 + q*8] = v;
    }
    #pragma unroll
    for (int p = 0; p < 2; ++p) {
      int idx = tid + p*256;
      if (idx < 320) {
        int j = idx >> 2, q = idx & 3;
        uint4 v = *(const uint4*)&wt[(size_t)j*KP + k0 + q*8];
        *(uint4*)&Bs[j*40 + q*8] = v;
      }
    }
    __syncthreads();
    short8 af[2], bf[5];
    #pragma unroll
    for (int mf = 0; mf < 2; ++mf)
      af[mf] = *(const short8*)&As[(w*32 + mf*16 + rl)*40 + kq*8];
    #pragma unroll
    for (int nf = 0; nf < 5; ++nf)
      bf[nf] = *(const short8*)&Bs[(nf*16 + rl)*40 + kq*8];
    #pragma unroll
    for (int mf = 0; mf < 2; ++mf)
      #pragma unroll
      for (int nf = 0; nf < 5; ++nf)
        acc[mf][nf] = __builtin_amdgcn_mfma_f32_16x16x32_bf16(af[mf], bf[nf], acc[mf][nf], 0, 0, 0);
  }
  // epilogue: P tile to LDS (C/D layout m89: col=lane&15, row=(lane>>4)*4+r)
  __syncthreads();
  float (*Pl)[84] = (float (*)[84])smem;
  #pragma unroll
  for (int mf = 0; mf < 2; ++mf)
    #pragma unroll
    for (int nf = 0; nf < 5; ++nf)
      #pragma unroll
      for (int r = 0; r < 4; ++r)
        Pl[w*32 + mf*16 + kq*4 + r][nf*16 + rl] = acc[mf][nf][r];
  __syncthreads();
  for (int idx = tid; idx < 128*FO_; idx += 256) {
    int row = idx / FO_, g = idx - row*FO_;
    int n = m0 + row;
    if (n < N_) {
      const float* p = Pl[row];
      float4 sc = *(const float4*)&scal[n*4];
      h[(size_t)n*(T_*FO_) + t*FO_ + g] =
        p[g] + sc.y*p[20+g] + sc.z*p[40+g] + sc.w*p[60+g] + qb[t*FO_+g];
    }
  }
}

// ---------------- batch norm ----------------
__global__ __launch_bounds__(256) void k_bnsum(const float* __restrict__ h2, float* __restrict__ bnsum) {
  const int tid  = threadIdx.x;
  const int c    = tid & 127;
  const int half = tid >> 7;
  if (c >= H_) return;
  float s = 0.f, s2 = 0.f;
  for (int r = blockIdx.x * 2 + half; r < N_; r += 256) {
    float v = h2[(size_t)r * H_ + c];
    s += v; s2 = fmaf(v, v, s2);
  }
  atomicAdd(&bnsum[c], s);
  atomicAdd(&bnsum[H_ + c], s2);
}

__global__ void k_bnapply(const float* __restrict__ h2, const float* __restrict__ bnsum,
                          const float* __restrict__ gam, const float* __restrict__ bet,
                          float* __restrict__ out) {
  size_t i = (size_t)blockIdx.x * blockDim.x + threadIdx.x;
  if (i >= (size_t)N_*H_) return;
  int c = (int)(i % H_);
  const float invn = 1.0f / (float)N_;
  float mu  = bnsum[c] * invn;
  float var = bnsum[H_ + c] * invn - mu*mu;
  float y = (h2[i] - mu) * rsqrtf(var + EPSF) * gam[c] + bet[c];
  out[i] = fmaxf(y, 0.f);
}

// ---------------- pooling + MLP ----------------
__global__ __launch_bounds__(256) void k_pool(const float* __restrict__ xc, const int* __restrict__ batch,
                                              float* __restrict__ gsum) {
  __shared__ float Pl[B_][H_];
  const int tid = threadIdx.x;
  for (int i = tid; i < B_*H_; i += 256) Pl[i / H_][i % H_] = 0.f;
  __syncthreads();
  const int r0 = blockIdx.x * PR_;
  const int rend = (r0 + PR_ < N_) ? r0 + PR_ : N_;
  const int nel = (rend - r0) * H_;
  for (int idx = tid; idx < nel; idx += 256) {
    int rr = idx / H_, c = idx - rr*H_;
    int n = r0 + rr;
    atomicAdd(&Pl[batch[n]][c], xc[(size_t)n*H_ + c]);
  }
  __syncthreads();
  const int blo = batch[r0], bhi = batch[rend-1];
  const int nb = (bhi - blo + 1) * H_;
  for (int idx = tid; idx < nb; idx += 256) {
    int b = blo + idx / H_, c = idx % H_;
    atomicAdd(&gsum[(size_t)b*H_ + c], Pl[b][c]);
  }
}

__global__ void k_gcnt(const int* __restrict__ batch, int* __restrict__ gcnt) {
  int n = blockIdx.x * blockDim.x + threadIdx.x;
  if (n < N_) atomicAdd(&gcnt[batch[n]], 1);
}

__global__ __launch_bounds__(512) void k_mlp(
    const float* __restrict__ gsum, const int* __restrict__ gcnt,
    const float* __restrict__ w1, const float* __restrict__ b1,
    const float* __restrict__ w2, const float* __restrict__ b2,
    const float* __restrict__ w3, const float* __restrict__ b3,
    float* __restrict__ out)
{
  __shared__ float G[B_][H_];
  __shared__ float A1[B_][50];
  __shared__ float A2[B_][25];
  const int tid = threadIdx.x;
  for (int i = tid; i < B_*H_; i += 512) {
    int r = i / H_;
    G[r][i - r*H_] = gsum[i] / fmaxf((float)gcnt[r], 1.0f);
  }
  __syncthreads();
  for (int i = tid; i < B_*50; i += 512) {
    int r = i / 50, c = i - r*50;
    float a = b1[c];
    for (int k = 0; k < H_; ++k) a = fmaf(G[r][k], w1[k*50 + c], a);
    A1[r][c] = fmaxf(a, 0.f);
  }
  __syncthreads();
  for (int i = tid; i < B_*25; i += 512) {
    int r = i / 25, c = i - r*25;
    float a = b2[c];
    for (int k = 0; k < 50; ++k) a = fmaf(A1[r][k], w2[k*25 + c], a);
    A2[r][c] = fmaxf(a, 0.f);
  }
  __syncthreads();
  for (int i = tid; i < B_; i += 512) {
    float a = b3[0];
    for (int k = 0; k < 25; ++k) a = fmaf(A2[i][k], w3[k], a);
    out[i] = a;   // float32 output — reference output dtype is f32
  }
}

// ---------------- host ----------------
extern "C" void kernel_launch(void* const* d_in, const int* in_sizes, int n_in,
                              void* d_out, int out_size, void* d_ws, size_t ws_size,
                              hipStream_t stream)
{
  (void)in_sizes; (void)n_in; (void)out_size;
  const float* x0   = (const float*)d_in[0];
  const int*   eidx = (const int*)  d_in[1];
  const float* ea   = (const float*)d_in[2];
  const int*   batch= (const int*)  d_in[3];
  const float* e0w  = (const float*)d_in[4];
  const float* e0b  = (const float*)d_in[5];
  const float* p0w  = (const float*)d_in[6];
  const float* p0b  = (const float*)d_in[7];
  const float* q0w  = (const float*)d_in[8];
  const float* q0b  = (const float*)d_in[9];
  const float* l0w  = (const float*)d_in[10];
  const float* l0b  = (const float*)d_in[11];
  const float* g0   = (const float*)d_in[12];
  const float* b0   = (const float*)d_in[13];
  const float* eLw  = (const float*)d_in[14];
  const float* eLb  = (const float*)d_in[15];
  const float* pLw  = (const float*)d_in[16];
  const float* pLb  = (const float*)d_in[17];
  const float* qLw  = (const float*)d_in[18];
  const float* qLb  = (const float*)d_in[19];
  const float* lLw  = (const float*)d_in[20];
  const float* lLb  = (const float*)d_in[21];
  const float* gL   = (const float*)d_in[22];
  const float* bL   = (const float*)d_in[23];
  const float* w1   = (const float*)d_in[24];
  const float* b1   = (const float*)d_in[25];
  const float* w2   = (const float*)d_in[26];
  const float* b2   = (const float*)d_in[27];
  const float* w3   = (const float*)d_in[28];
  const float* b3   = (const float*)d_in[29];

  const int* src = eidx;
  const int* dst = eidx + E_;

  char* w = (char*)d_ws;
  size_t off = 0;
  auto take = [&](size_t bytes) -> void* {
    void* p = (void*)(w + off);
    off = (off + bytes + 255) & ~(size_t)255;
    return p;
  };
  int*   cnt    = (int*)  take((size_t)N_*4);
  int*   rowptr = (int*)  take((size_t)(N_+1)*4);
  int*   cursor = (int*)  take((size_t)N_*4);
  int*   cols   = (int*)  take((size_t)E_*4);
  float* scal   = (float*)take((size_t)N_*16);
  float* sumlog = (float*)take(256);
  float* bnsum  = (float*)take((size_t)2*H_*4);
  float* vec_e  = (float*)take((size_t)T_*H_*4);
  float* cst_e  = (float*)take((size_t)T_*H_*4);
  unsigned short* BpreT = (unsigned short*)take((size_t)1024*128*2);  // padded [NcPad][KPk]
  unsigned short* W2 = (unsigned short*)take((size_t)T_*80*512*2);
  float* XI     = (float*)take((size_t)N_*T_*H_*4);          // 40 MB
  unsigned short* XJb = (unsigned short*)take((size_t)N_*T_*H_*2);  // 20 MB node-major
  unsigned short* Apost = (unsigned short*)take((size_t)N_*T_*512*2);  // 102 MB node-major
  float* hbuf   = (float*)take((size_t)N_*H_*4);
  float* h2buf  = (float*)take((size_t)N_*H_*4);
  float* xcur   = (float*)take((size_t)N_*H_*4);
  float* gsum   = (float*)take((size_t)B_*H_*4);
  int*   gcnt   = (int*)  take((size_t)B_*4);
  if (off > ws_size) return;   // workspace too small: bail (test fails loudly)

  hipMemsetAsync(cnt,    0, (size_t)N_*4, stream);
  hipMemsetAsync(cursor, 0, (size_t)N_*4, stream);
  hipMemsetAsync(sumlog, 0, 4, stream);
  hipMemsetAsync(gsum,   0, (size_t)B_*H_*4, stream);
  hipMemsetAsync(gcnt,   0, (size_t)B_*4, stream);

  k_count <<<dim3((E_+255)/256), dim3(256), 0, stream>>>(dst, cnt);
  k_scan  <<<dim3(1),            dim3(1024),0, stream>>>(cnt, rowptr);
  k_fill  <<<dim3((E_+255)/256), dim3(256), 0, stream>>>(dst, rowptr, cursor, cols);
  k_sumlog<<<dim3((N_+255)/256), dim3(256), 0, stream>>>(cnt, sumlog);
  k_scal  <<<dim3((N_+255)/256), dim3(256), 0, stream>>>(cnt, sumlog, scal);

  auto layer = [&](const float* xin, int f,
                   const float* ew, const float* eb, const float* pw, const float* pb,
                   const float* qw, const float* qb, const float* lw, const float* lb,
                   const float* bg, const float* bb) {
    const int C   = T_ * f;
    const int KP  = ((5*f + 31) / 32) * 32;  // post per-tower K (f=16:96, f=100:512)
    const int KPk = ((f + 31) / 32) * 32;    // pre K padded (16->32, 100->128)
    const int gN  = (2*C + 127) / 128;       // pre n-blocks
    const int NcPad = gN * 128;
    k_edgevec<<<dim3((C+255)/256), dim3(256), 0, stream>>>(pw, pb, ew, eb, vec_e, cst_e, f, C);
    const int pt = NcPad * KPk;
    k_pack_preT<<<dim3((pt+255)/256), dim3(256), 0, stream>>>(pw, BpreT, f, C, KPk, NcPad);
    const int wtot = T_ * 80 * KP;
    k_pack_w2<<<dim3((wtot+255)/256), dim3(256), 0, stream>>>(qw, W2, f, KP);
    k_mmsplit<<<dim3((N_+127)/128, gN), dim3(256), 0, stream>>>(xin, BpreT, XI, XJb, N_, f, KPk, C);
    k_agg<<<dim3(N_), dim3(256), 0, stream>>>(XI, XJb, rowptr, cols, src, ea, vec_e, cst_e, xin, Apost, f, C, KP);
    k_postmm<<<dim3((N_+127)/128, T_), dim3(256), 0, stream>>>(Apost, W2, scal, qb, hbuf, KP);
    k_gemm<<<dim3((N_+63)/64, (H_+63)/64), dim3(256), 0, stream>>>(hbuf, lw, lb, h2buf, N_, H_, H_);
    hipMemsetAsync(bnsum, 0, (size_t)2*H_*4, stream);
    k_bnsum<<<dim3(128), dim3(256), 0, stream>>>(h2buf, bnsum);
    k_bnapply<<<dim3((unsigned)(((size_t)N_*H_+255)/256)), dim3(256), 0, stream>>>(h2buf, bnsum, bg, bb, xcur);
  };

  layer(x0,   FI_, e0w, e0b, p0w, p0b, q0w, q0b, l0w, l0b, g0, b0);
  layer(xcur, H_,  eLw, eLb, pLw, pLb, qLw, qLb, lLw, lLb, gL, bL);
  layer(xcur, H_,  eLw + H_, eLb + H_,
        pLw + (size_t)T_*3*H_*H_, pLb + T_*H_,
        qLw + (size_t)T_*17*H_*FO_, qLb + T_*FO_,
        lLw + H_*H_, lLb + H_, gL + H_, bL + H_);

  k_pool<<<dim3((N_+PR_-1)/PR_), dim3(256), 0, stream>>>(xcur, batch, gsum);
  k_gcnt<<<dim3((N_+255)/256), dim3(256), 0, stream>>>(batch, gcnt);
  k_mlp <<<dim3(1), dim3(512), 0, stream>>>(gsum, gcnt, w1, b1, w2, b2, w3, b3, (float*)d_out);
}

// Round 10
// 996.756 us; speedup vs baseline: 1.6470x; 1.1865x over previous
//
#include <hip/hip_runtime.h>
#include <hip/hip_bf16.h>
#include <cstddef>

#define N_  20000
#define E_  320000
#define FI_ 16
#define H_  100
#define T_  5
#define FO_ 20
#define B_  50
#define EPSF 1e-5f
#define PR_  200    // k_pool rows per block

typedef __attribute__((ext_vector_type(8))) short short8;
typedef __attribute__((ext_vector_type(4))) float f32x4;

static __device__ __forceinline__ unsigned short f2bf(float x) {
  unsigned int u = __builtin_bit_cast(unsigned int, x);
  unsigned int r = (u + 0x7FFFu + ((u >> 16) & 1u)) >> 16;   // RNE
  return (unsigned short)r;
}
static __device__ __forceinline__ unsigned int packbf(float a, float b) {
  return (unsigned int)f2bf(a) | ((unsigned int)f2bf(b) << 16);
}
static __device__ __forceinline__ float bf2f_lo(unsigned int u) {
  return __builtin_bit_cast(float, (u & 0xFFFFu) << 16);
}
static __device__ __forceinline__ float bf2f_hi(unsigned int u) {
  return __builtin_bit_cast(float, u & 0xFFFF0000u);
}

// ---------------- graph prep ----------------
__global__ void k_count(const int* __restrict__ dst, int* __restrict__ cnt) {
  int e = blockIdx.x * blockDim.x + threadIdx.x;
  if (e < E_) atomicAdd(&cnt[dst[e]], 1);
}

__global__ __launch_bounds__(1024) void k_scan(const int* __restrict__ cnt, int* __restrict__ rowptr) {
  __shared__ int ls[1024];
  const int tid = threadIdx.x;
  int carry = 0;
  for (int start = 0; start < N_; start += 1024) {
    int i = start + tid;
    int v = (i < N_) ? cnt[i] : 0;
    ls[tid] = v;
    __syncthreads();
    for (int off = 1; off < 1024; off <<= 1) {
      int t = (tid >= off) ? ls[tid - off] : 0;
      __syncthreads();
      ls[tid] += t;
      __syncthreads();
    }
    if (i < N_) rowptr[i] = carry + ls[tid] - v;   // exclusive scan
    carry += ls[1023];
    __syncthreads();
  }
  if (tid == 0) rowptr[N_] = carry;
}

// CSR fill: store source id and edge value directly (no edge-id indirection)
__global__ void k_fill(const int* __restrict__ src, const int* __restrict__ dst,
                       const float* __restrict__ ea, const int* __restrict__ rowptr,
                       int* __restrict__ cursor, int* __restrict__ srcs,
                       float* __restrict__ eav) {
  int e = blockIdx.x * blockDim.x + threadIdx.x;
  if (e < E_) {
    int v = dst[e];
    int p = atomicAdd(&cursor[v], 1);
    int pos = rowptr[v] + p;
    srcs[pos] = src[e];
    eav[pos]  = ea[e];
  }
}

__global__ void k_sumlog(const int* __restrict__ cnt, float* __restrict__ sumlog) {
  int i = blockIdx.x * blockDim.x + threadIdx.x;
  float v = (i < N_) ? logf((float)cnt[i] + 1.0f) : 0.0f;
  #pragma unroll
  for (int off = 32; off > 0; off >>= 1) v += __shfl_down(v, off);
  __shared__ float red[4];
  if ((threadIdx.x & 63) == 0) red[threadIdx.x >> 6] = v;
  __syncthreads();
  if (threadIdx.x == 0) atomicAdd(sumlog, red[0] + red[1] + red[2] + red[3]);
}

__global__ void k_scal(const int* __restrict__ cnt, const float* __restrict__ sumlog,
                       float* __restrict__ scal) {
  int i = blockIdx.x * blockDim.x + threadIdx.x;
  if (i >= N_) return;
  float c  = (float)cnt[i];
  float d  = fmaxf(c, 1.0f);
  float ld = logf(d + 1.0f);
  float avg_log = sumlog[0] * (1.0f / (float)N_);
  float avg_lin = (float)E_ / (float)N_;
  scal[i*4+0] = 1.0f;
  scal[i*4+1] = ld / avg_log;
  scal[i*4+2] = avg_log / ld;
  scal[i*4+3] = d / avg_lin;
}

// ---------------- per-layer prep ----------------
__global__ void k_edgevec(const float* __restrict__ pw, const float* __restrict__ pb,
                          const float* __restrict__ ew, const float* __restrict__ eb,
                          float* __restrict__ vec_e, float* __restrict__ cst_e, int f, int C) {
  int c = blockIdx.x * blockDim.x + threadIdx.x;
  if (c >= C) return;
  int t = c / f, g = c - t*f;
  const float* wp = pw + (size_t)t*3*f*f + (size_t)2*f*f + g;
  float v = 0.f, s = 0.f;
  for (int ff = 0; ff < f; ++ff) { float wv = wp[(size_t)ff*f]; v += ew[ff]*wv; s += eb[ff]*wv; }
  vec_e[c] = v;
  cst_e[c] = s + pb[c];
}

// BpreT[c][KPk] bf16, transposed+padded: c<2C from pw (k<f), else 0.
__global__ void k_pack_preT(const float* __restrict__ pw, unsigned short* __restrict__ Bb,
                            int f, int C, int KPk, int NcPad) {
  int tot = NcPad * KPk;
  int idx = blockIdx.x * blockDim.x + threadIdx.x;
  if (idx >= tot) return;
  int k = idx % KPk, c = idx / KPk;
  float v = 0.f;
  if (c < 2*C && k < f) {
    int half = c / C, cc = c - half*C;
    int t = cc / f, g = cc - t*f;
    v = pw[(size_t)t*3*f*f + (size_t)(half*f + k)*f + g];
  }
  Bb[idx] = f2bf(v);
}

// Pack post weights transposed, bf16: W2[t][j=s*20+g][k], k in [0,KP).
__global__ void k_pack_w2(const float* __restrict__ qw, unsigned short* __restrict__ W2,
                          int f, int KP) {
  int tot = T_ * 80 * KP;
  int idx = blockIdx.x * blockDim.x + threadIdx.x;
  if (idx >= tot) return;
  int k = idx % KP;
  int r = idx / KP;
  int j = r % 80;
  int t = r / 80;
  int s = j / 20, g = j - s*20;
  float v = 0.f;
  if (k < 4*f)                 v = qw[((size_t)t*17*f + f + (size_t)s*4*f + k) * FO_ + g];
  else if (k < 5*f && s == 0)  v = qw[((size_t)t*17*f + (k - 4*f)) * FO_ + g];
  W2[idx] = f2bf(v);
}

// ---------------- generic tiled fp32 GEMM (lin layer only) ----------------
__global__ __launch_bounds__(256) void k_gemm(
    const float* __restrict__ A, const float* __restrict__ Bm,
    const float* __restrict__ bias, float* __restrict__ Cm,
    int M, int K, int Nc)
{
  __shared__ __align__(16) float As[16][68];
  __shared__ __align__(16) float Bs[16][64];
  const int tid = threadIdx.x;
  const int bm = blockIdx.x * 64;
  const int bn = blockIdx.y * 64;
  const int mg = tid & 15;
  const int ng = tid >> 4;
  float acc[4][4];
  #pragma unroll
  for (int i = 0; i < 4; ++i)
    #pragma unroll
    for (int j = 0; j < 4; ++j) acc[i][j] = 0.f;

  for (int k0 = 0; k0 < K; k0 += 16) {
    {
      int kk = tid & 15, mr = tid >> 4;
      #pragma unroll
      for (int p = 0; p < 4; ++p) {
        int m = mr + p*16;
        int gm = bm + m, gk = k0 + kk;
        As[kk][m] = (gm < M && gk < K) ? A[(size_t)gm*K + gk] : 0.f;
      }
      int nn = tid & 63, kr = tid >> 6;
      #pragma unroll
      for (int p = 0; p < 4; ++p) {
        int k = kr + p*4;
        int gk = k0 + k, gn = bn + nn;
        Bs[k][nn] = (gk < K && gn < Nc) ? Bm[(size_t)gk*Nc + gn] : 0.f;
      }
    }
    __syncthreads();
    #pragma unroll
    for (int kk = 0; kk < 16; ++kk) {
      const float4 a = *(const float4*)&As[kk][mg*4];
      const float4 b = *(const float4*)&Bs[kk][ng*4];
      const float av[4] = {a.x, a.y, a.z, a.w};
      const float bv[4] = {b.x, b.y, b.z, b.w};
      #pragma unroll
      for (int i = 0; i < 4; ++i)
        #pragma unroll
        for (int j = 0; j < 4; ++j)
          acc[i][j] = fmaf(av[i], bv[j], acc[i][j]);
    }
    __syncthreads();
  }
  #pragma unroll
  for (int i = 0; i < 4; ++i) {
    int gm = bm + mg*4 + i;
    if (gm >= M) continue;
    #pragma unroll
    for (int j = 0; j < 4; ++j) {
      int gn = bn + ng*4 + j;
      if (gn < Nc) {
        float v = acc[i][j];
        if (bias) v += bias[gn];
        Cm[(size_t)gm*Nc + gn] = v;
      }
    }
  }
}

// ---------------- pre-GEMM via MFMA, split epilogue ----------------
__global__ __launch_bounds__(256) void k_mmsplit(
    const float* __restrict__ A, const unsigned short* __restrict__ Bb,
    float* __restrict__ XI, unsigned short* __restrict__ XJb,
    int M, int K, int KPk, int split)
{
  const int m0 = blockIdx.x * 128;
  const int bn = blockIdx.y * 128;
  const int Nc = 2 * split;
  const int tid = threadIdx.x;
  const int w = tid >> 6, lane = tid & 63;
  const int rl = lane & 15, kq = lane >> 4;
  __shared__ __align__(16) unsigned short As[128*40];
  __shared__ __align__(16) unsigned short Bs[128*40];
  f32x4 acc[2][8];
  #pragma unroll
  for (int mf = 0; mf < 2; ++mf)
    #pragma unroll
    for (int nf = 0; nf < 8; ++nf) acc[mf][nf] = (f32x4){0.f,0.f,0.f,0.f};

  for (int k0 = 0; k0 < KPk; k0 += 32) {
    __syncthreads();
    // stage A: 128 rows x 32 k, fp32 -> bf16 (512 chunks of 8)
    #pragma unroll
    for (int p = 0; p < 2; ++p) {
      int idx = tid + p*256;
      int row = idx >> 2, q = idx & 3;
      int gm = m0 + row;
      int gk = k0 + q*8;
      unsigned int d0 = 0, d1 = 0, d2 = 0, d3 = 0;
      if (gm < M) {
        if (gk + 8 <= K) {
          const float4 v0 = *(const float4*)&A[(size_t)gm*K + gk];
          const float4 v1 = *(const float4*)&A[(size_t)gm*K + gk + 4];
          d0 = packbf(v0.x, v0.y); d1 = packbf(v0.z, v0.w);
          d2 = packbf(v1.x, v1.y); d3 = packbf(v1.z, v1.w);
        } else if (gk < K) {
          float tmp[8];
          #pragma unroll
          for (int e = 0; e < 8; ++e) tmp[e] = (gk + e < K) ? A[(size_t)gm*K + gk + e] : 0.f;
          d0 = packbf(tmp[0], tmp[1]); d1 = packbf(tmp[2], tmp[3]);
          d2 = packbf(tmp[4], tmp[5]); d3 = packbf(tmp[6], tmp[7]);
        }
      }
      uint4 dv = {d0, d1, d2, d3};
      *(uint4*)&As[row*40 + q*8] = dv;
    }
    // stage B: 128 cols x 32 k (padded buffer -> no bounds)
    #pragma unroll
    for (int p = 0; p < 2; ++p) {
      int idx = tid + p*256;
      int j = idx >> 2, q = idx & 3;
      uint4 v = *(const uint4*)&Bb[((size_t)(bn + j))*KPk + k0 + q*8];
      *(uint4*)&Bs[j*40 + q*8] = v;
    }
    __syncthreads();
    short8 af[2], bf[8];
    #pragma unroll
    for (int mf = 0; mf < 2; ++mf)
      af[mf] = *(const short8*)&As[(w*32 + mf*16 + rl)*40 + kq*8];
    #pragma unroll
    for (int nf = 0; nf < 8; ++nf)
      bf[nf] = *(const short8*)&Bs[(nf*16 + rl)*40 + kq*8];
    #pragma unroll
    for (int mf = 0; mf < 2; ++mf)
      #pragma unroll
      for (int nf = 0; nf < 8; ++nf)
        acc[mf][nf] = __builtin_amdgcn_mfma_f32_16x16x32_bf16(af[mf], bf[nf], acc[mf][nf], 0, 0, 0);
  }
  // epilogue: C/D layout (m89): col = lane&15, row = (lane>>4)*4 + r
  #pragma unroll
  for (int mf = 0; mf < 2; ++mf)
    #pragma unroll
    for (int nf = 0; nf < 8; ++nf)
      #pragma unroll
      for (int r = 0; r < 4; ++r) {
        int gm = m0 + w*32 + mf*16 + kq*4 + r;
        int gn = bn + nf*16 + rl;
        if (gm < M && gn < Nc) {
          float v = acc[mf][nf][r];
          if (gn < split) XI[(size_t)gm*split + gn] = v;
          else            XJb[(size_t)gm*split + (gn - split)] = f2bf(v);
        }
      }
}

// ---------------- per-node aggregation -> bf16 Apost rows ----------------
// Direct (srcs,eav) CSR streams + 4-way edge unroll: 4 gathers in flight.
__global__ __launch_bounds__(256) void k_agg(
    const float* __restrict__ XI, const unsigned short* __restrict__ XJb,
    const int* __restrict__ rowptr, const int* __restrict__ srcs,
    const float* __restrict__ eav, const float* __restrict__ vec_e,
    const float* __restrict__ cst_e, const float* __restrict__ xin,
    unsigned short* __restrict__ Apost, int f, int C, int KP)
{
  __shared__ float vsh[512];
  const int tid = threadIdx.x;
  for (int c = tid; c < C; c += 256) vsh[c] = vec_e[c];
  __syncthreads();
  const int v = blockIdx.x;
  const int start = rowptr[v], end = rowptr[v+1];
  const int half = C >> 1;                 // C even (T*f, f even)
  const bool act = (tid < half);
  const float v0 = act ? vsh[tid*2]   : 0.f;
  const float v1 = act ? vsh[tid*2+1] : 0.f;
  const unsigned int* xj = (const unsigned int*)XJb;
  float s10 = 0.f, s11 = 0.f, s20 = 0.f, s21 = 0.f;
  float mn0 = 1e30f, mn1 = 1e30f, mx0 = -1e30f, mx1 = -1e30f;

  int p = start;
  for (; p + 4 <= end; p += 4) {
    int   s0 = srcs[p],   s1 = srcs[p+1],   s2 = srcs[p+2],   s3 = srcs[p+3];
    float a0 = eav[p],    a1 = eav[p+1],    a2 = eav[p+2],    a3 = eav[p+3];
    if (act) {
      unsigned int u0 = xj[(size_t)s0*half + tid];
      unsigned int u1 = xj[(size_t)s1*half + tid];
      unsigned int u2 = xj[(size_t)s2*half + tid];
      unsigned int u3 = xj[(size_t)s3*half + tid];
      float y;
      y = fmaf(a0, v0, bf2f_lo(u0)); s10 += y; s20 = fmaf(y,y,s20); mn0 = fminf(mn0,y); mx0 = fmaxf(mx0,y);
      y = fmaf(a0, v1, bf2f_hi(u0)); s11 += y; s21 = fmaf(y,y,s21); mn1 = fminf(mn1,y); mx1 = fmaxf(mx1,y);
      y = fmaf(a1, v0, bf2f_lo(u1)); s10 += y; s20 = fmaf(y,y,s20); mn0 = fminf(mn0,y); mx0 = fmaxf(mx0,y);
      y = fmaf(a1, v1, bf2f_hi(u1)); s11 += y; s21 = fmaf(y,y,s21); mn1 = fminf(mn1,y); mx1 = fmaxf(mx1,y);
      y = fmaf(a2, v0, bf2f_lo(u2)); s10 += y; s20 = fmaf(y,y,s20); mn0 = fminf(mn0,y); mx0 = fmaxf(mx0,y);
      y = fmaf(a2, v1, bf2f_hi(u2)); s11 += y; s21 = fmaf(y,y,s21); mn1 = fminf(mn1,y); mx1 = fmaxf(mx1,y);
      y = fmaf(a3, v0, bf2f_lo(u3)); s10 += y; s20 = fmaf(y,y,s20); mn0 = fminf(mn0,y); mx0 = fmaxf(mx0,y);
      y = fmaf(a3, v1, bf2f_hi(u3)); s11 += y; s21 = fmaf(y,y,s21); mn1 = fminf(mn1,y); mx1 = fmaxf(mx1,y);
    }
  }
  for (; p < end; ++p) {
    int s = srcs[p];
    float a = eav[p];
    if (act) {
      unsigned int u = xj[(size_t)s*half + tid];
      float y0 = fmaf(a, v0, bf2f_lo(u));
      float y1 = fmaf(a, v1, bf2f_hi(u));
      s10 += y0; s20 = fmaf(y0, y0, s20);
      s11 += y1; s21 = fmaf(y1, y1, s21);
      mn0 = fminf(mn0, y0); mx0 = fmaxf(mx0, y0);
      mn1 = fminf(mn1, y1); mx1 = fmaxf(mx1, y1);
    }
  }

  const int dcnt = end - start;
  if (act) {
    int c0 = tid*2;
    int t = c0 / f, ff = c0 - t*f;          // pair never straddles towers (f even)
    float base0 = XI[(size_t)v*C + c0]     + cst_e[c0];
    float base1 = XI[(size_t)v*C + c0 + 1] + cst_e[c0 + 1];
    float me0, sd0, lo0, hi0, me1, sd1, lo1, hi1;
    if (dcnt > 0) {
      float inv = 1.0f / (float)dcnt;
      float m10 = s10 * inv, m11 = s11 * inv;
      me0 = base0 + m10; me1 = base1 + m11;
      sd0 = sqrtf(fmaxf(s20*inv - m10*m10, 0.f) + EPSF);
      sd1 = sqrtf(fmaxf(s21*inv - m11*m11, 0.f) + EPSF);
      lo0 = base0 + mn0; hi0 = base0 + mx0;
      lo1 = base1 + mn1; hi1 = base1 + mx1;
    } else {
      me0 = me1 = lo0 = lo1 = hi0 = hi1 = 0.f;
      sd0 = sd1 = sqrtf(EPSF);
    }
    unsigned short* o = Apost + ((size_t)v * T_ + t) * KP + ff;
    o[0]     = f2bf(me0); o[1]       = f2bf(me1);
    o[f]     = f2bf(lo0); o[f+1]     = f2bf(lo1);
    o[2*f]   = f2bf(hi0); o[2*f+1]   = f2bf(hi1);
    o[3*f]   = f2bf(sd0); o[3*f+1]   = f2bf(sd1);
  }
  // x copy (shared by all towers) + zero pad
  const int rem = KP - 4*f;
  for (int idx = tid; idx < T_*rem; idx += 256) {
    int t = idx / rem, kk = idx - t*rem;
    int k = 4*f + kk;
    unsigned short val = 0;
    if (k < 5*f) val = f2bf(xin[(size_t)v*f + (k - 4*f)]);
    Apost[((size_t)v * T_ + t) * KP + k] = val;
  }
}

// ---------------- post GEMM via MFMA + fused scaler combine ----------------
__global__ __launch_bounds__(256) void k_postmm(
    const unsigned short* __restrict__ Apost, const unsigned short* __restrict__ W2,
    const float* __restrict__ scal, const float* __restrict__ qb,
    float* __restrict__ h, int KP)
{
  const int t    = blockIdx.y;
  const int m0   = blockIdx.x * 128;
  const int tid  = threadIdx.x;
  const int w    = tid >> 6;
  const int lane = tid & 63;
  const int rl   = lane & 15;     // frag row/col
  const int kq   = lane >> 4;     // k-quarter 0..3
  __shared__ __align__(16) unsigned char smem[128*84*4];   // 43008 B, reused
  unsigned short* As = (unsigned short*)smem;              // [128][40]
  unsigned short* Bs = As + 128*40;                        // [80][40]
  f32x4 acc[2][5];
  #pragma unroll
  for (int mf = 0; mf < 2; ++mf)
    #pragma unroll
    for (int nf = 0; nf < 5; ++nf) acc[mf][nf] = (f32x4){0.f,0.f,0.f,0.f};

  const unsigned short* wt = W2 + (size_t)t * 80 * KP;

  for (int k0 = 0; k0 < KP; k0 += 32) {
    __syncthreads();
    #pragma unroll
    for (int p = 0; p < 2; ++p) {
      int idx = tid + p*256;
      int row = idx >> 2, q = idx & 3;
      int gm = m0 + row;
      uint4 v = {0u,0u,0u,0u};
      if (gm < N_) v = *(const uint4*)&Apost[((size_t)gm*T_ + t)*KP + k0 + q*8];
      *(uint4*)&As[row*40 + q*8] = v;
    }
    #pragma unroll
    for (int p = 0; p < 2; ++p) {
      int idx = tid + p*256;
      if (idx < 320) {
        int j = idx >> 2, q = idx & 3;
        uint4 v = *(const uint4*)&wt[(size_t)j*KP + k0 + q*8];
        *(uint4*)&Bs[j*40 + q*8] = v;
      }
    }
    __syncthreads();
    short8 af[2], bf[5];
    #pragma unroll
    for (int mf = 0; mf < 2; ++mf)
      af[mf] = *(const short8*)&As[(w*32 + mf*16 + rl)*40 + kq*8];
    #pragma unroll
    for (int nf = 0; nf < 5; ++nf)
      bf[nf] = *(const short8*)&Bs[(nf*16 + rl)*40 + kq*8];
    #pragma unroll
    for (int mf = 0; mf < 2; ++mf)
      #pragma unroll
      for (int nf = 0; nf < 5; ++nf)
        acc[mf][nf] = __builtin_amdgcn_mfma_f32_16x16x32_bf16(af[mf], bf[nf], acc[mf][nf], 0, 0, 0);
  }
  // epilogue: P tile to LDS (C/D layout m89: col=lane&15, row=(lane>>4)*4+r)
  __syncthreads();
  float (*Pl)[84] = (float (*)[84])smem;
  #pragma unroll
  for (int mf = 0; mf < 2; ++mf)
    #pragma unroll
    for (int nf = 0; nf < 5; ++nf)
      #pragma unroll
      for (int r = 0; r < 4; ++r)
        Pl[w*32 + mf*16 + kq*4 + r][nf*16 + rl] = acc[mf][nf][r];
  __syncthreads();
  for (int idx = tid; idx < 128*FO_; idx += 256) {
    int row = idx / FO_, g = idx - row*FO_;
    int n = m0 + row;
    if (n < N_) {
      const float* p = Pl[row];
      float4 sc = *(const float4*)&scal[n*4];
      h[(size_t)n*(T_*FO_) + t*FO_ + g] =
        p[g] + sc.y*p[20+g] + sc.z*p[40+g] + sc.w*p[60+g] + qb[t*FO_+g];
    }
  }
}

// ---------------- batch norm ----------------
__global__ __launch_bounds__(256) void k_bnsum(const float* __restrict__ h2, float* __restrict__ bnsum) {
  const int tid  = threadIdx.x;
  const int c    = tid & 127;
  const int half = tid >> 7;
  if (c >= H_) return;
  float s = 0.f, s2 = 0.f;
  for (int r = blockIdx.x * 2 + half; r < N_; r += 256) {
    float v = h2[(size_t)r * H_ + c];
    s += v; s2 = fmaf(v, v, s2);
  }
  atomicAdd(&bnsum[c], s);
  atomicAdd(&bnsum[H_ + c], s2);
}

__global__ void k_bnapply(const float* __restrict__ h2, const float* __restrict__ bnsum,
                          const float* __restrict__ gam, const float* __restrict__ bet,
                          float* __restrict__ out) {
  size_t i = (size_t)blockIdx.x * blockDim.x + threadIdx.x;
  if (i >= (size_t)N_*H_) return;
  int c = (int)(i % H_);
  const float invn = 1.0f / (float)N_;
  float mu  = bnsum[c] * invn;
  float var = bnsum[H_ + c] * invn - mu*mu;
  float y = (h2[i] - mu) * rsqrtf(var + EPSF) * gam[c] + bet[c];
  out[i] = fmaxf(y, 0.f);
}

// ---------------- pooling + MLP ----------------
__global__ __launch_bounds__(256) void k_pool(const float* __restrict__ xc, const int* __restrict__ batch,
                                              float* __restrict__ gsum) {
  __shared__ float Pl[B_][H_];
  const int tid = threadIdx.x;
  for (int i = tid; i < B_*H_; i += 256) Pl[i / H_][i % H_] = 0.f;
  __syncthreads();
  const int r0 = blockIdx.x * PR_;
  const int rend = (r0 + PR_ < N_) ? r0 + PR_ : N_;
  const int nel = (rend - r0) * H_;
  for (int idx = tid; idx < nel; idx += 256) {
    int rr = idx / H_, c = idx - rr*H_;
    int n = r0 + rr;
    atomicAdd(&Pl[batch[n]][c], xc[(size_t)n*H_ + c]);
  }
  __syncthreads();
  const int blo = batch[r0], bhi = batch[rend-1];
  const int nb = (bhi - blo + 1) * H_;
  for (int idx = tid; idx < nb; idx += 256) {
    int b = blo + idx / H_, c = idx % H_;
    atomicAdd(&gsum[(size_t)b*H_ + c], Pl[b][c]);
  }
}

__global__ void k_gcnt(const int* __restrict__ batch, int* __restrict__ gcnt) {
  int n = blockIdx.x * blockDim.x + threadIdx.x;
  if (n < N_) atomicAdd(&gcnt[batch[n]], 1);
}

__global__ __launch_bounds__(512) void k_mlp(
    const float* __restrict__ gsum, const int* __restrict__ gcnt,
    const float* __restrict__ w1, const float* __restrict__ b1,
    const float* __restrict__ w2, const float* __restrict__ b2,
    const float* __restrict__ w3, const float* __restrict__ b3,
    float* __restrict__ out)
{
  __shared__ float G[B_][H_];
  __shared__ float A1[B_][50];
  __shared__ float A2[B_][25];
  const int tid = threadIdx.x;
  for (int i = tid; i < B_*H_; i += 512) {
    int r = i / H_;
    G[r][i - r*H_] = gsum[i] / fmaxf((float)gcnt[r], 1.0f);
  }
  __syncthreads();
  for (int i = tid; i < B_*50; i += 512) {
    int r = i / 50, c = i - r*50;
    float a = b1[c];
    for (int k = 0; k < H_; ++k) a = fmaf(G[r][k], w1[k*50 + c], a);
    A1[r][c] = fmaxf(a, 0.f);
  }
  __syncthreads();
  for (int i = tid; i < B_*25; i += 512) {
    int r = i / 25, c = i - r*25;
    float a = b2[c];
    for (int k = 0; k < 50; ++k) a = fmaf(A1[r][k], w2[k*25 + c], a);
    A2[r][c] = fmaxf(a, 0.f);
  }
  __syncthreads();
  for (int i = tid; i < B_; i += 512) {
    float a = b3[0];
    for (int k = 0; k < 25; ++k) a = fmaf(A2[i][k], w3[k], a);
    out[i] = a;   // float32 output — reference output dtype is f32
  }
}

// ---------------- host ----------------
extern "C" void kernel_launch(void* const* d_in, const int* in_sizes, int n_in,
                              void* d_out, int out_size, void* d_ws, size_t ws_size,
                              hipStream_t stream)
{
  (void)in_sizes; (void)n_in; (void)out_size;
  const float* x0   = (const float*)d_in[0];
  const int*   eidx = (const int*)  d_in[1];
  const float* ea   = (const float*)d_in[2];
  const int*   batch= (const int*)  d_in[3];
  const float* e0w  = (const float*)d_in[4];
  const float* e0b  = (const float*)d_in[5];
  const float* p0w  = (const float*)d_in[6];
  const float* p0b  = (const float*)d_in[7];
  const float* q0w  = (const float*)d_in[8];
  const float* q0b  = (const float*)d_in[9];
  const float* l0w  = (const float*)d_in[10];
  const float* l0b  = (const float*)d_in[11];
  const float* g0   = (const float*)d_in[12];
  const float* b0   = (const float*)d_in[13];
  const float* eLw  = (const float*)d_in[14];
  const float* eLb  = (const float*)d_in[15];
  const float* pLw  = (const float*)d_in[16];
  const float* pLb  = (const float*)d_in[17];
  const float* qLw  = (const float*)d_in[18];
  const float* qLb  = (const float*)d_in[19];
  const float* lLw  = (const float*)d_in[20];
  const float* lLb  = (const float*)d_in[21];
  const float* gL   = (const float*)d_in[22];
  const float* bL   = (const float*)d_in[23];
  const float* w1   = (const float*)d_in[24];
  const float* b1   = (const float*)d_in[25];
  const float* w2   = (const float*)d_in[26];
  const float* b2   = (const float*)d_in[27];
  const float* w3   = (const float*)d_in[28];
  const float* b3   = (const float*)d_in[29];

  const int* src = eidx;
  const int* dst = eidx + E_;

  char* w = (char*)d_ws;
  size_t off = 0;
  auto take = [&](size_t bytes) -> void* {
    void* p = (void*)(w + off);
    off = (off + bytes + 255) & ~(size_t)255;
    return p;
  };
  int*   cnt    = (int*)  take((size_t)N_*4);
  int*   rowptr = (int*)  take((size_t)(N_+1)*4);
  int*   cursor = (int*)  take((size_t)N_*4);
  int*   srcs   = (int*)  take((size_t)E_*4);
  float* eav    = (float*)take((size_t)E_*4);
  float* scal   = (float*)take((size_t)N_*16);
  float* sumlog = (float*)take(256);
  float* bnsum  = (float*)take((size_t)2*H_*4);
  float* vec_e  = (float*)take((size_t)T_*H_*4);
  float* cst_e  = (float*)take((size_t)T_*H_*4);
  unsigned short* BpreT = (unsigned short*)take((size_t)1024*128*2);  // padded [NcPad][KPk]
  unsigned short* W2 = (unsigned short*)take((size_t)T_*80*512*2);
  float* XI     = (float*)take((size_t)N_*T_*H_*4);          // 40 MB
  unsigned short* XJb = (unsigned short*)take((size_t)N_*T_*H_*2);  // 20 MB node-major
  unsigned short* Apost = (unsigned short*)take((size_t)N_*T_*512*2);  // 102 MB node-major
  float* hbuf   = (float*)take((size_t)N_*H_*4);
  float* h2buf  = (float*)take((size_t)N_*H_*4);
  float* xcur   = (float*)take((size_t)N_*H_*4);
  float* gsum   = (float*)take((size_t)B_*H_*4);
  int*   gcnt   = (int*)  take((size_t)B_*4);
  if (off > ws_size) return;   // workspace too small: bail (test fails loudly)

  hipMemsetAsync(cnt,    0, (size_t)N_*4, stream);
  hipMemsetAsync(cursor, 0, (size_t)N_*4, stream);
  hipMemsetAsync(sumlog, 0, 4, stream);
  hipMemsetAsync(gsum,   0, (size_t)B_*H_*4, stream);
  hipMemsetAsync(gcnt,   0, (size_t)B_*4, stream);

  k_count <<<dim3((E_+255)/256), dim3(256), 0, stream>>>(dst, cnt);
  k_scan  <<<dim3(1),            dim3(1024),0, stream>>>(cnt, rowptr);
  k_fill  <<<dim3((E_+255)/256), dim3(256), 0, stream>>>(src, dst, ea, rowptr, cursor, srcs, eav);
  k_sumlog<<<dim3((N_+255)/256), dim3(256), 0, stream>>>(cnt, sumlog);
  k_scal  <<<dim3((N_+255)/256), dim3(256), 0, stream>>>(cnt, sumlog, scal);

  auto layer = [&](const float* xin, int f,
                   const float* ew, const float* eb, const float* pw, const float* pb,
                   const float* qw, const float* qb, const float* lw, const float* lb,
                   const float* bg, const float* bb) {
    const int C   = T_ * f;
    const int KP  = ((5*f + 31) / 32) * 32;  // post per-tower K (f=16:96, f=100:512)
    const int KPk = ((f + 31) / 32) * 32;    // pre K padded (16->32, 100->128)
    const int gN  = (2*C + 127) / 128;       // pre n-blocks
    const int NcPad = gN * 128;
    k_edgevec<<<dim3((C+255)/256), dim3(256), 0, stream>>>(pw, pb, ew, eb, vec_e, cst_e, f, C);
    const int pt = NcPad * KPk;
    k_pack_preT<<<dim3((pt+255)/256), dim3(256), 0, stream>>>(pw, BpreT, f, C, KPk, NcPad);
    const int wtot = T_ * 80 * KP;
    k_pack_w2<<<dim3((wtot+255)/256), dim3(256), 0, stream>>>(qw, W2, f, KP);
    k_mmsplit<<<dim3((N_+127)/128, gN), dim3(256), 0, stream>>>(xin, BpreT, XI, XJb, N_, f, KPk, C);
    k_agg<<<dim3(N_), dim3(256), 0, stream>>>(XI, XJb, rowptr, srcs, eav, vec_e, cst_e, xin, Apost, f, C, KP);
    k_postmm<<<dim3((N_+127)/128, T_), dim3(256), 0, stream>>>(Apost, W2, scal, qb, hbuf, KP);
    k_gemm<<<dim3((N_+63)/64, (H_+63)/64), dim3(256), 0, stream>>>(hbuf, lw, lb, h2buf, N_, H_, H_);
    hipMemsetAsync(bnsum, 0, (size_t)2*H_*4, stream);
    k_bnsum<<<dim3(128), dim3(256), 0, stream>>>(h2buf, bnsum);
    k_bnapply<<<dim3((unsigned)(((size_t)N_*H_+255)/256)), dim3(256), 0, stream>>>(h2buf, bnsum, bg, bb, xcur);
  };

  layer(x0,   FI_, e0w, e0b, p0w, p0b, q0w, q0b, l0w, l0b, g0, b0);
  layer(xcur, H_,  eLw, eLb, pLw, pLb, qLw, qLb, lLw, lLb, gL, bL);
  layer(xcur, H_,  eLw + H_, eLb + H_,
        pLw + (size_t)T_*3*H_*H_, pLb + T_*H_,
        qLw + (size_t)T_*17*H_*FO_, qLb + T_*FO_,
        lLw + H_*H_, lLb + H_, gL + H_, bL + H_);

  k_pool<<<dim3((N_+PR_-1)/PR_), dim3(256), 0, stream>>>(xcur, batch, gsum);
  k_gcnt<<<dim3((N_+255)/256), dim3(256), 0, stream>>>(batch, gcnt);
  k_mlp <<<dim3(1), dim3(512), 0, stream>>>(gsum, gcnt, w1, b1, w2, b2, w3, b3, (float*)d_out);
}

// Round 11
// 895.577 us; speedup vs baseline: 1.8330x; 1.1130x over previous
//
#include <hip/hip_runtime.h>
#include <hip/hip_bf16.h>
#include <cstddef>

#define N_  20000
#define E_  320000
#define FI_ 16
#define H_  100
#define T_  5
#define FO_ 20
#define B_  50
#define EPSF 1e-5f
#define PR_  200    // k_pool rows per block

typedef __attribute__((ext_vector_type(8))) short short8;
typedef __attribute__((ext_vector_type(4))) float f32x4;

static __device__ __forceinline__ unsigned short f2bf(float x) {
  unsigned int u = __builtin_bit_cast(unsigned int, x);
  unsigned int r = (u + 0x7FFFu + ((u >> 16) & 1u)) >> 16;   // RNE
  return (unsigned short)r;
}
static __device__ __forceinline__ unsigned int packbf(float a, float b) {
  return (unsigned int)f2bf(a) | ((unsigned int)f2bf(b) << 16);
}
static __device__ __forceinline__ float bf2f_lo(unsigned int u) {
  return __builtin_bit_cast(float, (u & 0xFFFFu) << 16);
}
static __device__ __forceinline__ float bf2f_hi(unsigned int u) {
  return __builtin_bit_cast(float, u & 0xFFFF0000u);
}

// ---------------- graph prep ----------------
__global__ void k_count(const int* __restrict__ dst, int* __restrict__ cnt) {
  int e = blockIdx.x * blockDim.x + threadIdx.x;
  if (e < E_) atomicAdd(&cnt[dst[e]], 1);
}

__global__ __launch_bounds__(1024) void k_scan(const int* __restrict__ cnt, int* __restrict__ rowptr) {
  __shared__ int ls[1024];
  const int tid = threadIdx.x;
  int carry = 0;
  for (int start = 0; start < N_; start += 1024) {
    int i = start + tid;
    int v = (i < N_) ? cnt[i] : 0;
    ls[tid] = v;
    __syncthreads();
    for (int off = 1; off < 1024; off <<= 1) {
      int t = (tid >= off) ? ls[tid - off] : 0;
      __syncthreads();
      ls[tid] += t;
      __syncthreads();
    }
    if (i < N_) rowptr[i] = carry + ls[tid] - v;   // exclusive scan
    carry += ls[1023];
    __syncthreads();
  }
  if (tid == 0) rowptr[N_] = carry;
}

// CSR fill: store source id and edge value directly (no edge-id indirection)
__global__ void k_fill(const int* __restrict__ src, const int* __restrict__ dst,
                       const float* __restrict__ ea, const int* __restrict__ rowptr,
                       int* __restrict__ cursor, int* __restrict__ srcs,
                       float* __restrict__ eav) {
  int e = blockIdx.x * blockDim.x + threadIdx.x;
  if (e < E_) {
    int v = dst[e];
    int p = atomicAdd(&cursor[v], 1);
    int pos = rowptr[v] + p;
    srcs[pos] = src[e];
    eav[pos]  = ea[e];
  }
}

__global__ void k_sumlog(const int* __restrict__ cnt, float* __restrict__ sumlog) {
  int i = blockIdx.x * blockDim.x + threadIdx.x;
  float v = (i < N_) ? logf((float)cnt[i] + 1.0f) : 0.0f;
  #pragma unroll
  for (int off = 32; off > 0; off >>= 1) v += __shfl_down(v, off);
  __shared__ float red[4];
  if ((threadIdx.x & 63) == 0) red[threadIdx.x >> 6] = v;
  __syncthreads();
  if (threadIdx.x == 0) atomicAdd(sumlog, red[0] + red[1] + red[2] + red[3]);
}

__global__ void k_scal(const int* __restrict__ cnt, const float* __restrict__ sumlog,
                       float* __restrict__ scal) {
  int i = blockIdx.x * blockDim.x + threadIdx.x;
  if (i >= N_) return;
  float c  = (float)cnt[i];
  float d  = fmaxf(c, 1.0f);
  float ld = logf(d + 1.0f);
  float avg_log = sumlog[0] * (1.0f / (float)N_);
  float avg_lin = (float)E_ / (float)N_;
  scal[i*4+0] = 1.0f;
  scal[i*4+1] = ld / avg_log;
  scal[i*4+2] = avg_log / ld;
  scal[i*4+3] = d / avg_lin;
}

// ---------------- per-layer prep ----------------
__global__ void k_edgevec(const float* __restrict__ pw, const float* __restrict__ pb,
                          const float* __restrict__ ew, const float* __restrict__ eb,
                          float* __restrict__ vec_e, float* __restrict__ cst_e, int f, int C) {
  int c = blockIdx.x * blockDim.x + threadIdx.x;
  if (c >= C) return;
  int t = c / f, g = c - t*f;
  const float* wp = pw + (size_t)t*3*f*f + (size_t)2*f*f + g;
  float v = 0.f, s = 0.f;
  for (int ff = 0; ff < f; ++ff) { float wv = wp[(size_t)ff*f]; v += ew[ff]*wv; s += eb[ff]*wv; }
  vec_e[c] = v;
  cst_e[c] = s + pb[c];
}

// BpreT[c][KPk] bf16, transposed+padded: c<2C from pw (k<f), else 0.
__global__ void k_pack_preT(const float* __restrict__ pw, unsigned short* __restrict__ Bb,
                            int f, int C, int KPk, int NcPad) {
  int tot = NcPad * KPk;
  int idx = blockIdx.x * blockDim.x + threadIdx.x;
  if (idx >= tot) return;
  int k = idx % KPk, c = idx / KPk;
  float v = 0.f;
  if (c < 2*C && k < f) {
    int half = c / C, cc = c - half*C;
    int t = cc / f, g = cc - t*f;
    v = pw[(size_t)t*3*f*f + (size_t)(half*f + k)*f + g];
  }
  Bb[idx] = f2bf(v);
}

// Pack post weights transposed, bf16: W2[t][j=s*20+g][k], k in [0,KP).
__global__ void k_pack_w2(const float* __restrict__ qw, unsigned short* __restrict__ W2,
                          int f, int KP) {
  int tot = T_ * 80 * KP;
  int idx = blockIdx.x * blockDim.x + threadIdx.x;
  if (idx >= tot) return;
  int k = idx % KP;
  int r = idx / KP;
  int j = r % 80;
  int t = r / 80;
  int s = j / 20, g = j - s*20;
  float v = 0.f;
  if (k < 4*f)                 v = qw[((size_t)t*17*f + f + (size_t)s*4*f + k) * FO_ + g];
  else if (k < 5*f && s == 0)  v = qw[((size_t)t*17*f + (k - 4*f)) * FO_ + g];
  W2[idx] = f2bf(v);
}

// ---------------- generic tiled fp32 GEMM (lin layer only) ----------------
__global__ __launch_bounds__(256) void k_gemm(
    const float* __restrict__ A, const float* __restrict__ Bm,
    const float* __restrict__ bias, float* __restrict__ Cm,
    int M, int K, int Nc)
{
  __shared__ __align__(16) float As[16][68];
  __shared__ __align__(16) float Bs[16][64];
  const int tid = threadIdx.x;
  const int bm = blockIdx.x * 64;
  const int bn = blockIdx.y * 64;
  const int mg = tid & 15;
  const int ng = tid >> 4;
  float acc[4][4];
  #pragma unroll
  for (int i = 0; i < 4; ++i)
    #pragma unroll
    for (int j = 0; j < 4; ++j) acc[i][j] = 0.f;

  for (int k0 = 0; k0 < K; k0 += 16) {
    {
      int kk = tid & 15, mr = tid >> 4;
      #pragma unroll
      for (int p = 0; p < 4; ++p) {
        int m = mr + p*16;
        int gm = bm + m, gk = k0 + kk;
        As[kk][m] = (gm < M && gk < K) ? A[(size_t)gm*K + gk] : 0.f;
      }
      int nn = tid & 63, kr = tid >> 6;
      #pragma unroll
      for (int p = 0; p < 4; ++p) {
        int k = kr + p*4;
        int gk = k0 + k, gn = bn + nn;
        Bs[k][nn] = (gk < K && gn < Nc) ? Bm[(size_t)gk*Nc + gn] : 0.f;
      }
    }
    __syncthreads();
    #pragma unroll
    for (int kk = 0; kk < 16; ++kk) {
      const float4 a = *(const float4*)&As[kk][mg*4];
      const float4 b = *(const float4*)&Bs[kk][ng*4];
      const float av[4] = {a.x, a.y, a.z, a.w};
      const float bv[4] = {b.x, b.y, b.z, b.w};
      #pragma unroll
      for (int i = 0; i < 4; ++i)
        #pragma unroll
        for (int j = 0; j < 4; ++j)
          acc[i][j] = fmaf(av[i], bv[j], acc[i][j]);
    }
    __syncthreads();
  }
  #pragma unroll
  for (int i = 0; i < 4; ++i) {
    int gm = bm + mg*4 + i;
    if (gm >= M) continue;
    #pragma unroll
    for (int j = 0; j < 4; ++j) {
      int gn = bn + ng*4 + j;
      if (gn < Nc) {
        float v = acc[i][j];
        if (bias) v += bias[gn];
        Cm[(size_t)gm*Nc + gn] = v;
      }
    }
  }
}

// ---------------- pre-GEMM via MFMA, split epilogue ----------------
__global__ __launch_bounds__(256) void k_mmsplit(
    const float* __restrict__ A, const unsigned short* __restrict__ Bb,
    float* __restrict__ XI, unsigned short* __restrict__ XJb,
    int M, int K, int KPk, int split)
{
  const int m0 = blockIdx.x * 128;
  const int bn = blockIdx.y * 128;
  const int Nc = 2 * split;
  const int tid = threadIdx.x;
  const int w = tid >> 6, lane = tid & 63;
  const int rl = lane & 15, kq = lane >> 4;
  __shared__ __align__(16) unsigned short As[128*40];
  __shared__ __align__(16) unsigned short Bs[128*40];
  f32x4 acc[2][8];
  #pragma unroll
  for (int mf = 0; mf < 2; ++mf)
    #pragma unroll
    for (int nf = 0; nf < 8; ++nf) acc[mf][nf] = (f32x4){0.f,0.f,0.f,0.f};

  for (int k0 = 0; k0 < KPk; k0 += 32) {
    __syncthreads();
    // stage A: 128 rows x 32 k, fp32 -> bf16 (512 chunks of 8)
    #pragma unroll
    for (int p = 0; p < 2; ++p) {
      int idx = tid + p*256;
      int row = idx >> 2, q = idx & 3;
      int gm = m0 + row;
      int gk = k0 + q*8;
      unsigned int d0 = 0, d1 = 0, d2 = 0, d3 = 0;
      if (gm < M) {
        if (gk + 8 <= K) {
          const float4 v0 = *(const float4*)&A[(size_t)gm*K + gk];
          const float4 v1 = *(const float4*)&A[(size_t)gm*K + gk + 4];
          d0 = packbf(v0.x, v0.y); d1 = packbf(v0.z, v0.w);
          d2 = packbf(v1.x, v1.y); d3 = packbf(v1.z, v1.w);
        } else if (gk < K) {
          float tmp[8];
          #pragma unroll
          for (int e = 0; e < 8; ++e) tmp[e] = (gk + e < K) ? A[(size_t)gm*K + gk + e] : 0.f;
          d0 = packbf(tmp[0], tmp[1]); d1 = packbf(tmp[2], tmp[3]);
          d2 = packbf(tmp[4], tmp[5]); d3 = packbf(tmp[6], tmp[7]);
        }
      }
      uint4 dv = {d0, d1, d2, d3};
      *(uint4*)&As[row*40 + q*8] = dv;
    }
    // stage B: 128 cols x 32 k (padded buffer -> no bounds)
    #pragma unroll
    for (int p = 0; p < 2; ++p) {
      int idx = tid + p*256;
      int j = idx >> 2, q = idx & 3;
      uint4 v = *(const uint4*)&Bb[((size_t)(bn + j))*KPk + k0 + q*8];
      *(uint4*)&Bs[j*40 + q*8] = v;
    }
    __syncthreads();
    short8 af[2], bf[8];
    #pragma unroll
    for (int mf = 0; mf < 2; ++mf)
      af[mf] = *(const short8*)&As[(w*32 + mf*16 + rl)*40 + kq*8];
    #pragma unroll
    for (int nf = 0; nf < 8; ++nf)
      bf[nf] = *(const short8*)&Bs[(nf*16 + rl)*40 + kq*8];
    #pragma unroll
    for (int mf = 0; mf < 2; ++mf)
      #pragma unroll
      for (int nf = 0; nf < 8; ++nf)
        acc[mf][nf] = __builtin_amdgcn_mfma_f32_16x16x32_bf16(af[mf], bf[nf], acc[mf][nf], 0, 0, 0);
  }
  // epilogue: C/D layout (m89): col = lane&15, row = (lane>>4)*4 + r
  #pragma unroll
  for (int mf = 0; mf < 2; ++mf)
    #pragma unroll
    for (int nf = 0; nf < 8; ++nf)
      #pragma unroll
      for (int r = 0; r < 4; ++r) {
        int gm = m0 + w*32 + mf*16 + kq*4 + r;
        int gn = bn + nf*16 + rl;
        if (gm < M && gn < Nc) {
          float v = acc[mf][nf][r];
          if (gn < split) XI[(size_t)gm*split + gn] = v;
          else            XJb[(size_t)gm*split + (gn - split)] = f2bf(v);
        }
      }
}

// ---------------- per-node aggregation -> bf16 Apost rows ----------------
// Direct (srcs,eav) CSR streams + 8-way edge unroll: 8 gathers in flight.
__global__ __launch_bounds__(256) void k_agg(
    const float* __restrict__ XI, const unsigned short* __restrict__ XJb,
    const int* __restrict__ rowptr, const int* __restrict__ srcs,
    const float* __restrict__ eav, const float* __restrict__ vec_e,
    const float* __restrict__ cst_e, const float* __restrict__ xin,
    unsigned short* __restrict__ Apost, int f, int C, int KP)
{
  __shared__ float vsh[512];
  const int tid = threadIdx.x;
  for (int c = tid; c < C; c += 256) vsh[c] = vec_e[c];
  __syncthreads();
  const int v = blockIdx.x;
  const int start = rowptr[v], end = rowptr[v+1];
  const int half = C >> 1;                 // C even (T*f, f even)
  const bool act = (tid < half);
  const float v0 = act ? vsh[tid*2]   : 0.f;
  const float v1 = act ? vsh[tid*2+1] : 0.f;
  const unsigned int* xj = (const unsigned int*)XJb;
  float s10 = 0.f, s11 = 0.f, s20 = 0.f, s21 = 0.f;
  float mn0 = 1e30f, mn1 = 1e30f, mx0 = -1e30f, mx1 = -1e30f;

  int p = start;
  for (; p + 8 <= end; p += 8) {
    int ss[8]; float aa[8];
    #pragma unroll
    for (int q = 0; q < 8; ++q) { ss[q] = srcs[p+q]; aa[q] = eav[p+q]; }
    if (act) {
      unsigned int uu[8];
      #pragma unroll
      for (int q = 0; q < 8; ++q) uu[q] = xj[(size_t)ss[q]*half + tid];
      #pragma unroll
      for (int q = 0; q < 8; ++q) {
        float y0 = fmaf(aa[q], v0, bf2f_lo(uu[q]));
        float y1 = fmaf(aa[q], v1, bf2f_hi(uu[q]));
        s10 += y0; s20 = fmaf(y0,y0,s20); mn0 = fminf(mn0,y0); mx0 = fmaxf(mx0,y0);
        s11 += y1; s21 = fmaf(y1,y1,s21); mn1 = fminf(mn1,y1); mx1 = fmaxf(mx1,y1);
      }
    }
  }
  for (; p < end; ++p) {
    int s = srcs[p];
    float a = eav[p];
    if (act) {
      unsigned int u = xj[(size_t)s*half + tid];
      float y0 = fmaf(a, v0, bf2f_lo(u));
      float y1 = fmaf(a, v1, bf2f_hi(u));
      s10 += y0; s20 = fmaf(y0, y0, s20);
      s11 += y1; s21 = fmaf(y1, y1, s21);
      mn0 = fminf(mn0, y0); mx0 = fmaxf(mx0, y0);
      mn1 = fminf(mn1, y1); mx1 = fmaxf(mx1, y1);
    }
  }

  const int dcnt = end - start;
  if (act) {
    int c0 = tid*2;
    int t = c0 / f, ff = c0 - t*f;          // pair never straddles towers (f even)
    float base0 = XI[(size_t)v*C + c0]     + cst_e[c0];
    float base1 = XI[(size_t)v*C + c0 + 1] + cst_e[c0 + 1];
    float me0, sd0, lo0, hi0, me1, sd1, lo1, hi1;
    if (dcnt > 0) {
      float inv = 1.0f / (float)dcnt;
      float m10 = s10 * inv, m11 = s11 * inv;
      me0 = base0 + m10; me1 = base1 + m11;
      sd0 = sqrtf(fmaxf(s20*inv - m10*m10, 0.f) + EPSF);
      sd1 = sqrtf(fmaxf(s21*inv - m11*m11, 0.f) + EPSF);
      lo0 = base0 + mn0; hi0 = base0 + mx0;
      lo1 = base1 + mn1; hi1 = base1 + mx1;
    } else {
      me0 = me1 = lo0 = lo1 = hi0 = hi1 = 0.f;
      sd0 = sd1 = sqrtf(EPSF);
    }
    unsigned short* o = Apost + ((size_t)v * T_ + t) * KP + ff;
    o[0]     = f2bf(me0); o[1]       = f2bf(me1);
    o[f]     = f2bf(lo0); o[f+1]     = f2bf(lo1);
    o[2*f]   = f2bf(hi0); o[2*f+1]   = f2bf(hi1);
    o[3*f]   = f2bf(sd0); o[3*f+1]   = f2bf(sd1);
  }
  // x copy (shared by all towers) + zero pad
  const int rem = KP - 4*f;
  for (int idx = tid; idx < T_*rem; idx += 256) {
    int t = idx / rem, kk = idx - t*rem;
    int k = 4*f + kk;
    unsigned short val = 0;
    if (k < 5*f) val = f2bf(xin[(size_t)v*f + (k - 4*f)]);
    Apost[((size_t)v * T_ + t) * KP + k] = val;
  }
}

// ---------------- post GEMM via MFMA + fused scaler combine ----------------
__global__ __launch_bounds__(256) void k_postmm(
    const unsigned short* __restrict__ Apost, const unsigned short* __restrict__ W2,
    const float* __restrict__ scal, const float* __restrict__ qb,
    float* __restrict__ h, int KP)
{
  const int t    = blockIdx.y;
  const int m0   = blockIdx.x * 128;
  const int tid  = threadIdx.x;
  const int w    = tid >> 6;
  const int lane = tid & 63;
  const int rl   = lane & 15;     // frag row/col
  const int kq   = lane >> 4;     // k-quarter 0..3
  __shared__ __align__(16) unsigned char smem[128*84*4];   // 43008 B, reused
  unsigned short* As = (unsigned short*)smem;              // [128][40]
  unsigned short* Bs = As + 128*40;                        // [80][40]
  f32x4 acc[2][5];
  #pragma unroll
  for (int mf = 0; mf < 2; ++mf)
    #pragma unroll
    for (int nf = 0; nf < 5; ++nf) acc[mf][nf] = (f32x4){0.f,0.f,0.f,0.f};

  const unsigned short* wt = W2 + (size_t)t * 80 * KP;

  for (int k0 = 0; k0 < KP; k0 += 32) {
    __syncthreads();
    #pragma unroll
    for (int p = 0; p < 2; ++p) {
      int idx = tid + p*256;
      int row = idx >> 2, q = idx & 3;
      int gm = m0 + row;
      uint4 v = {0u,0u,0u,0u};
      if (gm < N_) v = *(const uint4*)&Apost[((size_t)gm*T_ + t)*KP + k0 + q*8];
      *(uint4*)&As[row*40 + q*8] = v;
    }
    #pragma unroll
    for (int p = 0; p < 2; ++p) {
      int idx = tid + p*256;
      if (idx < 320) {
        int j = idx >> 2, q = idx & 3;
        uint4 v = *(const uint4*)&wt[(size_t)j*KP + k0 + q*8];
        *(uint4*)&Bs[j*40 + q*8] = v;
      }
    }
    __syncthreads();
    short8 af[2], bf[5];
    #pragma unroll
    for (int mf = 0; mf < 2; ++mf)
      af[mf] = *(const short8*)&As[(w*32 + mf*16 + rl)*40 + kq*8];
    #pragma unroll
    for (int nf = 0; nf < 5; ++nf)
      bf[nf] = *(const short8*)&Bs[(nf*16 + rl)*40 + kq*8];
    #pragma unroll
    for (int mf = 0; mf < 2; ++mf)
      #pragma unroll
      for (int nf = 0; nf < 5; ++nf)
        acc[mf][nf] = __builtin_amdgcn_mfma_f32_16x16x32_bf16(af[mf], bf[nf], acc[mf][nf], 0, 0, 0);
  }
  // epilogue: P tile to LDS (C/D layout m89: col=lane&15, row=(lane>>4)*4+r)
  __syncthreads();
  float (*Pl)[84] = (float (*)[84])smem;
  #pragma unroll
  for (int mf = 0; mf < 2; ++mf)
    #pragma unroll
    for (int nf = 0; nf < 5; ++nf)
      #pragma unroll
      for (int r = 0; r < 4; ++r)
        Pl[w*32 + mf*16 + kq*4 + r][nf*16 + rl] = acc[mf][nf][r];
  __syncthreads();
  for (int idx = tid; idx < 128*FO_; idx += 256) {
    int row = idx / FO_, g = idx - row*FO_;
    int n = m0 + row;
    if (n < N_) {
      const float* p = Pl[row];
      float4 sc = *(const float4*)&scal[n*4];
      h[(size_t)n*(T_*FO_) + t*FO_ + g] =
        p[g] + sc.y*p[20+g] + sc.z*p[40+g] + sc.w*p[60+g] + qb[t*FO_+g];
    }
  }
}

// ---------------- batch norm ----------------
__global__ __launch_bounds__(256) void k_bnsum(const float* __restrict__ h2, float* __restrict__ bnsum) {
  const int tid  = threadIdx.x;
  const int c    = tid & 127;
  const int half = tid >> 7;
  if (c >= H_) return;
  float s = 0.f, s2 = 0.f;
  for (int r = blockIdx.x * 2 + half; r < N_; r += 256) {
    float v = h2[(size_t)r * H_ + c];
    s += v; s2 = fmaf(v, v, s2);
  }
  atomicAdd(&bnsum[c], s);
  atomicAdd(&bnsum[H_ + c], s2);
}

__global__ void k_bnapply(const float* __restrict__ h2, const float* __restrict__ bnsum,
                          const float* __restrict__ gam, const float* __restrict__ bet,
                          float* __restrict__ out) {
  size_t i = (size_t)blockIdx.x * blockDim.x + threadIdx.x;
  if (i >= (size_t)N_*H_) return;
  int c = (int)(i % H_);
  const float invn = 1.0f / (float)N_;
  float mu  = bnsum[c] * invn;
  float var = bnsum[H_ + c] * invn - mu*mu;
  float y = (h2[i] - mu) * rsqrtf(var + EPSF) * gam[c] + bet[c];
  out[i] = fmaxf(y, 0.f);
}

// ---------------- pooling (fused gcnt) + MLP ----------------
// batch[] sorted; per-block LDS partials + LDS count histogram; flush only
// the <=3 spanned batches -> ~3 global atomics per block instead of 20000/50.
__global__ __launch_bounds__(256) void k_pool(const float* __restrict__ xc, const int* __restrict__ batch,
                                              float* __restrict__ gsum, int* __restrict__ gcnt) {
  __shared__ float Pl[B_][H_];
  __shared__ int cl[B_];
  const int tid = threadIdx.x;
  for (int i = tid; i < B_*H_; i += 256) Pl[i / H_][i % H_] = 0.f;
  for (int i = tid; i < B_; i += 256) cl[i] = 0;
  __syncthreads();
  const int r0 = blockIdx.x * PR_;
  const int rend = (r0 + PR_ < N_) ? r0 + PR_ : N_;
  for (int rr = tid; rr < rend - r0; rr += 256) atomicAdd(&cl[batch[r0 + rr]], 1);
  const int nel = (rend - r0) * H_;
  for (int idx = tid; idx < nel; idx += 256) {
    int rr = idx / H_, c = idx - rr*H_;
    int n = r0 + rr;
    atomicAdd(&Pl[batch[n]][c], xc[(size_t)n*H_ + c]);
  }
  __syncthreads();
  const int blo = batch[r0], bhi = batch[rend-1];
  const int nb = (bhi - blo + 1) * H_;
  for (int idx = tid; idx < nb; idx += 256) {
    int b = blo + idx / H_, c = idx % H_;
    atomicAdd(&gsum[(size_t)b*H_ + c], Pl[b][c]);
  }
  for (int b = blo + tid; b <= bhi; b += 256) atomicAdd(&gcnt[b], cl[b]);
}

__global__ __launch_bounds__(512) void k_mlp(
    const float* __restrict__ gsum, const int* __restrict__ gcnt,
    const float* __restrict__ w1, const float* __restrict__ b1,
    const float* __restrict__ w2, const float* __restrict__ b2,
    const float* __restrict__ w3, const float* __restrict__ b3,
    float* __restrict__ out)
{
  __shared__ float G[B_][H_];
  __shared__ float A1[B_][50];
  __shared__ float A2[B_][25];
  const int tid = threadIdx.x;
  for (int i = tid; i < B_*H_; i += 512) {
    int r = i / H_;
    G[r][i - r*H_] = gsum[i] / fmaxf((float)gcnt[r], 1.0f);
  }
  __syncthreads();
  for (int i = tid; i < B_*50; i += 512) {
    int r = i / 50, c = i - r*50;
    float a = b1[c];
    for (int k = 0; k < H_; ++k) a = fmaf(G[r][k], w1[k*50 + c], a);
    A1[r][c] = fmaxf(a, 0.f);
  }
  __syncthreads();
  for (int i = tid; i < B_*25; i += 512) {
    int r = i / 25, c = i - r*25;
    float a = b2[c];
    for (int k = 0; k < 50; ++k) a = fmaf(A1[r][k], w2[k*25 + c], a);
    A2[r][c] = fmaxf(a, 0.f);
  }
  __syncthreads();
  for (int i = tid; i < B_; i += 512) {
    float a = b3[0];
    for (int k = 0; k < 25; ++k) a = fmaf(A2[i][k], w3[k], a);
    out[i] = a;   // float32 output — reference output dtype is f32
  }
}

// ---------------- host ----------------
extern "C" void kernel_launch(void* const* d_in, const int* in_sizes, int n_in,
                              void* d_out, int out_size, void* d_ws, size_t ws_size,
                              hipStream_t stream)
{
  (void)in_sizes; (void)n_in; (void)out_size;
  const float* x0   = (const float*)d_in[0];
  const int*   eidx = (const int*)  d_in[1];
  const float* ea   = (const float*)d_in[2];
  const int*   batch= (const int*)  d_in[3];
  const float* e0w  = (const float*)d_in[4];
  const float* e0b  = (const float*)d_in[5];
  const float* p0w  = (const float*)d_in[6];
  const float* p0b  = (const float*)d_in[7];
  const float* q0w  = (const float*)d_in[8];
  const float* q0b  = (const float*)d_in[9];
  const float* l0w  = (const float*)d_in[10];
  const float* l0b  = (const float*)d_in[11];
  const float* g0   = (const float*)d_in[12];
  const float* b0   = (const float*)d_in[13];
  const float* eLw  = (const float*)d_in[14];
  const float* eLb  = (const float*)d_in[15];
  const float* pLw  = (const float*)d_in[16];
  const float* pLb  = (const float*)d_in[17];
  const float* qLw  = (const float*)d_in[18];
  const float* qLb  = (const float*)d_in[19];
  const float* lLw  = (const float*)d_in[20];
  const float* lLb  = (const float*)d_in[21];
  const float* gL   = (const float*)d_in[22];
  const float* bL   = (const float*)d_in[23];
  const float* w1   = (const float*)d_in[24];
  const float* b1   = (const float*)d_in[25];
  const float* w2   = (const float*)d_in[26];
  const float* b2   = (const float*)d_in[27];
  const float* w3   = (const float*)d_in[28];
  const float* b3   = (const float*)d_in[29];

  const int* src = eidx;
  const int* dst = eidx + E_;

  char* w = (char*)d_ws;
  size_t off = 0;
  auto take = [&](size_t bytes) -> void* {
    void* p = (void*)(w + off);
    off = (off + bytes + 255) & ~(size_t)255;
    return p;
  };
  int*   cnt    = (int*)  take((size_t)N_*4);
  int*   rowptr = (int*)  take((size_t)(N_+1)*4);
  int*   cursor = (int*)  take((size_t)N_*4);
  int*   srcs   = (int*)  take((size_t)E_*4);
  float* eav    = (float*)take((size_t)E_*4);
  float* scal   = (float*)take((size_t)N_*16);
  float* sumlog = (float*)take(256);
  float* bnsum  = (float*)take((size_t)2*H_*4);
  float* vec_e  = (float*)take((size_t)T_*H_*4);
  float* cst_e  = (float*)take((size_t)T_*H_*4);
  unsigned short* BpreT = (unsigned short*)take((size_t)1024*128*2);  // padded [NcPad][KPk]
  unsigned short* W2 = (unsigned short*)take((size_t)T_*80*512*2);
  float* XI     = (float*)take((size_t)N_*T_*H_*4);          // 40 MB
  unsigned short* XJb = (unsigned short*)take((size_t)N_*T_*H_*2);  // 20 MB node-major
  unsigned short* Apost = (unsigned short*)take((size_t)N_*T_*512*2);  // 102 MB node-major
  float* hbuf   = (float*)take((size_t)N_*H_*4);
  float* h2buf  = (float*)take((size_t)N_*H_*4);
  float* xcur   = (float*)take((size_t)N_*H_*4);
  float* gsum   = (float*)take((size_t)B_*H_*4);
  int*   gcnt   = (int*)  take((size_t)B_*4);
  if (off > ws_size) return;   // workspace too small: bail (test fails loudly)

  hipMemsetAsync(cnt,    0, (size_t)N_*4, stream);
  hipMemsetAsync(cursor, 0, (size_t)N_*4, stream);
  hipMemsetAsync(sumlog, 0, 4, stream);
  hipMemsetAsync(gsum,   0, (size_t)B_*H_*4, stream);
  hipMemsetAsync(gcnt,   0, (size_t)B_*4, stream);

  k_count <<<dim3((E_+255)/256), dim3(256), 0, stream>>>(dst, cnt);
  k_scan  <<<dim3(1),            dim3(1024),0, stream>>>(cnt, rowptr);
  k_fill  <<<dim3((E_+255)/256), dim3(256), 0, stream>>>(src, dst, ea, rowptr, cursor, srcs, eav);
  k_sumlog<<<dim3((N_+255)/256), dim3(256), 0, stream>>>(cnt, sumlog);
  k_scal  <<<dim3((N_+255)/256), dim3(256), 0, stream>>>(cnt, sumlog, scal);

  auto layer = [&](const float* xin, int f,
                   const float* ew, const float* eb, const float* pw, const float* pb,
                   const float* qw, const float* qb, const float* lw, const float* lb,
                   const float* bg, const float* bb) {
    const int C   = T_ * f;
    const int KP  = ((5*f + 31) / 32) * 32;  // post per-tower K (f=16:96, f=100:512)
    const int KPk = ((f + 31) / 32) * 32;    // pre K padded (16->32, 100->128)
    const int gN  = (2*C + 127) / 128;       // pre n-blocks
    const int NcPad = gN * 128;
    k_edgevec<<<dim3((C+255)/256), dim3(256), 0, stream>>>(pw, pb, ew, eb, vec_e, cst_e, f, C);
    const int pt = NcPad * KPk;
    k_pack_preT<<<dim3((pt+255)/256), dim3(256), 0, stream>>>(pw, BpreT, f, C, KPk, NcPad);
    const int wtot = T_ * 80 * KP;
    k_pack_w2<<<dim3((wtot+255)/256), dim3(256), 0, stream>>>(qw, W2, f, KP);
    k_mmsplit<<<dim3((N_+127)/128, gN), dim3(256), 0, stream>>>(xin, BpreT, XI, XJb, N_, f, KPk, C);
    k_agg<<<dim3(N_), dim3(256), 0, stream>>>(XI, XJb, rowptr, srcs, eav, vec_e, cst_e, xin, Apost, f, C, KP);
    k_postmm<<<dim3((N_+127)/128, T_), dim3(256), 0, stream>>>(Apost, W2, scal, qb, hbuf, KP);
    k_gemm<<<dim3((N_+63)/64, (H_+63)/64), dim3(256), 0, stream>>>(hbuf, lw, lb, h2buf, N_, H_, H_);
    hipMemsetAsync(bnsum, 0, (size_t)2*H_*4, stream);
    k_bnsum<<<dim3(128), dim3(256), 0, stream>>>(h2buf, bnsum);
    k_bnapply<<<dim3((unsigned)(((size_t)N_*H_+255)/256)), dim3(256), 0, stream>>>(h2buf, bnsum, bg, bb, xcur);
  };

  layer(x0,   FI_, e0w, e0b, p0w, p0b, q0w, q0b, l0w, l0b, g0, b0);
  layer(xcur, H_,  eLw, eLb, pLw, pLb, qLw, qLb, lLw, lLb, gL, bL);
  layer(xcur, H_,  eLw + H_, eLb + H_,
        pLw + (size_t)T_*3*H_*H_, pLb + T_*H_,
        qLw + (size_t)T_*17*H_*FO_, qLb + T_*FO_,
        lLw + H_*H_, lLb + H_, gL + H_, bL + H_);

  k_pool<<<dim3((N_+PR_-1)/PR_), dim3(256), 0, stream>>>(xcur, batch, gsum, gcnt);
  k_mlp <<<dim3(1), dim3(512), 0, stream>>>(gsum, gcnt, w1, b1, w2, b2, w3, b3, (float*)d_out);
}

// Round 12
// 835.106 us; speedup vs baseline: 1.9657x; 1.0724x over previous
//
#include <hip/hip_runtime.h>
#include <hip/hip_bf16.h>
#include <cstddef>

#define N_  20000
#define E_  320000
#define FI_ 16
#define H_  100
#define T_  5
#define FO_ 20
#define B_  50
#define EPSF 1e-5f
#define PR_  200    // k_pool rows per block

typedef __attribute__((ext_vector_type(8))) short short8;
typedef __attribute__((ext_vector_type(4))) float f32x4;

static __device__ __forceinline__ unsigned short f2bf(float x) {
  unsigned int u = __builtin_bit_cast(unsigned int, x);
  unsigned int r = (u + 0x7FFFu + ((u >> 16) & 1u)) >> 16;   // RNE
  return (unsigned short)r;
}
static __device__ __forceinline__ unsigned int packbf(float a, float b) {
  return (unsigned int)f2bf(a) | ((unsigned int)f2bf(b) << 16);
}
static __device__ __forceinline__ float bf2f_lo(unsigned int u) {
  return __builtin_bit_cast(float, (u & 0xFFFFu) << 16);
}
static __device__ __forceinline__ float bf2f_hi(unsigned int u) {
  return __builtin_bit_cast(float, u & 0xFFFF0000u);
}

// ---------------- graph prep ----------------
__global__ void k_count(const int* __restrict__ dst, int* __restrict__ cnt) {
  int e = blockIdx.x * blockDim.x + threadIdx.x;
  if (e < E_) atomicAdd(&cnt[dst[e]], 1);
}

// thread-serial segments (20/thread, unrolled -> regs) + one 1024-wide scan:
// 20 barriers total instead of 400.
__global__ __launch_bounds__(1024) void k_scan(const int* __restrict__ cnt, int* __restrict__ rowptr) {
  __shared__ int ls[1024];
  const int tid = threadIdx.x;
  const int base = tid * 20;
  int loc[20];
  int lsum = 0;
  #pragma unroll
  for (int i = 0; i < 20; ++i) {
    int idx = base + i;
    int v = (idx < N_) ? cnt[idx] : 0;
    loc[i] = lsum;
    lsum += v;
  }
  ls[tid] = lsum;
  __syncthreads();
  for (int off = 1; off < 1024; off <<= 1) {
    int t = (tid >= off) ? ls[tid - off] : 0;
    __syncthreads();
    ls[tid] += t;
    __syncthreads();
  }
  const int pre = (tid > 0) ? ls[tid - 1] : 0;
  #pragma unroll
  for (int i = 0; i < 20; ++i) {
    int idx = base + i;
    if (idx < N_) rowptr[idx] = pre + loc[i];
  }
  if (tid == 1023) rowptr[N_] = ls[1023];
}

// CSR fill: store source id and edge value directly (no edge-id indirection)
__global__ void k_fill(const int* __restrict__ src, const int* __restrict__ dst,
                       const float* __restrict__ ea, const int* __restrict__ rowptr,
                       int* __restrict__ cursor, int* __restrict__ srcs,
                       float* __restrict__ eav) {
  int e = blockIdx.x * blockDim.x + threadIdx.x;
  if (e < E_) {
    int v = dst[e];
    int p = atomicAdd(&cursor[v], 1);
    int pos = rowptr[v] + p;
    srcs[pos] = src[e];
    eav[pos]  = ea[e];
  }
}

__global__ void k_sumlog(const int* __restrict__ cnt, float* __restrict__ sumlog) {
  int i = blockIdx.x * blockDim.x + threadIdx.x;
  float v = (i < N_) ? logf((float)cnt[i] + 1.0f) : 0.0f;
  #pragma unroll
  for (int off = 32; off > 0; off >>= 1) v += __shfl_down(v, off);
  __shared__ float red[4];
  if ((threadIdx.x & 63) == 0) red[threadIdx.x >> 6] = v;
  __syncthreads();
  if (threadIdx.x == 0) atomicAdd(sumlog, red[0] + red[1] + red[2] + red[3]);
}

__global__ void k_scal(const int* __restrict__ cnt, const float* __restrict__ sumlog,
                       float* __restrict__ scal) {
  int i = blockIdx.x * blockDim.x + threadIdx.x;
  if (i >= N_) return;
  float c  = (float)cnt[i];
  float d  = fmaxf(c, 1.0f);
  float ld = logf(d + 1.0f);
  float avg_log = sumlog[0] * (1.0f / (float)N_);
  float avg_lin = (float)E_ / (float)N_;
  scal[i*4+0] = 1.0f;
  scal[i*4+1] = ld / avg_log;
  scal[i*4+2] = avg_log / ld;
  scal[i*4+3] = d / avg_lin;
}

// ---------------- per-layer prep ----------------
__global__ void k_edgevec(const float* __restrict__ pw, const float* __restrict__ pb,
                          const float* __restrict__ ew, const float* __restrict__ eb,
                          float* __restrict__ vec_e, float* __restrict__ cst_e, int f, int C) {
  int c = blockIdx.x * blockDim.x + threadIdx.x;
  if (c >= C) return;
  int t = c / f, g = c - t*f;
  const float* wp = pw + (size_t)t*3*f*f + (size_t)2*f*f + g;
  float v = 0.f, s = 0.f;
  for (int ff = 0; ff < f; ++ff) { float wv = wp[(size_t)ff*f]; v += ew[ff]*wv; s += eb[ff]*wv; }
  vec_e[c] = v;
  cst_e[c] = s + pb[c];
}

// BpreT[c][KPk] bf16, transposed+padded: c<2C from pw (k<f), else 0.
__global__ void k_pack_preT(const float* __restrict__ pw, unsigned short* __restrict__ Bb,
                            int f, int C, int KPk, int NcPad) {
  int tot = NcPad * KPk;
  int idx = blockIdx.x * blockDim.x + threadIdx.x;
  if (idx >= tot) return;
  int k = idx % KPk, c = idx / KPk;
  float v = 0.f;
  if (c < 2*C && k < f) {
    int half = c / C, cc = c - half*C;
    int t = cc / f, g = cc - t*f;
    v = pw[(size_t)t*3*f*f + (size_t)(half*f + k)*f + g];
  }
  Bb[idx] = f2bf(v);
}

// Pack post weights transposed, bf16: W2[t][j=s*20+g][k], k in [0,KP).
__global__ void k_pack_w2(const float* __restrict__ qw, unsigned short* __restrict__ W2,
                          int f, int KP) {
  int tot = T_ * 80 * KP;
  int idx = blockIdx.x * blockDim.x + threadIdx.x;
  if (idx >= tot) return;
  int k = idx % KP;
  int r = idx / KP;
  int j = r % 80;
  int t = r / 80;
  int s = j / 20, g = j - s*20;
  float v = 0.f;
  if (k < 4*f)                 v = qw[((size_t)t*17*f + f + (size_t)s*4*f + k) * FO_ + g];
  else if (k < 5*f && s == 0)  v = qw[((size_t)t*17*f + (k - 4*f)) * FO_ + g];
  W2[idx] = f2bf(v);
}

// Pack lin weights transposed bf16: Lb[j*128 + k] = lw[k*100 + j] (pad 128x128)
__global__ void k_pack_lin(const float* __restrict__ lw, unsigned short* __restrict__ Lb) {
  int idx = blockIdx.x * blockDim.x + threadIdx.x;
  if (idx >= 128*128) return;
  int k = idx & 127, j = idx >> 7;
  float v = (j < H_ && k < H_) ? lw[(size_t)k*H_ + j] : 0.f;
  Lb[idx] = f2bf(v);
}

// ---------------- pre-GEMM via MFMA, split epilogue ----------------
__global__ __launch_bounds__(256) void k_mmsplit(
    const float* __restrict__ A, const unsigned short* __restrict__ Bb,
    float* __restrict__ XI, unsigned short* __restrict__ XJb,
    int M, int K, int KPk, int split)
{
  const int m0 = blockIdx.x * 128;
  const int bn = blockIdx.y * 128;
  const int Nc = 2 * split;
  const int tid = threadIdx.x;
  const int w = tid >> 6, lane = tid & 63;
  const int rl = lane & 15, kq = lane >> 4;
  __shared__ __align__(16) unsigned short As[128*40];
  __shared__ __align__(16) unsigned short Bs[128*40];
  f32x4 acc[2][8];
  #pragma unroll
  for (int mf = 0; mf < 2; ++mf)
    #pragma unroll
    for (int nf = 0; nf < 8; ++nf) acc[mf][nf] = (f32x4){0.f,0.f,0.f,0.f};

  for (int k0 = 0; k0 < KPk; k0 += 32) {
    __syncthreads();
    // stage A: 128 rows x 32 k, fp32 -> bf16 (512 chunks of 8)
    #pragma unroll
    for (int p = 0; p < 2; ++p) {
      int idx = tid + p*256;
      int row = idx >> 2, q = idx & 3;
      int gm = m0 + row;
      int gk = k0 + q*8;
      unsigned int d0 = 0, d1 = 0, d2 = 0, d3 = 0;
      if (gm < M) {
        if (gk + 8 <= K) {
          const float4 v0 = *(const float4*)&A[(size_t)gm*K + gk];
          const float4 v1 = *(const float4*)&A[(size_t)gm*K + gk + 4];
          d0 = packbf(v0.x, v0.y); d1 = packbf(v0.z, v0.w);
          d2 = packbf(v1.x, v1.y); d3 = packbf(v1.z, v1.w);
        } else if (gk < K) {
          float tmp[8];
          #pragma unroll
          for (int e = 0; e < 8; ++e) tmp[e] = (gk + e < K) ? A[(size_t)gm*K + gk + e] : 0.f;
          d0 = packbf(tmp[0], tmp[1]); d1 = packbf(tmp[2], tmp[3]);
          d2 = packbf(tmp[4], tmp[5]); d3 = packbf(tmp[6], tmp[7]);
        }
      }
      uint4 dv = {d0, d1, d2, d3};
      *(uint4*)&As[row*40 + q*8] = dv;
    }
    // stage B: 128 cols x 32 k (padded buffer -> no bounds)
    #pragma unroll
    for (int p = 0; p < 2; ++p) {
      int idx = tid + p*256;
      int j = idx >> 2, q = idx & 3;
      uint4 v = *(const uint4*)&Bb[((size_t)(bn + j))*KPk + k0 + q*8];
      *(uint4*)&Bs[j*40 + q*8] = v;
    }
    __syncthreads();
    short8 af[2], bf[8];
    #pragma unroll
    for (int mf = 0; mf < 2; ++mf)
      af[mf] = *(const short8*)&As[(w*32 + mf*16 + rl)*40 + kq*8];
    #pragma unroll
    for (int nf = 0; nf < 8; ++nf)
      bf[nf] = *(const short8*)&Bs[(nf*16 + rl)*40 + kq*8];
    #pragma unroll
    for (int mf = 0; mf < 2; ++mf)
      #pragma unroll
      for (int nf = 0; nf < 8; ++nf)
        acc[mf][nf] = __builtin_amdgcn_mfma_f32_16x16x32_bf16(af[mf], bf[nf], acc[mf][nf], 0, 0, 0);
  }
  // epilogue: C/D layout (m89): col = lane&15, row = (lane>>4)*4 + r
  #pragma unroll
  for (int mf = 0; mf < 2; ++mf)
    #pragma unroll
    for (int nf = 0; nf < 8; ++nf)
      #pragma unroll
      for (int r = 0; r < 4; ++r) {
        int gm = m0 + w*32 + mf*16 + kq*4 + r;
        int gn = bn + nf*16 + rl;
        if (gm < M && gn < Nc) {
          float v = acc[mf][nf][r];
          if (gn < split) XI[(size_t)gm*split + gn] = v;
          else            XJb[(size_t)gm*split + (gn - split)] = f2bf(v);
        }
      }
}

// ---------------- lin layer via MFMA: Cm = A(Mx100) @ LwT + bias ----------------
// 64-row tile, 256 thr = 4 waves; wave w rows w*16, 8 n-frags (128 cols, 100 real)
__global__ __launch_bounds__(256) void k_lin(
    const float* __restrict__ A, const unsigned short* __restrict__ Bb,
    const float* __restrict__ bias, float* __restrict__ Cm, int M)
{
  const int m0 = blockIdx.x * 64;
  const int tid = threadIdx.x;
  const int w = tid >> 6, lane = tid & 63;
  const int rl = lane & 15, kq = lane >> 4;
  __shared__ __align__(16) unsigned short As[64*40];
  __shared__ __align__(16) unsigned short Bs[128*40];
  f32x4 acc[8];
  #pragma unroll
  for (int nf = 0; nf < 8; ++nf) acc[nf] = (f32x4){0.f,0.f,0.f,0.f};
  for (int k0 = 0; k0 < 128; k0 += 32) {
    __syncthreads();
    {
      int row = tid >> 2, q = tid & 3;   // 64 rows x 4 chunks of 8
      int gm = m0 + row;
      int gk = k0 + q*8;
      unsigned int d0=0,d1=0,d2=0,d3=0;
      if (gm < M && gk < H_) {
        if (gk + 8 <= H_) {
          const float4 v0 = *(const float4*)&A[(size_t)gm*H_ + gk];
          const float4 v1 = *(const float4*)&A[(size_t)gm*H_ + gk + 4];
          d0 = packbf(v0.x,v0.y); d1 = packbf(v0.z,v0.w);
          d2 = packbf(v1.x,v1.y); d3 = packbf(v1.z,v1.w);
        } else {
          float tmp[8];
          #pragma unroll
          for (int e = 0; e < 8; ++e) tmp[e] = (gk+e < H_) ? A[(size_t)gm*H_ + gk + e] : 0.f;
          d0 = packbf(tmp[0],tmp[1]); d1 = packbf(tmp[2],tmp[3]);
          d2 = packbf(tmp[4],tmp[5]); d3 = packbf(tmp[6],tmp[7]);
        }
      }
      uint4 dv = {d0,d1,d2,d3};
      *(uint4*)&As[row*40 + q*8] = dv;
    }
    #pragma unroll
    for (int p = 0; p < 2; ++p) {
      int idx = tid + p*256;
      int j = idx >> 2, q = idx & 3;
      uint4 v = *(const uint4*)&Bb[(size_t)j*128 + k0 + q*8];
      *(uint4*)&Bs[j*40 + q*8] = v;
    }
    __syncthreads();
    short8 af = *(const short8*)&As[(w*16 + rl)*40 + kq*8];
    #pragma unroll
    for (int nf = 0; nf < 8; ++nf) {
      short8 bf = *(const short8*)&Bs[(nf*16 + rl)*40 + kq*8];
      acc[nf] = __builtin_amdgcn_mfma_f32_16x16x32_bf16(af, bf, acc[nf], 0, 0, 0);
    }
  }
  #pragma unroll
  for (int nf = 0; nf < 8; ++nf)
    #pragma unroll
    for (int r = 0; r < 4; ++r) {
      int gm = m0 + w*16 + kq*4 + r;
      int gn = nf*16 + rl;
      if (gm < M && gn < H_)
        Cm[(size_t)gm*H_ + gn] = acc[nf][r] + bias[gn];
    }
}

// ---------------- per-node aggregation -> bf16 Apost rows ----------------
// Direct (srcs,eav) CSR streams + 8-way edge unroll: 8 gathers in flight.
__global__ __launch_bounds__(256) void k_agg(
    const float* __restrict__ XI, const unsigned short* __restrict__ XJb,
    const int* __restrict__ rowptr, const int* __restrict__ srcs,
    const float* __restrict__ eav, const float* __restrict__ vec_e,
    const float* __restrict__ cst_e, const float* __restrict__ xin,
    unsigned short* __restrict__ Apost, int f, int C, int KP)
{
  __shared__ float vsh[512];
  const int tid = threadIdx.x;
  for (int c = tid; c < C; c += 256) vsh[c] = vec_e[c];
  __syncthreads();
  const int v = blockIdx.x;
  const int start = rowptr[v], end = rowptr[v+1];
  const int half = C >> 1;                 // C even (T*f, f even)
  const bool act = (tid < half);
  const float v0 = act ? vsh[tid*2]   : 0.f;
  const float v1 = act ? vsh[tid*2+1] : 0.f;
  const unsigned int* xj = (const unsigned int*)XJb;
  float s10 = 0.f, s11 = 0.f, s20 = 0.f, s21 = 0.f;
  float mn0 = 1e30f, mn1 = 1e30f, mx0 = -1e30f, mx1 = -1e30f;

  int p = start;
  for (; p + 8 <= end; p += 8) {
    int ss[8]; float aa[8];
    #pragma unroll
    for (int q = 0; q < 8; ++q) { ss[q] = srcs[p+q]; aa[q] = eav[p+q]; }
    if (act) {
      unsigned int uu[8];
      #pragma unroll
      for (int q = 0; q < 8; ++q) uu[q] = xj[(size_t)ss[q]*half + tid];
      #pragma unroll
      for (int q = 0; q < 8; ++q) {
        float y0 = fmaf(aa[q], v0, bf2f_lo(uu[q]));
        float y1 = fmaf(aa[q], v1, bf2f_hi(uu[q]));
        s10 += y0; s20 = fmaf(y0,y0,s20); mn0 = fminf(mn0,y0); mx0 = fmaxf(mx0,y0);
        s11 += y1; s21 = fmaf(y1,y1,s21); mn1 = fminf(mn1,y1); mx1 = fmaxf(mx1,y1);
      }
    }
  }
  for (; p < end; ++p) {
    int s = srcs[p];
    float a = eav[p];
    if (act) {
      unsigned int u = xj[(size_t)s*half + tid];
      float y0 = fmaf(a, v0, bf2f_lo(u));
      float y1 = fmaf(a, v1, bf2f_hi(u));
      s10 += y0; s20 = fmaf(y0, y0, s20);
      s11 += y1; s21 = fmaf(y1, y1, s21);
      mn0 = fminf(mn0, y0); mx0 = fmaxf(mx0, y0);
      mn1 = fminf(mn1, y1); mx1 = fmaxf(mx1, y1);
    }
  }

  const int dcnt = end - start;
  if (act) {
    int c0 = tid*2;
    int t = c0 / f, ff = c0 - t*f;          // pair never straddles towers (f even)
    float base0 = XI[(size_t)v*C + c0]     + cst_e[c0];
    float base1 = XI[(size_t)v*C + c0 + 1] + cst_e[c0 + 1];
    float me0, sd0, lo0, hi0, me1, sd1, lo1, hi1;
    if (dcnt > 0) {
      float inv = 1.0f / (float)dcnt;
      float m10 = s10 * inv, m11 = s11 * inv;
      me0 = base0 + m10; me1 = base1 + m11;
      sd0 = sqrtf(fmaxf(s20*inv - m10*m10, 0.f) + EPSF);
      sd1 = sqrtf(fmaxf(s21*inv - m11*m11, 0.f) + EPSF);
      lo0 = base0 + mn0; hi0 = base0 + mx0;
      lo1 = base1 + mn1; hi1 = base1 + mx1;
    } else {
      me0 = me1 = lo0 = lo1 = hi0 = hi1 = 0.f;
      sd0 = sd1 = sqrtf(EPSF);
    }
    // dword-packed stat stores (same addresses, half the store count)
    unsigned int* od = (unsigned int*)(Apost + ((size_t)v * T_ + t) * KP);
    int fd = ff >> 1, f2 = f >> 1;
    od[fd]          = packbf(me0, me1);
    od[f2 + fd]     = packbf(lo0, lo1);
    od[2*f2 + fd]   = packbf(hi0, hi1);
    od[3*f2 + fd]   = packbf(sd0, sd1);
  }
  // x copy (shared by all towers) + zero pad
  const int rem = KP - 4*f;
  for (int idx = tid; idx < T_*rem; idx += 256) {
    int t = idx / rem, kk = idx - t*rem;
    int k = 4*f + kk;
    unsigned short val = 0;
    if (k < 5*f) val = f2bf(xin[(size_t)v*f + (k - 4*f)]);
    Apost[((size_t)v * T_ + t) * KP + k] = val;
  }
}

// ---------------- post GEMM via MFMA + fused scaler combine ----------------
__global__ __launch_bounds__(256) void k_postmm(
    const unsigned short* __restrict__ Apost, const unsigned short* __restrict__ W2,
    const float* __restrict__ scal, const float* __restrict__ qb,
    float* __restrict__ h, int KP)
{
  const int t    = blockIdx.y;
  const int m0   = blockIdx.x * 128;
  const int tid  = threadIdx.x;
  const int w    = tid >> 6;
  const int lane = tid & 63;
  const int rl   = lane & 15;     // frag row/col
  const int kq   = lane >> 4;     // k-quarter 0..3
  __shared__ __align__(16) unsigned char smem[128*84*4];   // 43008 B, reused
  unsigned short* As = (unsigned short*)smem;              // [128][40]
  unsigned short* Bs = As + 128*40;                        // [80][40]
  f32x4 acc[2][5];
  #pragma unroll
  for (int mf = 0; mf < 2; ++mf)
    #pragma unroll
    for (int nf = 0; nf < 5; ++nf) acc[mf][nf] = (f32x4){0.f,0.f,0.f,0.f};

  const unsigned short* wt = W2 + (size_t)t * 80 * KP;

  for (int k0 = 0; k0 < KP; k0 += 32) {
    __syncthreads();
    #pragma unroll
    for (int p = 0; p < 2; ++p) {
      int idx = tid + p*256;
      int row = idx >> 2, q = idx & 3;
      int gm = m0 + row;
      uint4 v = {0u,0u,0u,0u};
      if (gm < N_) v = *(const uint4*)&Apost[((size_t)gm*T_ + t)*KP + k0 + q*8];
      *(uint4*)&As[row*40 + q*8] = v;
    }
    #pragma unroll
    for (int p = 0; p < 2; ++p) {
      int idx = tid + p*256;
      if (idx < 320) {
        int j = idx >> 2, q = idx & 3;
        uint4 v = *(const uint4*)&wt[(size_t)j*KP + k0 + q*8];
        *(uint4*)&Bs[j*40 + q*8] = v;
      }
    }
    __syncthreads();
    short8 af[2], bf[5];
    #pragma unroll
    for (int mf = 0; mf < 2; ++mf)
      af[mf] = *(const short8*)&As[(w*32 + mf*16 + rl)*40 + kq*8];
    #pragma unroll
    for (int nf = 0; nf < 5; ++nf)
      bf[nf] = *(const short8*)&Bs[(nf*16 + rl)*40 + kq*8];
    #pragma unroll
    for (int mf = 0; mf < 2; ++mf)
      #pragma unroll
      for (int nf = 0; nf < 5; ++nf)
        acc[mf][nf] = __builtin_amdgcn_mfma_f32_16x16x32_bf16(af[mf], bf[nf], acc[mf][nf], 0, 0, 0);
  }
  // epilogue: P tile to LDS (C/D layout m89: col=lane&15, row=(lane>>4)*4+r)
  __syncthreads();
  float (*Pl)[84] = (float (*)[84])smem;
  #pragma unroll
  for (int mf = 0; mf < 2; ++mf)
    #pragma unroll
    for (int nf = 0; nf < 5; ++nf)
      #pragma unroll
      for (int r = 0; r < 4; ++r)
        Pl[w*32 + mf*16 + kq*4 + r][nf*16 + rl] = acc[mf][nf][r];
  __syncthreads();
  for (int idx = tid; idx < 128*FO_; idx += 256) {
    int row = idx / FO_, g = idx - row*FO_;
    int n = m0 + row;
    if (n < N_) {
      const float* p = Pl[row];
      float4 sc = *(const float4*)&scal[n*4];
      h[(size_t)n*(T_*FO_) + t*FO_ + g] =
        p[g] + sc.y*p[20+g] + sc.z*p[40+g] + sc.w*p[60+g] + qb[t*FO_+g];
    }
  }
}

// ---------------- batch norm ----------------
__global__ __launch_bounds__(256) void k_bnsum(const float* __restrict__ h2, float* __restrict__ bnsum) {
  const int tid  = threadIdx.x;
  const int c    = tid & 127;
  const int half = tid >> 7;
  if (c >= H_) return;
  float s = 0.f, s2 = 0.f;
  for (int r = blockIdx.x * 2 + half; r < N_; r += 256) {
    float v = h2[(size_t)r * H_ + c];
    s += v; s2 = fmaf(v, v, s2);
  }
  atomicAdd(&bnsum[c], s);
  atomicAdd(&bnsum[H_ + c], s2);
}

__global__ void k_bnapply(const float* __restrict__ h2, const float* __restrict__ bnsum,
                          const float* __restrict__ gam, const float* __restrict__ bet,
                          float* __restrict__ out) {
  size_t i = (size_t)blockIdx.x * blockDim.x + threadIdx.x;
  if (i >= (size_t)N_*H_) return;
  int c = (int)(i % H_);
  const float invn = 1.0f / (float)N_;
  float mu  = bnsum[c] * invn;
  float var = bnsum[H_ + c] * invn - mu*mu;
  float y = (h2[i] - mu) * rsqrtf(var + EPSF) * gam[c] + bet[c];
  out[i] = fmaxf(y, 0.f);
}

// ---------------- pooling (fused gcnt) + MLP ----------------
__global__ __launch_bounds__(256) void k_pool(const float* __restrict__ xc, const int* __restrict__ batch,
                                              float* __restrict__ gsum, int* __restrict__ gcnt) {
  __shared__ float Pl[B_][H_];
  __shared__ int cl[B_];
  const int tid = threadIdx.x;
  for (int i = tid; i < B_*H_; i += 256) Pl[i / H_][i % H_] = 0.f;
  for (int i = tid; i < B_; i += 256) cl[i] = 0;
  __syncthreads();
  const int r0 = blockIdx.x * PR_;
  const int rend = (r0 + PR_ < N_) ? r0 + PR_ : N_;
  for (int rr = tid; rr < rend - r0; rr += 256) atomicAdd(&cl[batch[r0 + rr]], 1);
  const int nel = (rend - r0) * H_;
  for (int idx = tid; idx < nel; idx += 256) {
    int rr = idx / H_, c = idx - rr*H_;
    int n = r0 + rr;
    atomicAdd(&Pl[batch[n]][c], xc[(size_t)n*H_ + c]);
  }
  __syncthreads();
  const int blo = batch[r0], bhi = batch[rend-1];
  const int nb = (bhi - blo + 1) * H_;
  for (int idx = tid; idx < nb; idx += 256) {
    int b = blo + idx / H_, c = idx % H_;
    atomicAdd(&gsum[(size_t)b*H_ + c], Pl[b][c]);
  }
  for (int b = blo + tid; b <= bhi; b += 256) atomicAdd(&gcnt[b], cl[b]);
}

__global__ __launch_bounds__(512) void k_mlp(
    const float* __restrict__ gsum, const int* __restrict__ gcnt,
    const float* __restrict__ w1, const float* __restrict__ b1,
    const float* __restrict__ w2, const float* __restrict__ b2,
    const float* __restrict__ w3, const float* __restrict__ b3,
    float* __restrict__ out)
{
  __shared__ float G[B_][H_];
  __shared__ float A1[B_][50];
  __shared__ float A2[B_][25];
  const int tid = threadIdx.x;
  for (int i = tid; i < B_*H_; i += 512) {
    int r = i / H_;
    G[r][i - r*H_] = gsum[i] / fmaxf((float)gcnt[r], 1.0f);
  }
  __syncthreads();
  for (int i = tid; i < B_*50; i += 512) {
    int r = i / 50, c = i - r*50;
    float a = b1[c];
    for (int k = 0; k < H_; ++k) a = fmaf(G[r][k], w1[k*50 + c], a);
    A1[r][c] = fmaxf(a, 0.f);
  }
  __syncthreads();
  for (int i = tid; i < B_*25; i += 512) {
    int r = i / 25, c = i - r*25;
    float a = b2[c];
    for (int k = 0; k < 50; ++k) a = fmaf(A1[r][k], w2[k*25 + c], a);
    A2[r][c] = fmaxf(a, 0.f);
  }
  __syncthreads();
  for (int i = tid; i < B_; i += 512) {
    float a = b3[0];
    for (int k = 0; k < 25; ++k) a = fmaf(A2[i][k], w3[k], a);
    out[i] = a;   // float32 output — reference output dtype is f32
  }
}

// ---------------- host ----------------
extern "C" void kernel_launch(void* const* d_in, const int* in_sizes, int n_in,
                              void* d_out, int out_size, void* d_ws, size_t ws_size,
                              hipStream_t stream)
{
  (void)in_sizes; (void)n_in; (void)out_size;
  const float* x0   = (const float*)d_in[0];
  const int*   eidx = (const int*)  d_in[1];
  const float* ea   = (const float*)d_in[2];
  const int*   batch= (const int*)  d_in[3];
  const float* e0w  = (const float*)d_in[4];
  const float* e0b  = (const float*)d_in[5];
  const float* p0w  = (const float*)d_in[6];
  const float* p0b  = (const float*)d_in[7];
  const float* q0w  = (const float*)d_in[8];
  const float* q0b  = (const float*)d_in[9];
  const float* l0w  = (const float*)d_in[10];
  const float* l0b  = (const float*)d_in[11];
  const float* g0   = (const float*)d_in[12];
  const float* b0   = (const float*)d_in[13];
  const float* eLw  = (const float*)d_in[14];
  const float* eLb  = (const float*)d_in[15];
  const float* pLw  = (const float*)d_in[16];
  const float* pLb  = (const float*)d_in[17];
  const float* qLw  = (const float*)d_in[18];
  const float* qLb  = (const float*)d_in[19];
  const float* lLw  = (const float*)d_in[20];
  const float* lLb  = (const float*)d_in[21];
  const float* gL   = (const float*)d_in[22];
  const float* bL   = (const float*)d_in[23];
  const float* w1   = (const float*)d_in[24];
  const float* b1   = (const float*)d_in[25];
  const float* w2   = (const float*)d_in[26];
  const float* b2   = (const float*)d_in[27];
  const float* w3   = (const float*)d_in[28];
  const float* b3   = (const float*)d_in[29];

  const int* src = eidx;
  const int* dst = eidx + E_;

  char* w = (char*)d_ws;
  size_t off = 0;
  auto take = [&](size_t bytes) -> void* {
    void* p = (void*)(w + off);
    off = (off + bytes + 255) & ~(size_t)255;
    return p;
  };
  int*   cnt    = (int*)  take((size_t)N_*4);
  int*   rowptr = (int*)  take((size_t)(N_+1)*4);
  int*   cursor = (int*)  take((size_t)N_*4);
  int*   srcs   = (int*)  take((size_t)E_*4);
  float* eav    = (float*)take((size_t)E_*4);
  float* scal   = (float*)take((size_t)N_*16);
  float* sumlog = (float*)take(256);
  float* bnsum  = (float*)take((size_t)2*H_*4);
  float* vec_e  = (float*)take((size_t)T_*H_*4);
  float* cst_e  = (float*)take((size_t)T_*H_*4);
  unsigned short* BpreT = (unsigned short*)take((size_t)1024*128*2);  // padded [NcPad][KPk]
  unsigned short* W2 = (unsigned short*)take((size_t)T_*80*512*2);
  unsigned short* LwT = (unsigned short*)take((size_t)128*128*2);
  float* XI     = (float*)take((size_t)N_*T_*H_*4);          // 40 MB
  unsigned short* XJb = (unsigned short*)take((size_t)N_*T_*H_*2);  // 20 MB node-major
  unsigned short* Apost = (unsigned short*)take((size_t)N_*T_*512*2);  // 102 MB node-major
  float* hbuf   = (float*)take((size_t)N_*H_*4);
  float* h2buf  = (float*)take((size_t)N_*H_*4);
  float* xcur   = (float*)take((size_t)N_*H_*4);
  float* gsum   = (float*)take((size_t)B_*H_*4);
  int*   gcnt   = (int*)  take((size_t)B_*4);
  if (off > ws_size) return;   // workspace too small: bail (test fails loudly)

  hipMemsetAsync(cnt,    0, (size_t)N_*4, stream);
  hipMemsetAsync(cursor, 0, (size_t)N_*4, stream);
  hipMemsetAsync(sumlog, 0, 4, stream);
  hipMemsetAsync(gsum,   0, (size_t)B_*H_*4, stream);
  hipMemsetAsync(gcnt,   0, (size_t)B_*4, stream);

  k_count <<<dim3((E_+255)/256), dim3(256), 0, stream>>>(dst, cnt);
  k_scan  <<<dim3(1),            dim3(1024),0, stream>>>(cnt, rowptr);
  k_fill  <<<dim3((E_+255)/256), dim3(256), 0, stream>>>(src, dst, ea, rowptr, cursor, srcs, eav);
  k_sumlog<<<dim3((N_+255)/256), dim3(256), 0, stream>>>(cnt, sumlog);
  k_scal  <<<dim3((N_+255)/256), dim3(256), 0, stream>>>(cnt, sumlog, scal);

  auto layer = [&](const float* xin, int f,
                   const float* ew, const float* eb, const float* pw, const float* pb,
                   const float* qw, const float* qb, const float* lw, const float* lb,
                   const float* bg, const float* bb) {
    const int C   = T_ * f;
    const int KP  = ((5*f + 31) / 32) * 32;  // post per-tower K (f=16:96, f=100:512)
    const int KPk = ((f + 31) / 32) * 32;    // pre K padded (16->32, 100->128)
    const int gN  = (2*C + 127) / 128;       // pre n-blocks
    const int NcPad = gN * 128;
    k_edgevec<<<dim3((C+255)/256), dim3(256), 0, stream>>>(pw, pb, ew, eb, vec_e, cst_e, f, C);
    const int pt = NcPad * KPk;
    k_pack_preT<<<dim3((pt+255)/256), dim3(256), 0, stream>>>(pw, BpreT, f, C, KPk, NcPad);
    const int wtot = T_ * 80 * KP;
    k_pack_w2<<<dim3((wtot+255)/256), dim3(256), 0, stream>>>(qw, W2, f, KP);
    k_pack_lin<<<dim3((128*128+255)/256), dim3(256), 0, stream>>>(lw, LwT);
    k_mmsplit<<<dim3((N_+127)/128, gN), dim3(256), 0, stream>>>(xin, BpreT, XI, XJb, N_, f, KPk, C);
    k_agg<<<dim3(N_), dim3(256), 0, stream>>>(XI, XJb, rowptr, srcs, eav, vec_e, cst_e, xin, Apost, f, C, KP);
    k_postmm<<<dim3((N_+127)/128, T_), dim3(256), 0, stream>>>(Apost, W2, scal, qb, hbuf, KP);
    k_lin<<<dim3((N_+63)/64), dim3(256), 0, stream>>>(hbuf, LwT, lb, h2buf, N_);
    hipMemsetAsync(bnsum, 0, (size_t)2*H_*4, stream);
    k_bnsum<<<dim3(128), dim3(256), 0, stream>>>(h2buf, bnsum);
    k_bnapply<<<dim3((unsigned)(((size_t)N_*H_+255)/256)), dim3(256), 0, stream>>>(h2buf, bnsum, bg, bb, xcur);
  };

  layer(x0,   FI_, e0w, e0b, p0w, p0b, q0w, q0b, l0w, l0b, g0, b0);
  layer(xcur, H_,  eLw, eLb, pLw, pLb, qLw, qLb, lLw, lLb, gL, bL);
  layer(xcur, H_,  eLw + H_, eLb + H_,
        pLw + (size_t)T_*3*H_*H_, pLb + T_*H_,
        qLw + (size_t)T_*17*H_*FO_, qLb + T_*FO_,
        lLw + H_*H_, lLb + H_, gL + H_, bL + H_);

  k_pool<<<dim3((N_+PR_-1)/PR_), dim3(256), 0, stream>>>(xcur, batch, gsum, gcnt);
  k_mlp <<<dim3(1), dim3(512), 0, stream>>>(gsum, gcnt, w1, b1, w2, b2, w3, b3, (float*)d_out);
}

// Round 13
// 760.250 us; speedup vs baseline: 2.1593x; 1.0985x over previous
//
#include <hip/hip_runtime.h>
#include <hip/hip_bf16.h>
#include <cstddef>

#define N_  20000
#define E_  320000
#define FI_ 16
#define H_  100
#define T_  5
#define FO_ 20
#define B_  50
#define EPSF 1e-5f
#define PR_  200    // k_pool rows per block

typedef __attribute__((ext_vector_type(8))) short short8;
typedef __attribute__((ext_vector_type(4))) float f32x4;

static __device__ __forceinline__ unsigned short f2bf(float x) {
  unsigned int u = __builtin_bit_cast(unsigned int, x);
  unsigned int r = (u + 0x7FFFu + ((u >> 16) & 1u)) >> 16;   // RNE
  return (unsigned short)r;
}
static __device__ __forceinline__ unsigned int packbf(float a, float b) {
  return (unsigned int)f2bf(a) | ((unsigned int)f2bf(b) << 16);
}
static __device__ __forceinline__ float bf2f_lo(unsigned int u) {
  return __builtin_bit_cast(float, (u & 0xFFFFu) << 16);
}
static __device__ __forceinline__ float bf2f_hi(unsigned int u) {
  return __builtin_bit_cast(float, u & 0xFFFF0000u);
}

// ---------------- graph prep ----------------
__global__ void k_count(const int* __restrict__ dst, int* __restrict__ cnt) {
  int e = blockIdx.x * blockDim.x + threadIdx.x;
  if (e < E_) atomicAdd(&cnt[dst[e]], 1);
}

// thread-serial segments (20/thread, unrolled -> regs) + one 1024-wide scan.
__global__ __launch_bounds__(1024) void k_scan(const int* __restrict__ cnt, int* __restrict__ rowptr) {
  __shared__ int ls[1024];
  const int tid = threadIdx.x;
  const int base = tid * 20;
  int loc[20];
  int lsum = 0;
  #pragma unroll
  for (int i = 0; i < 20; ++i) {
    int idx = base + i;
    int v = (idx < N_) ? cnt[idx] : 0;
    loc[i] = lsum;
    lsum += v;
  }
  ls[tid] = lsum;
  __syncthreads();
  for (int off = 1; off < 1024; off <<= 1) {
    int t = (tid >= off) ? ls[tid - off] : 0;
    __syncthreads();
    ls[tid] += t;
    __syncthreads();
  }
  const int pre = (tid > 0) ? ls[tid - 1] : 0;
  #pragma unroll
  for (int i = 0; i < 20; ++i) {
    int idx = base + i;
    if (idx < N_) rowptr[idx] = pre + loc[i];
  }
  if (tid == 1023) rowptr[N_] = ls[1023];
}

__global__ void k_fill(const int* __restrict__ src, const int* __restrict__ dst,
                       const float* __restrict__ ea, const int* __restrict__ rowptr,
                       int* __restrict__ cursor, int* __restrict__ srcs,
                       float* __restrict__ eav) {
  int e = blockIdx.x * blockDim.x + threadIdx.x;
  if (e < E_) {
    int v = dst[e];
    int p = atomicAdd(&cursor[v], 1);
    int pos = rowptr[v] + p;
    srcs[pos] = src[e];
    eav[pos]  = ea[e];
  }
}

__global__ void k_sumlog(const int* __restrict__ cnt, float* __restrict__ sumlog) {
  int i = blockIdx.x * blockDim.x + threadIdx.x;
  float v = (i < N_) ? logf((float)cnt[i] + 1.0f) : 0.0f;
  #pragma unroll
  for (int off = 32; off > 0; off >>= 1) v += __shfl_down(v, off);
  __shared__ float red[4];
  if ((threadIdx.x & 63) == 0) red[threadIdx.x >> 6] = v;
  __syncthreads();
  if (threadIdx.x == 0) atomicAdd(sumlog, red[0] + red[1] + red[2] + red[3]);
}

__global__ void k_scal(const int* __restrict__ cnt, const float* __restrict__ sumlog,
                       float* __restrict__ scal) {
  int i = blockIdx.x * blockDim.x + threadIdx.x;
  if (i >= N_) return;
  float c  = (float)cnt[i];
  float d  = fmaxf(c, 1.0f);
  float ld = logf(d + 1.0f);
  float avg_log = sumlog[0] * (1.0f / (float)N_);
  float avg_lin = (float)E_ / (float)N_;
  scal[i*4+0] = 1.0f;
  scal[i*4+1] = ld / avg_log;
  scal[i*4+2] = avg_log / ld;
  scal[i*4+3] = d / avg_lin;
}

// ---------------- batched weight prep (all 3 layers, gridDim.y = layer) ----------------
__global__ void k_edgevec3(const float* __restrict__ p0w, const float* __restrict__ pLw,
                           const float* __restrict__ p0b, const float* __restrict__ pLb,
                           const float* __restrict__ e0w, const float* __restrict__ eLw,
                           const float* __restrict__ e0b, const float* __restrict__ eLb,
                           float* __restrict__ vec_e3, float* __restrict__ cst_e3) {
  const int l = blockIdx.y;
  const int f = l ? H_ : FI_;
  const int C = T_ * f;
  int c = blockIdx.x * blockDim.x + threadIdx.x;
  if (c >= C) return;
  const float* pw = l ? pLw + (size_t)(l-1)*T_*3*H_*H_ : p0w;
  const float* pb = l ? pLb + (l-1)*T_*H_ : p0b;
  const float* ew = l ? eLw + (l-1)*H_ : e0w;
  const float* eb = l ? eLb + (l-1)*H_ : e0b;
  int t = c / f, g = c - t*f;
  const float* wp = pw + (size_t)t*3*f*f + (size_t)2*f*f + g;
  float v = 0.f, s = 0.f;
  for (int ff = 0; ff < f; ++ff) { float wv = wp[(size_t)ff*f]; v += ew[ff]*wv; s += eb[ff]*wv; }
  vec_e3[l*512 + c] = v;
  cst_e3[l*512 + c] = s + pb[c];
}

__global__ void k_pack_preT3(const float* __restrict__ p0w, const float* __restrict__ pLw,
                             unsigned short* __restrict__ Bb3) {
  const int l = blockIdx.y;
  const int f = l ? H_ : FI_;
  const int C = T_ * f;
  const int KPk = l ? 128 : 32;
  const int NcPad = l ? 1024 : 256;
  const int tot = NcPad * KPk;
  int idx = blockIdx.x * blockDim.x + threadIdx.x;
  if (idx >= tot) return;
  const float* pw = l ? pLw + (size_t)(l-1)*T_*3*H_*H_ : p0w;
  int k = idx % KPk, c = idx / KPk;
  float v = 0.f;
  if (c < 2*C && k < f) {
    int half = c / C, cc = c - half*C;
    int t = cc / f, g = cc - t*f;
    v = pw[(size_t)t*3*f*f + (size_t)(half*f + k)*f + g];
  }
  Bb3[(size_t)l*131072 + idx] = f2bf(v);
}

__global__ void k_pack_w23(const float* __restrict__ q0w, const float* __restrict__ qLw,
                           unsigned short* __restrict__ W23) {
  const int l = blockIdx.y;
  const int f = l ? H_ : FI_;
  const int KP = l ? 512 : 96;
  const int tot = T_ * 80 * KP;
  int idx = blockIdx.x * blockDim.x + threadIdx.x;
  if (idx >= tot) return;
  const float* qw = l ? qLw + (size_t)(l-1)*T_*17*H_*FO_ : q0w;
  int k = idx % KP;
  int r = idx / KP;
  int j = r % 80;
  int t = r / 80;
  int s = j / 20, g = j - s*20;
  float v = 0.f;
  if (k < 4*f)                 v = qw[((size_t)t*17*f + f + (size_t)s*4*f + k) * FO_ + g];
  else if (k < 5*f && s == 0)  v = qw[((size_t)t*17*f + (k - 4*f)) * FO_ + g];
  W23[(size_t)l*204800 + idx] = f2bf(v);
}

__global__ void k_pack_lin3(const float* __restrict__ l0w, const float* __restrict__ lLw,
                            unsigned short* __restrict__ Lb3) {
  const int l = blockIdx.y;
  int idx = blockIdx.x * blockDim.x + threadIdx.x;
  if (idx >= 128*128) return;
  const float* lw = l ? lLw + (size_t)(l-1)*H_*H_ : l0w;
  int k = idx & 127, j = idx >> 7;
  float v = (j < H_ && k < H_) ? lw[(size_t)k*H_ + j] : 0.f;
  Lb3[(size_t)l*16384 + idx] = f2bf(v);
}

// ---------------- pre-GEMM via MFMA, split epilogue (XI in bf16) ----------------
__global__ __launch_bounds__(256) void k_mmsplit(
    const float* __restrict__ A, const unsigned short* __restrict__ Bb,
    unsigned short* __restrict__ XIb, unsigned short* __restrict__ XJb,
    int M, int K, int KPk, int split)
{
  const int m0 = blockIdx.x * 128;
  const int bn = blockIdx.y * 128;
  const int Nc = 2 * split;
  const int tid = threadIdx.x;
  const int w = tid >> 6, lane = tid & 63;
  const int rl = lane & 15, kq = lane >> 4;
  __shared__ __align__(16) unsigned short As[128*40];
  __shared__ __align__(16) unsigned short Bs[128*40];
  f32x4 acc[2][8];
  #pragma unroll
  for (int mf = 0; mf < 2; ++mf)
    #pragma unroll
    for (int nf = 0; nf < 8; ++nf) acc[mf][nf] = (f32x4){0.f,0.f,0.f,0.f};

  for (int k0 = 0; k0 < KPk; k0 += 32) {
    __syncthreads();
    #pragma unroll
    for (int p = 0; p < 2; ++p) {
      int idx = tid + p*256;
      int row = idx >> 2, q = idx & 3;
      int gm = m0 + row;
      int gk = k0 + q*8;
      unsigned int d0 = 0, d1 = 0, d2 = 0, d3 = 0;
      if (gm < M) {
        if (gk + 8 <= K) {
          const float4 v0 = *(const float4*)&A[(size_t)gm*K + gk];
          const float4 v1 = *(const float4*)&A[(size_t)gm*K + gk + 4];
          d0 = packbf(v0.x, v0.y); d1 = packbf(v0.z, v0.w);
          d2 = packbf(v1.x, v1.y); d3 = packbf(v1.z, v1.w);
        } else if (gk < K) {
          float tmp[8];
          #pragma unroll
          for (int e = 0; e < 8; ++e) tmp[e] = (gk + e < K) ? A[(size_t)gm*K + gk + e] : 0.f;
          d0 = packbf(tmp[0], tmp[1]); d1 = packbf(tmp[2], tmp[3]);
          d2 = packbf(tmp[4], tmp[5]); d3 = packbf(tmp[6], tmp[7]);
        }
      }
      uint4 dv = {d0, d1, d2, d3};
      *(uint4*)&As[row*40 + q*8] = dv;
    }
    #pragma unroll
    for (int p = 0; p < 2; ++p) {
      int idx = tid + p*256;
      int j = idx >> 2, q = idx & 3;
      uint4 v = *(const uint4*)&Bb[((size_t)(bn + j))*KPk + k0 + q*8];
      *(uint4*)&Bs[j*40 + q*8] = v;
    }
    __syncthreads();
    short8 af[2], bf[8];
    #pragma unroll
    for (int mf = 0; mf < 2; ++mf)
      af[mf] = *(const short8*)&As[(w*32 + mf*16 + rl)*40 + kq*8];
    #pragma unroll
    for (int nf = 0; nf < 8; ++nf)
      bf[nf] = *(const short8*)&Bs[(nf*16 + rl)*40 + kq*8];
    #pragma unroll
    for (int mf = 0; mf < 2; ++mf)
      #pragma unroll
      for (int nf = 0; nf < 8; ++nf)
        acc[mf][nf] = __builtin_amdgcn_mfma_f32_16x16x32_bf16(af[mf], bf[nf], acc[mf][nf], 0, 0, 0);
  }
  // epilogue: C/D layout (m89): col = lane&15, row = (lane>>4)*4 + r
  #pragma unroll
  for (int mf = 0; mf < 2; ++mf)
    #pragma unroll
    for (int nf = 0; nf < 8; ++nf)
      #pragma unroll
      for (int r = 0; r < 4; ++r) {
        int gm = m0 + w*32 + mf*16 + kq*4 + r;
        int gn = bn + nf*16 + rl;
        if (gm < M && gn < Nc) {
          unsigned short v = f2bf(acc[mf][nf][r]);
          if (gn < split) XIb[(size_t)gm*split + gn] = v;
          else            XJb[(size_t)gm*split + (gn - split)] = v;
        }
      }
}

// ---------------- lin layer via MFMA ----------------
__global__ __launch_bounds__(256) void k_lin(
    const float* __restrict__ A, const unsigned short* __restrict__ Bb,
    const float* __restrict__ bias, float* __restrict__ Cm, int M)
{
  const int m0 = blockIdx.x * 64;
  const int tid = threadIdx.x;
  const int w = tid >> 6, lane = tid & 63;
  const int rl = lane & 15, kq = lane >> 4;
  __shared__ __align__(16) unsigned short As[64*40];
  __shared__ __align__(16) unsigned short Bs[128*40];
  f32x4 acc[8];
  #pragma unroll
  for (int nf = 0; nf < 8; ++nf) acc[nf] = (f32x4){0.f,0.f,0.f,0.f};
  for (int k0 = 0; k0 < 128; k0 += 32) {
    __syncthreads();
    {
      int row = tid >> 2, q = tid & 3;
      int gm = m0 + row;
      int gk = k0 + q*8;
      unsigned int d0=0,d1=0,d2=0,d3=0;
      if (gm < M && gk < H_) {
        if (gk + 8 <= H_) {
          const float4 v0 = *(const float4*)&A[(size_t)gm*H_ + gk];
          const float4 v1 = *(const float4*)&A[(size_t)gm*H_ + gk + 4];
          d0 = packbf(v0.x,v0.y); d1 = packbf(v0.z,v0.w);
          d2 = packbf(v1.x,v1.y); d3 = packbf(v1.z,v1.w);
        } else {
          float tmp[8];
          #pragma unroll
          for (int e = 0; e < 8; ++e) tmp[e] = (gk+e < H_) ? A[(size_t)gm*H_ + gk + e] : 0.f;
          d0 = packbf(tmp[0],tmp[1]); d1 = packbf(tmp[2],tmp[3]);
          d2 = packbf(tmp[4],tmp[5]); d3 = packbf(tmp[6],tmp[7]);
        }
      }
      uint4 dv = {d0,d1,d2,d3};
      *(uint4*)&As[row*40 + q*8] = dv;
    }
    #pragma unroll
    for (int p = 0; p < 2; ++p) {
      int idx = tid + p*256;
      int j = idx >> 2, q = idx & 3;
      uint4 v = *(const uint4*)&Bb[(size_t)j*128 + k0 + q*8];
      *(uint4*)&Bs[j*40 + q*8] = v;
    }
    __syncthreads();
    short8 af = *(const short8*)&As[(w*16 + rl)*40 + kq*8];
    #pragma unroll
    for (int nf = 0; nf < 8; ++nf) {
      short8 bf = *(const short8*)&Bs[(nf*16 + rl)*40 + kq*8];
      acc[nf] = __builtin_amdgcn_mfma_f32_16x16x32_bf16(af, bf, acc[nf], 0, 0, 0);
    }
  }
  #pragma unroll
  for (int nf = 0; nf < 8; ++nf)
    #pragma unroll
    for (int r = 0; r < 4; ++r) {
      int gm = m0 + w*16 + kq*4 + r;
      int gn = nf*16 + rl;
      if (gm < M && gn < H_)
        Cm[(size_t)gm*H_ + gn] = acc[nf][r] + bias[gn];
    }
}

// ---------------- per-node aggregation -> bf16 Apost rows ----------------
// template on block size: layer0 (f=16, 40 active lanes) uses 64-thread blocks.
template<int BT>
__global__ __launch_bounds__(BT) void k_agg(
    const unsigned short* __restrict__ XIb, const unsigned short* __restrict__ XJb,
    const int* __restrict__ rowptr, const int* __restrict__ srcs,
    const float* __restrict__ eav, const float* __restrict__ vec_e,
    const float* __restrict__ cst_e, const float* __restrict__ xin,
    unsigned short* __restrict__ Apost, int f, int C, int KP)
{
  __shared__ float vsh[512];
  const int tid = threadIdx.x;
  for (int c = tid; c < C; c += BT) vsh[c] = vec_e[c];
  __syncthreads();
  const int v = blockIdx.x;
  const int start = rowptr[v], end = rowptr[v+1];
  const int half = C >> 1;                 // C even
  const bool act = (tid < half);
  const float v0 = act ? vsh[tid*2]   : 0.f;
  const float v1 = act ? vsh[tid*2+1] : 0.f;
  const unsigned int* xj = (const unsigned int*)XJb;
  float s10 = 0.f, s11 = 0.f, s20 = 0.f, s21 = 0.f;
  float mn0 = 1e30f, mn1 = 1e30f, mx0 = -1e30f, mx1 = -1e30f;

  int p = start;
  for (; p + 8 <= end; p += 8) {
    int ss[8]; float aa[8];
    #pragma unroll
    for (int q = 0; q < 8; ++q) { ss[q] = srcs[p+q]; aa[q] = eav[p+q]; }
    if (act) {
      unsigned int uu[8];
      #pragma unroll
      for (int q = 0; q < 8; ++q) uu[q] = xj[(size_t)ss[q]*half + tid];
      #pragma unroll
      for (int q = 0; q < 8; ++q) {
        float y0 = fmaf(aa[q], v0, bf2f_lo(uu[q]));
        float y1 = fmaf(aa[q], v1, bf2f_hi(uu[q]));
        s10 += y0; s20 = fmaf(y0,y0,s20); mn0 = fminf(mn0,y0); mx0 = fmaxf(mx0,y0);
        s11 += y1; s21 = fmaf(y1,y1,s21); mn1 = fminf(mn1,y1); mx1 = fmaxf(mx1,y1);
      }
    }
  }
  for (; p < end; ++p) {
    int s = srcs[p];
    float a = eav[p];
    if (act) {
      unsigned int u = xj[(size_t)s*half + tid];
      float y0 = fmaf(a, v0, bf2f_lo(u));
      float y1 = fmaf(a, v1, bf2f_hi(u));
      s10 += y0; s20 = fmaf(y0, y0, s20);
      s11 += y1; s21 = fmaf(y1, y1, s21);
      mn0 = fminf(mn0, y0); mx0 = fmaxf(mx0, y0);
      mn1 = fminf(mn1, y1); mx1 = fmaxf(mx1, y1);
    }
  }

  const int dcnt = end - start;
  if (act) {
    int c0 = tid*2;
    int t = c0 / f, ff = c0 - t*f;
    unsigned int ub = ((const unsigned int*)XIb)[(size_t)v*half + tid];
    float base0 = bf2f_lo(ub) + cst_e[c0];
    float base1 = bf2f_hi(ub) + cst_e[c0 + 1];
    float me0, sd0, lo0, hi0, me1, sd1, lo1, hi1;
    if (dcnt > 0) {
      float inv = 1.0f / (float)dcnt;
      float m10 = s10 * inv, m11 = s11 * inv;
      me0 = base0 + m10; me1 = base1 + m11;
      sd0 = sqrtf(fmaxf(s20*inv - m10*m10, 0.f) + EPSF);
      sd1 = sqrtf(fmaxf(s21*inv - m11*m11, 0.f) + EPSF);
      lo0 = base0 + mn0; hi0 = base0 + mx0;
      lo1 = base1 + mn1; hi1 = base1 + mx1;
    } else {
      me0 = me1 = lo0 = lo1 = hi0 = hi1 = 0.f;
      sd0 = sd1 = sqrtf(EPSF);
    }
    unsigned int* od = (unsigned int*)(Apost + ((size_t)v * T_ + t) * KP);
    int fd = ff >> 1, f2 = f >> 1;
    od[fd]          = packbf(me0, me1);
    od[f2 + fd]     = packbf(lo0, lo1);
    od[2*f2 + fd]   = packbf(hi0, hi1);
    od[3*f2 + fd]   = packbf(sd0, sd1);
  }
  // x copy (shared by all towers) + zero pad
  const int rem = KP - 4*f;
  for (int idx = tid; idx < T_*rem; idx += BT) {
    int t = idx / rem, kk = idx - t*rem;
    int k = 4*f + kk;
    unsigned short val = 0;
    if (k < 5*f) val = f2bf(xin[(size_t)v*f + (k - 4*f)]);
    Apost[((size_t)v * T_ + t) * KP + k] = val;
  }
}

// ---------------- post GEMM via MFMA + fused scaler combine ----------------
__global__ __launch_bounds__(256) void k_postmm(
    const unsigned short* __restrict__ Apost, const unsigned short* __restrict__ W2,
    const float* __restrict__ scal, const float* __restrict__ qb,
    float* __restrict__ h, int KP)
{
  const int t    = blockIdx.y;
  const int m0   = blockIdx.x * 128;
  const int tid  = threadIdx.x;
  const int w    = tid >> 6;
  const int lane = tid & 63;
  const int rl   = lane & 15;
  const int kq   = lane >> 4;
  __shared__ __align__(16) unsigned char smem[128*84*4];
  unsigned short* As = (unsigned short*)smem;
  unsigned short* Bs = As + 128*40;
  f32x4 acc[2][5];
  #pragma unroll
  for (int mf = 0; mf < 2; ++mf)
    #pragma unroll
    for (int nf = 0; nf < 5; ++nf) acc[mf][nf] = (f32x4){0.f,0.f,0.f,0.f};

  const unsigned short* wt = W2 + (size_t)t * 80 * KP;

  for (int k0 = 0; k0 < KP; k0 += 32) {
    __syncthreads();
    #pragma unroll
    for (int p = 0; p < 2; ++p) {
      int idx = tid + p*256;
      int row = idx >> 2, q = idx & 3;
      int gm = m0 + row;
      uint4 v = {0u,0u,0u,0u};
      if (gm < N_) v = *(const uint4*)&Apost[((size_t)gm*T_ + t)*KP + k0 + q*8];
      *(uint4*)&As[row*40 + q*8] = v;
    }
    #pragma unroll
    for (int p = 0; p < 2; ++p) {
      int idx = tid + p*256;
      if (idx < 320) {
        int j = idx >> 2, q = idx & 3;
        uint4 v = *(const uint4*)&wt[(size_t)j*KP + k0 + q*8];
        *(uint4*)&Bs[j*40 + q*8] = v;
      }
    }
    __syncthreads();
    short8 af[2], bf[5];
    #pragma unroll
    for (int mf = 0; mf < 2; ++mf)
      af[mf] = *(const short8*)&As[(w*32 + mf*16 + rl)*40 + kq*8];
    #pragma unroll
    for (int nf = 0; nf < 5; ++nf)
      bf[nf] = *(const short8*)&Bs[(nf*16 + rl)*40 + kq*8];
    #pragma unroll
    for (int mf = 0; mf < 2; ++mf)
      #pragma unroll
      for (int nf = 0; nf < 5; ++nf)
        acc[mf][nf] = __builtin_amdgcn_mfma_f32_16x16x32_bf16(af[mf], bf[nf], acc[mf][nf], 0, 0, 0);
  }
  __syncthreads();
  float (*Pl)[84] = (float (*)[84])smem;
  #pragma unroll
  for (int mf = 0; mf < 2; ++mf)
    #pragma unroll
    for (int nf = 0; nf < 5; ++nf)
      #pragma unroll
      for (int r = 0; r < 4; ++r)
        Pl[w*32 + mf*16 + kq*4 + r][nf*16 + rl] = acc[mf][nf][r];
  __syncthreads();
  for (int idx = tid; idx < 128*FO_; idx += 256) {
    int row = idx / FO_, g = idx - row*FO_;
    int n = m0 + row;
    if (n < N_) {
      const float* p = Pl[row];
      float4 sc = *(const float4*)&scal[n*4];
      h[(size_t)n*(T_*FO_) + t*FO_ + g] =
        p[g] + sc.y*p[20+g] + sc.z*p[40+g] + sc.w*p[60+g] + qb[t*FO_+g];
    }
  }
}

// ---------------- batch norm ----------------
__global__ __launch_bounds__(256) void k_bnsum(const float* __restrict__ h2, float* __restrict__ bnsum) {
  const int tid  = threadIdx.x;
  const int c    = tid & 127;
  const int half = tid >> 7;
  if (c >= H_) return;
  float s = 0.f, s2 = 0.f;
  for (int r = blockIdx.x * 2 + half; r < N_; r += 256) {
    float v = h2[(size_t)r * H_ + c];
    s += v; s2 = fmaf(v, v, s2);
  }
  atomicAdd(&bnsum[c], s);
  atomicAdd(&bnsum[H_ + c], s2);
}

__global__ void k_bnapply(const float* __restrict__ h2, const float* __restrict__ bnsum,
                          const float* __restrict__ gam, const float* __restrict__ bet,
                          float* __restrict__ out) {
  size_t i = (size_t)blockIdx.x * blockDim.x + threadIdx.x;
  if (i >= (size_t)N_*H_) return;
  int c = (int)(i % H_);
  const float invn = 1.0f / (float)N_;
  float mu  = bnsum[c] * invn;
  float var = bnsum[H_ + c] * invn - mu*mu;
  float y = (h2[i] - mu) * rsqrtf(var + EPSF) * gam[c] + bet[c];
  out[i] = fmaxf(y, 0.f);
}

// ---------------- pooling (fused gcnt) + MLP ----------------
__global__ __launch_bounds__(256) void k_pool(const float* __restrict__ xc, const int* __restrict__ batch,
                                              float* __restrict__ gsum, int* __restrict__ gcnt) {
  __shared__ float Pl[B_][H_];
  __shared__ int cl[B_];
  const int tid = threadIdx.x;
  for (int i = tid; i < B_*H_; i += 256) Pl[i / H_][i % H_] = 0.f;
  for (int i = tid; i < B_; i += 256) cl[i] = 0;
  __syncthreads();
  const int r0 = blockIdx.x * PR_;
  const int rend = (r0 + PR_ < N_) ? r0 + PR_ : N_;
  for (int rr = tid; rr < rend - r0; rr += 256) atomicAdd(&cl[batch[r0 + rr]], 1);
  const int nel = (rend - r0) * H_;
  for (int idx = tid; idx < nel; idx += 256) {
    int rr = idx / H_, c = idx - rr*H_;
    int n = r0 + rr;
    atomicAdd(&Pl[batch[n]][c], xc[(size_t)n*H_ + c]);
  }
  __syncthreads();
  const int blo = batch[r0], bhi = batch[rend-1];
  const int nb = (bhi - blo + 1) * H_;
  for (int idx = tid; idx < nb; idx += 256) {
    int b = blo + idx / H_, c = idx % H_;
    atomicAdd(&gsum[(size_t)b*H_ + c], Pl[b][c]);
  }
  for (int b = blo + tid; b <= bhi; b += 256) atomicAdd(&gcnt[b], cl[b]);
}

__global__ __launch_bounds__(512) void k_mlp(
    const float* __restrict__ gsum, const int* __restrict__ gcnt,
    const float* __restrict__ w1, const float* __restrict__ b1,
    const float* __restrict__ w2, const float* __restrict__ b2,
    const float* __restrict__ w3, const float* __restrict__ b3,
    float* __restrict__ out)
{
  __shared__ float G[B_][H_];
  __shared__ float A1[B_][50];
  __shared__ float A2[B_][25];
  const int tid = threadIdx.x;
  for (int i = tid; i < B_*H_; i += 512) {
    int r = i / H_;
    G[r][i - r*H_] = gsum[i] / fmaxf((float)gcnt[r], 1.0f);
  }
  __syncthreads();
  for (int i = tid; i < B_*50; i += 512) {
    int r = i / 50, c = i - r*50;
    float a = b1[c];
    for (int k = 0; k < H_; ++k) a = fmaf(G[r][k], w1[k*50 + c], a);
    A1[r][c] = fmaxf(a, 0.f);
  }
  __syncthreads();
  for (int i = tid; i < B_*25; i += 512) {
    int r = i / 25, c = i - r*25;
    float a = b2[c];
    for (int k = 0; k < 50; ++k) a = fmaf(A1[r][k], w2[k*25 + c], a);
    A2[r][c] = fmaxf(a, 0.f);
  }
  __syncthreads();
  for (int i = tid; i < B_; i += 512) {
    float a = b3[0];
    for (int k = 0; k < 25; ++k) a = fmaf(A2[i][k], w3[k], a);
    out[i] = a;   // float32 output — reference output dtype is f32
  }
}

// ---------------- host ----------------
extern "C" void kernel_launch(void* const* d_in, const int* in_sizes, int n_in,
                              void* d_out, int out_size, void* d_ws, size_t ws_size,
                              hipStream_t stream)
{
  (void)in_sizes; (void)n_in; (void)out_size;
  const float* x0   = (const float*)d_in[0];
  const int*   eidx = (const int*)  d_in[1];
  const float* ea   = (const float*)d_in[2];
  const int*   batch= (const int*)  d_in[3];
  const float* e0w  = (const float*)d_in[4];
  const float* e0b  = (const float*)d_in[5];
  const float* p0w  = (const float*)d_in[6];
  const float* p0b  = (const float*)d_in[7];
  const float* q0w  = (const float*)d_in[8];
  const float* q0b  = (const float*)d_in[9];
  const float* l0w  = (const float*)d_in[10];
  const float* l0b  = (const float*)d_in[11];
  const float* g0   = (const float*)d_in[12];
  const float* b0   = (const float*)d_in[13];
  const float* eLw  = (const float*)d_in[14];
  const float* eLb  = (const float*)d_in[15];
  const float* pLw  = (const float*)d_in[16];
  const float* pLb  = (const float*)d_in[17];
  const float* qLw  = (const float*)d_in[18];
  const float* qLb  = (const float*)d_in[19];
  const float* lLw  = (const float*)d_in[20];
  const float* lLb  = (const float*)d_in[21];
  const float* gL   = (const float*)d_in[22];
  const float* bL   = (const float*)d_in[23];
  const float* w1   = (const float*)d_in[24];
  const float* b1   = (const float*)d_in[25];
  const float* w2   = (const float*)d_in[26];
  const float* b2   = (const float*)d_in[27];
  const float* w3   = (const float*)d_in[28];
  const float* b3   = (const float*)d_in[29];

  const int* src = eidx;
  const int* dst = eidx + E_;

  char* w = (char*)d_ws;
  size_t off = 0;
  auto take = [&](size_t bytes) -> void* {
    void* p = (void*)(w + off);
    off = (off + bytes + 255) & ~(size_t)255;
    return p;
  };
  int*   cnt    = (int*)  take((size_t)N_*4);
  int*   rowptr = (int*)  take((size_t)(N_+1)*4);
  int*   cursor = (int*)  take((size_t)N_*4);
  int*   srcs   = (int*)  take((size_t)E_*4);
  float* eav    = (float*)take((size_t)E_*4);
  float* scal   = (float*)take((size_t)N_*16);
  float* sumlog = (float*)take(256);
  float* bnsum3 = (float*)take((size_t)3*256*4);
  float* vec_e3 = (float*)take((size_t)3*512*4);
  float* cst_e3 = (float*)take((size_t)3*512*4);
  unsigned short* BpreT3 = (unsigned short*)take((size_t)3*131072*2);
  unsigned short* W23    = (unsigned short*)take((size_t)3*204800*2);
  unsigned short* LwT3   = (unsigned short*)take((size_t)3*16384*2);
  unsigned short* XIb    = (unsigned short*)take((size_t)N_*T_*H_*2);   // 20 MB bf16
  unsigned short* XJb    = (unsigned short*)take((size_t)N_*T_*H_*2);   // 20 MB
  unsigned short* Apost  = (unsigned short*)take((size_t)N_*T_*512*2);  // 102 MB
  float* hbuf   = (float*)take((size_t)N_*H_*4);
  float* h2buf  = (float*)take((size_t)N_*H_*4);
  float* xcur   = (float*)take((size_t)N_*H_*4);
  float* gsum   = (float*)take((size_t)B_*H_*4);
  int*   gcnt   = (int*)  take((size_t)B_*4);
  if (off > ws_size) return;   // workspace too small: bail (test fails loudly)

  hipMemsetAsync(cnt,    0, (size_t)N_*4, stream);
  hipMemsetAsync(cursor, 0, (size_t)N_*4, stream);
  hipMemsetAsync(sumlog, 0, 4, stream);
  hipMemsetAsync(bnsum3, 0, (size_t)3*256*4, stream);
  hipMemsetAsync(gsum,   0, (size_t)B_*H_*4, stream);
  hipMemsetAsync(gcnt,   0, (size_t)B_*4, stream);

  // batched weight prep (independent of graph / activations)
  k_edgevec3 <<<dim3(2, 3),   dim3(256), 0, stream>>>(p0w, pLw, p0b, pLb, e0w, eLw, e0b, eLb, vec_e3, cst_e3);
  k_pack_preT3<<<dim3(512, 3), dim3(256), 0, stream>>>(p0w, pLw, BpreT3);
  k_pack_w23 <<<dim3(800, 3), dim3(256), 0, stream>>>(q0w, qLw, W23);
  k_pack_lin3<<<dim3(64, 3),  dim3(256), 0, stream>>>(l0w, lLw, LwT3);

  k_count <<<dim3((E_+255)/256), dim3(256), 0, stream>>>(dst, cnt);
  k_scan  <<<dim3(1),            dim3(1024),0, stream>>>(cnt, rowptr);
  k_fill  <<<dim3((E_+255)/256), dim3(256), 0, stream>>>(src, dst, ea, rowptr, cursor, srcs, eav);
  k_sumlog<<<dim3((N_+255)/256), dim3(256), 0, stream>>>(cnt, sumlog);
  k_scal  <<<dim3((N_+255)/256), dim3(256), 0, stream>>>(cnt, sumlog, scal);

  auto layer = [&](int l, const float* xin, int f,
                   const float* qb, const float* lb, const float* bg, const float* bb) {
    const int C   = T_ * f;
    const int KP  = ((5*f + 31) / 32) * 32;
    const int KPk = ((f + 31) / 32) * 32;
    const int gN  = (2*C + 127) / 128;
    const float* vec_e = vec_e3 + l*512;
    const float* cst_e = cst_e3 + l*512;
    const unsigned short* BpreT = BpreT3 + (size_t)l*131072;
    const unsigned short* W2    = W23    + (size_t)l*204800;
    const unsigned short* LwT   = LwT3   + (size_t)l*16384;
    float* bnsum = bnsum3 + l*256;
    k_mmsplit<<<dim3((N_+127)/128, gN), dim3(256), 0, stream>>>(xin, BpreT, XIb, XJb, N_, f, KPk, C);
    if (f == FI_)
      k_agg<64><<<dim3(N_), dim3(64), 0, stream>>>(XIb, XJb, rowptr, srcs, eav, vec_e, cst_e, xin, Apost, f, C, KP);
    else
      k_agg<256><<<dim3(N_), dim3(256), 0, stream>>>(XIb, XJb, rowptr, srcs, eav, vec_e, cst_e, xin, Apost, f, C, KP);
    k_postmm<<<dim3((N_+127)/128, T_), dim3(256), 0, stream>>>(Apost, W2, scal, qb, hbuf, KP);
    k_lin<<<dim3((N_+63)/64), dim3(256), 0, stream>>>(hbuf, LwT, lb, h2buf, N_);
    k_bnsum<<<dim3(128), dim3(256), 0, stream>>>(h2buf, bnsum);
    k_bnapply<<<dim3((unsigned)(((size_t)N_*H_+255)/256)), dim3(256), 0, stream>>>(h2buf, bnsum, bg, bb, xcur);
  };

  layer(0, x0,   FI_, q0b, l0b, g0, b0);
  layer(1, xcur, H_,  qLb, lLb, gL, bL);
  layer(2, xcur, H_,  qLb + T_*FO_, lLb + H_, gL + H_, bL + H_);

  k_pool<<<dim3((N_+PR_-1)/PR_), dim3(256), 0, stream>>>(xcur, batch, gsum, gcnt);
  k_mlp <<<dim3(1), dim3(512), 0, stream>>>(gsum, gcnt, w1, b1, w2, b2, w3, b3, (float*)d_out);
}

// Round 14
// 703.758 us; speedup vs baseline: 2.3326x; 1.0803x over previous
//
#include <hip/hip_runtime.h>
#include <hip/hip_bf16.h>
#include <cstddef>

#define N_  20000
#define E_  320000
#define FI_ 16
#define H_  100
#define T_  5
#define FO_ 20
#define B_  50
#define EPSF 1e-5f
#define PR_  200    // k_pool rows per block

typedef __attribute__((ext_vector_type(8))) short short8;
typedef __attribute__((ext_vector_type(4))) float f32x4;
typedef __attribute__((ext_vector_type(2))) float f32x2;

static __device__ __forceinline__ unsigned short f2bf(float x) {
  unsigned int u = __builtin_bit_cast(unsigned int, x);
  unsigned int r = (u + 0x7FFFu + ((u >> 16) & 1u)) >> 16;   // RNE
  return (unsigned short)r;
}
static __device__ __forceinline__ unsigned int packbf(float a, float b) {
  return (unsigned int)f2bf(a) | ((unsigned int)f2bf(b) << 16);
}
static __device__ __forceinline__ float bf2f_lo(unsigned int u) {
  return __builtin_bit_cast(float, (u & 0xFFFFu) << 16);
}
static __device__ __forceinline__ float bf2f_hi(unsigned int u) {
  return __builtin_bit_cast(float, u & 0xFFFF0000u);
}

// ---------------- graph prep ----------------
__global__ void k_count(const int* __restrict__ dst, int* __restrict__ cnt) {
  int e = blockIdx.x * blockDim.x + threadIdx.x;
  if (e < E_) atomicAdd(&cnt[dst[e]], 1);
}

__global__ __launch_bounds__(1024) void k_scan(const int* __restrict__ cnt, int* __restrict__ rowptr) {
  __shared__ int ls[1024];
  const int tid = threadIdx.x;
  const int base = tid * 20;
  int loc[20];
  int lsum = 0;
  #pragma unroll
  for (int i = 0; i < 20; ++i) {
    int idx = base + i;
    int v = (idx < N_) ? cnt[idx] : 0;
    loc[i] = lsum;
    lsum += v;
  }
  ls[tid] = lsum;
  __syncthreads();
  for (int off = 1; off < 1024; off <<= 1) {
    int t = (tid >= off) ? ls[tid - off] : 0;
    __syncthreads();
    ls[tid] += t;
    __syncthreads();
  }
  const int pre = (tid > 0) ? ls[tid - 1] : 0;
  #pragma unroll
  for (int i = 0; i < 20; ++i) {
    int idx = base + i;
    if (idx < N_) rowptr[idx] = pre + loc[i];
  }
  if (tid == 1023) rowptr[N_] = ls[1023];
}

__global__ void k_fill(const int* __restrict__ src, const int* __restrict__ dst,
                       const float* __restrict__ ea, const int* __restrict__ rowptr,
                       int* __restrict__ cursor, int* __restrict__ srcs,
                       float* __restrict__ eav) {
  int e = blockIdx.x * blockDim.x + threadIdx.x;
  if (e < E_) {
    int v = dst[e];
    int p = atomicAdd(&cursor[v], 1);
    int pos = rowptr[v] + p;
    srcs[pos] = src[e];
    eav[pos]  = ea[e];
  }
}

__global__ void k_sumlog(const int* __restrict__ cnt, float* __restrict__ sumlog) {
  int i = blockIdx.x * blockDim.x + threadIdx.x;
  float v = (i < N_) ? logf((float)cnt[i] + 1.0f) : 0.0f;
  #pragma unroll
  for (int off = 32; off > 0; off >>= 1) v += __shfl_down(v, off);
  __shared__ float red[4];
  if ((threadIdx.x & 63) == 0) red[threadIdx.x >> 6] = v;
  __syncthreads();
  if (threadIdx.x == 0) atomicAdd(sumlog, red[0] + red[1] + red[2] + red[3]);
}

__global__ void k_scal(const int* __restrict__ cnt, const float* __restrict__ sumlog,
                       float* __restrict__ scal) {
  int i = blockIdx.x * blockDim.x + threadIdx.x;
  if (i >= N_) return;
  float c  = (float)cnt[i];
  float d  = fmaxf(c, 1.0f);
  float ld = logf(d + 1.0f);
  float avg_log = sumlog[0] * (1.0f / (float)N_);
  float avg_lin = (float)E_ / (float)N_;
  scal[i*4+0] = 1.0f;
  scal[i*4+1] = ld / avg_log;
  scal[i*4+2] = avg_log / ld;
  scal[i*4+3] = d / avg_lin;
}

// x0 fp32 -> bf16 (layer0 activations, stride 16)
__global__ void k_cvtx(const float* __restrict__ x0, unsigned int* __restrict__ x0b) {
  int i = blockIdx.x * blockDim.x + threadIdx.x;
  if (i >= N_*FI_/2) return;
  x0b[i] = packbf(x0[2*i], x0[2*i+1]);
}

// ---------------- batched weight prep (all 3 layers, gridDim.y = layer) ----------------
__global__ void k_edgevec3(const float* __restrict__ p0w, const float* __restrict__ pLw,
                           const float* __restrict__ p0b, const float* __restrict__ pLb,
                           const float* __restrict__ e0w, const float* __restrict__ eLw,
                           const float* __restrict__ e0b, const float* __restrict__ eLb,
                           float* __restrict__ vec_e3, float* __restrict__ cst_e3) {
  const int l = blockIdx.y;
  const int f = l ? H_ : FI_;
  const int C = T_ * f;
  int c = blockIdx.x * blockDim.x + threadIdx.x;
  if (c >= C) return;
  const float* pw = l ? pLw + (size_t)(l-1)*T_*3*H_*H_ : p0w;
  const float* pb = l ? pLb + (l-1)*T_*H_ : p0b;
  const float* ew = l ? eLw + (l-1)*H_ : e0w;
  const float* eb = l ? eLb + (l-1)*H_ : e0b;
  int t = c / f, g = c - t*f;
  const float* wp = pw + (size_t)t*3*f*f + (size_t)2*f*f + g;
  float v = 0.f, s = 0.f;
  for (int ff = 0; ff < f; ++ff) { float wv = wp[(size_t)ff*f]; v += ew[ff]*wv; s += eb[ff]*wv; }
  vec_e3[l*512 + c] = v;
  cst_e3[l*512 + c] = s + pb[c];
}

__global__ void k_pack_preT3(const float* __restrict__ p0w, const float* __restrict__ pLw,
                             unsigned short* __restrict__ Bb3) {
  const int l = blockIdx.y;
  const int f = l ? H_ : FI_;
  const int C = T_ * f;
  const int KPk = l ? 128 : 32;
  const int NcPad = l ? 1024 : 256;
  const int tot = NcPad * KPk;
  int idx = blockIdx.x * blockDim.x + threadIdx.x;
  if (idx >= tot) return;
  const float* pw = l ? pLw + (size_t)(l-1)*T_*3*H_*H_ : p0w;
  int k = idx % KPk, c = idx / KPk;
  float v = 0.f;
  if (c < 2*C && k < f) {
    int half = c / C, cc = c - half*C;
    int t = cc / f, g = cc - t*f;
    v = pw[(size_t)t*3*f*f + (size_t)(half*f + k)*f + g];
  }
  Bb3[(size_t)l*131072 + idx] = f2bf(v);
}

__global__ void k_pack_w23(const float* __restrict__ q0w, const float* __restrict__ qLw,
                           unsigned short* __restrict__ W23) {
  const int l = blockIdx.y;
  const int f = l ? H_ : FI_;
  const int KP = l ? 512 : 96;
  const int tot = T_ * 80 * KP;
  int idx = blockIdx.x * blockDim.x + threadIdx.x;
  if (idx >= tot) return;
  const float* qw = l ? qLw + (size_t)(l-1)*T_*17*H_*FO_ : q0w;
  int k = idx % KP;
  int r = idx / KP;
  int j = r % 80;
  int t = r / 80;
  int s = j / 20, g = j - s*20;
  float v = 0.f;
  if (k < 4*f)                 v = qw[((size_t)t*17*f + f + (size_t)s*4*f + k) * FO_ + g];
  else if (k < 5*f && s == 0)  v = qw[((size_t)t*17*f + (k - 4*f)) * FO_ + g];
  W23[(size_t)l*204800 + idx] = f2bf(v);
}

__global__ void k_pack_lin3(const float* __restrict__ l0w, const float* __restrict__ lLw,
                            unsigned short* __restrict__ Lb3) {
  const int l = blockIdx.y;
  int idx = blockIdx.x * blockDim.x + threadIdx.x;
  if (idx >= 128*128) return;
  const float* lw = l ? lLw + (size_t)(l-1)*H_*H_ : l0w;
  int k = idx & 127, j = idx >> 7;
  float v = (j < H_ && k < H_) ? lw[(size_t)k*H_ + j] : 0.f;
  Lb3[(size_t)l*16384 + idx] = f2bf(v);
}

// ---------------- pre-GEMM via MFMA (bf16 A), split epilogue ----------------
__global__ __launch_bounds__(256) void k_mmsplit(
    const unsigned short* __restrict__ Ab, const unsigned short* __restrict__ Bb,
    unsigned short* __restrict__ XIb, unsigned short* __restrict__ XJb,
    int M, int KA, int KPk, int split)
{
  const int m0 = blockIdx.x * 128;
  const int bn = blockIdx.y * 128;
  const int Nc = 2 * split;
  const int tid = threadIdx.x;
  const int w = tid >> 6, lane = tid & 63;
  const int rl = lane & 15, kq = lane >> 4;
  __shared__ __align__(16) unsigned short As[128*40];
  __shared__ __align__(16) unsigned short Bs[128*40];
  f32x4 acc[2][8];
  #pragma unroll
  for (int mf = 0; mf < 2; ++mf)
    #pragma unroll
    for (int nf = 0; nf < 8; ++nf) acc[mf][nf] = (f32x4){0.f,0.f,0.f,0.f};

  for (int k0 = 0; k0 < KPk; k0 += 32) {
    __syncthreads();
    // stage A: 128 rows x 32 k, bf16 direct copy (pad cols pre-zeroed)
    #pragma unroll
    for (int p = 0; p < 2; ++p) {
      int idx = tid + p*256;
      int row = idx >> 2, q = idx & 3;
      int gm = m0 + row;
      int gk = k0 + q*8;
      uint4 v = {0u,0u,0u,0u};
      if (gm < M && gk + 8 <= KA) v = *(const uint4*)&Ab[(size_t)gm*KA + gk];
      *(uint4*)&As[row*40 + q*8] = v;
    }
    #pragma unroll
    for (int p = 0; p < 2; ++p) {
      int idx = tid + p*256;
      int j = idx >> 2, q = idx & 3;
      uint4 v = *(const uint4*)&Bb[((size_t)(bn + j))*KPk + k0 + q*8];
      *(uint4*)&Bs[j*40 + q*8] = v;
    }
    __syncthreads();
    short8 af[2], bf[8];
    #pragma unroll
    for (int mf = 0; mf < 2; ++mf)
      af[mf] = *(const short8*)&As[(w*32 + mf*16 + rl)*40 + kq*8];
    #pragma unroll
    for (int nf = 0; nf < 8; ++nf)
      bf[nf] = *(const short8*)&Bs[(nf*16 + rl)*40 + kq*8];
    #pragma unroll
    for (int mf = 0; mf < 2; ++mf)
      #pragma unroll
      for (int nf = 0; nf < 8; ++nf)
        acc[mf][nf] = __builtin_amdgcn_mfma_f32_16x16x32_bf16(af[mf], bf[nf], acc[mf][nf], 0, 0, 0);
  }
  // epilogue: C/D layout (m89): col = lane&15, row = (lane>>4)*4 + r
  #pragma unroll
  for (int mf = 0; mf < 2; ++mf)
    #pragma unroll
    for (int nf = 0; nf < 8; ++nf)
      #pragma unroll
      for (int r = 0; r < 4; ++r) {
        int gm = m0 + w*32 + mf*16 + kq*4 + r;
        int gn = bn + nf*16 + rl;
        if (gm < M && gn < Nc) {
          unsigned short v = f2bf(acc[mf][nf][r]);
          if (gn < split) XIb[(size_t)gm*split + gn] = v;
          else            XJb[(size_t)gm*split + (gn - split)] = v;
        }
      }
}

// ---------------- lin layer via MFMA + fused BN stats ----------------
__global__ __launch_bounds__(256) void k_linbn(
    const float* __restrict__ A, const unsigned short* __restrict__ Bb,
    const float* __restrict__ bias, float* __restrict__ Cm,
    float* __restrict__ bnsum, int M)
{
  const int m0 = blockIdx.x * 64;
  const int tid = threadIdx.x;
  const int w = tid >> 6, lane = tid & 63;
  const int rl = lane & 15, kq = lane >> 4;
  __shared__ __align__(16) unsigned short As[64*40];
  __shared__ __align__(16) unsigned short Bs[128*40];
  __shared__ float bns[4][128];
  __shared__ float bnq[4][128];
  f32x4 acc[8];
  #pragma unroll
  for (int nf = 0; nf < 8; ++nf) acc[nf] = (f32x4){0.f,0.f,0.f,0.f};
  for (int k0 = 0; k0 < 128; k0 += 32) {
    __syncthreads();
    {
      int row = tid >> 2, q = tid & 3;
      int gm = m0 + row;
      int gk = k0 + q*8;
      unsigned int d0=0,d1=0,d2=0,d3=0;
      if (gm < M && gk < H_) {
        if (gk + 8 <= H_) {
          const float4 v0 = *(const float4*)&A[(size_t)gm*H_ + gk];
          const float4 v1 = *(const float4*)&A[(size_t)gm*H_ + gk + 4];
          d0 = packbf(v0.x,v0.y); d1 = packbf(v0.z,v0.w);
          d2 = packbf(v1.x,v1.y); d3 = packbf(v1.z,v1.w);
        } else {
          float tmp[8];
          #pragma unroll
          for (int e = 0; e < 8; ++e) tmp[e] = (gk+e < H_) ? A[(size_t)gm*H_ + gk + e] : 0.f;
          d0 = packbf(tmp[0],tmp[1]); d1 = packbf(tmp[2],tmp[3]);
          d2 = packbf(tmp[4],tmp[5]); d3 = packbf(tmp[6],tmp[7]);
        }
      }
      uint4 dv = {d0,d1,d2,d3};
      *(uint4*)&As[row*40 + q*8] = dv;
    }
    #pragma unroll
    for (int p = 0; p < 2; ++p) {
      int idx = tid + p*256;
      int j = idx >> 2, q = idx & 3;
      uint4 v = *(const uint4*)&Bb[(size_t)j*128 + k0 + q*8];
      *(uint4*)&Bs[j*40 + q*8] = v;
    }
    __syncthreads();
    short8 af = *(const short8*)&As[(w*16 + rl)*40 + kq*8];
    #pragma unroll
    for (int nf = 0; nf < 8; ++nf) {
      short8 bf = *(const short8*)&Bs[(nf*16 + rl)*40 + kq*8];
      acc[nf] = __builtin_amdgcn_mfma_f32_16x16x32_bf16(af, bf, acc[nf], 0, 0, 0);
    }
  }
  #pragma unroll
  for (int nf = 0; nf < 8; ++nf) {
    int gn = nf*16 + rl;
    float cs = 0.f, cq = 0.f;
    #pragma unroll
    for (int r = 0; r < 4; ++r) {
      int gm = m0 + w*16 + kq*4 + r;
      if (gm < M && gn < H_) {
        float v = acc[nf][r] + bias[gn];
        Cm[(size_t)gm*H_ + gn] = v;
        cs += v; cq = fmaf(v, v, cq);
      }
    }
    // reduce over kq (lane bits 4,5)
    cs += __shfl_xor(cs, 16); cs += __shfl_xor(cs, 32);
    cq += __shfl_xor(cq, 16); cq += __shfl_xor(cq, 32);
    if (kq == 0) { bns[w][gn] = cs; bnq[w][gn] = cq; }
  }
  __syncthreads();
  if (tid < H_) {
    float s = bns[0][tid] + bns[1][tid] + bns[2][tid] + bns[3][tid];
    float q = bnq[0][tid] + bnq[1][tid] + bnq[2][tid] + bnq[3][tid];
    atomicAdd(&bnsum[tid], s);
    atomicAdd(&bnsum[H_ + tid], q);
  }
}

// ---------------- per-node aggregation -> bf16 Apost rows ----------------
// packed float2 math; 8-way edge unroll; bf16 x-copy.
template<int BT>
__global__ __launch_bounds__(BT) void k_agg(
    const unsigned short* __restrict__ XIb, const unsigned short* __restrict__ XJb,
    const int* __restrict__ rowptr, const int* __restrict__ srcs,
    const float* __restrict__ eav, const float* __restrict__ vec_e,
    const float* __restrict__ cst_e, const unsigned short* __restrict__ xb,
    unsigned short* __restrict__ Apost, int f, int C, int KP, int KA)
{
  __shared__ float vsh[512];
  const int tid = threadIdx.x;
  for (int c = tid; c < C; c += BT) vsh[c] = vec_e[c];
  __syncthreads();
  const int v = blockIdx.x;
  const int start = rowptr[v], end = rowptr[v+1];
  const int half = C >> 1;
  const bool act = (tid < half);
  f32x2 vv = {act ? vsh[tid*2] : 0.f, act ? vsh[tid*2+1] : 0.f};
  const unsigned int* xj = (const unsigned int*)XJb;
  f32x2 s1 = {0.f, 0.f}, s2 = {0.f, 0.f};
  f32x2 mn = {1e30f, 1e30f}, mx = {-1e30f, -1e30f};

  int p = start;
  for (; p + 8 <= end; p += 8) {
    int ss[8]; float aa[8];
    #pragma unroll
    for (int q = 0; q < 8; ++q) { ss[q] = srcs[p+q]; aa[q] = eav[p+q]; }
    if (act) {
      unsigned int uu[8];
      #pragma unroll
      for (int q = 0; q < 8; ++q) uu[q] = xj[(size_t)ss[q]*half + tid];
      #pragma unroll
      for (int q = 0; q < 8; ++q) {
        f32x2 u2 = {bf2f_lo(uu[q]), bf2f_hi(uu[q])};
        f32x2 a2 = {aa[q], aa[q]};
        f32x2 y = __builtin_elementwise_fma(a2, vv, u2);
        s1 += y;
        s2 = __builtin_elementwise_fma(y, y, s2);
        mn = __builtin_elementwise_min(mn, y);
        mx = __builtin_elementwise_max(mx, y);
      }
    }
  }
  for (; p < end; ++p) {
    int s = srcs[p];
    float a = eav[p];
    if (act) {
      unsigned int u = xj[(size_t)s*half + tid];
      f32x2 u2 = {bf2f_lo(u), bf2f_hi(u)};
      f32x2 a2 = {a, a};
      f32x2 y = __builtin_elementwise_fma(a2, vv, u2);
      s1 += y;
      s2 = __builtin_elementwise_fma(y, y, s2);
      mn = __builtin_elementwise_min(mn, y);
      mx = __builtin_elementwise_max(mx, y);
    }
  }

  const int dcnt = end - start;
  if (act) {
    int c0 = tid*2;
    int t = c0 / f, ff = c0 - t*f;
    unsigned int ub = ((const unsigned int*)XIb)[(size_t)v*half + tid];
    float base0 = bf2f_lo(ub) + cst_e[c0];
    float base1 = bf2f_hi(ub) + cst_e[c0 + 1];
    float me0, sd0, lo0, hi0, me1, sd1, lo1, hi1;
    if (dcnt > 0) {
      float inv = 1.0f / (float)dcnt;
      float m10 = s1.x * inv, m11 = s1.y * inv;
      me0 = base0 + m10; me1 = base1 + m11;
      sd0 = sqrtf(fmaxf(s2.x*inv - m10*m10, 0.f) + EPSF);
      sd1 = sqrtf(fmaxf(s2.y*inv - m11*m11, 0.f) + EPSF);
      lo0 = base0 + mn.x; hi0 = base0 + mx.x;
      lo1 = base1 + mn.y; hi1 = base1 + mx.y;
    } else {
      me0 = me1 = lo0 = lo1 = hi0 = hi1 = 0.f;
      sd0 = sd1 = sqrtf(EPSF);
    }
    unsigned int* od = (unsigned int*)(Apost + ((size_t)v * T_ + t) * KP);
    int fd = ff >> 1, f2 = f >> 1;
    od[fd]          = packbf(me0, me1);
    od[f2 + fd]     = packbf(lo0, lo1);
    od[2*f2 + fd]   = packbf(hi0, hi1);
    od[3*f2 + fd]   = packbf(sd0, sd1);
  }
  // x copy (bf16 source) + zero pad
  const int rem = KP - 4*f;
  for (int idx = tid; idx < T_*rem; idx += BT) {
    int t = idx / rem, kk = idx - t*rem;
    int k = 4*f + kk;
    unsigned short val = 0;
    if (k < 5*f) val = xb[(size_t)v*KA + (k - 4*f)];
    Apost[((size_t)v * T_ + t) * KP + k] = val;
  }
}

// ---------------- post GEMM via MFMA + fused scaler combine ----------------
__global__ __launch_bounds__(256) void k_postmm(
    const unsigned short* __restrict__ Apost, const unsigned short* __restrict__ W2,
    const float* __restrict__ scal, const float* __restrict__ qb,
    float* __restrict__ h, int KP)
{
  const int t    = blockIdx.y;
  const int m0   = blockIdx.x * 128;
  const int tid  = threadIdx.x;
  const int w    = tid >> 6;
  const int lane = tid & 63;
  const int rl   = lane & 15;
  const int kq   = lane >> 4;
  __shared__ __align__(16) unsigned char smem[128*84*4];
  unsigned short* As = (unsigned short*)smem;
  unsigned short* Bs = As + 128*40;
  f32x4 acc[2][5];
  #pragma unroll
  for (int mf = 0; mf < 2; ++mf)
    #pragma unroll
    for (int nf = 0; nf < 5; ++nf) acc[mf][nf] = (f32x4){0.f,0.f,0.f,0.f};

  const unsigned short* wt = W2 + (size_t)t * 80 * KP;

  for (int k0 = 0; k0 < KP; k0 += 32) {
    __syncthreads();
    #pragma unroll
    for (int p = 0; p < 2; ++p) {
      int idx = tid + p*256;
      int row = idx >> 2, q = idx & 3;
      int gm = m0 + row;
      uint4 v = {0u,0u,0u,0u};
      if (gm < N_) v = *(const uint4*)&Apost[((size_t)gm*T_ + t)*KP + k0 + q*8];
      *(uint4*)&As[row*40 + q*8] = v;
    }
    #pragma unroll
    for (int p = 0; p < 2; ++p) {
      int idx = tid + p*256;
      if (idx < 320) {
        int j = idx >> 2, q = idx & 3;
        uint4 v = *(const uint4*)&wt[(size_t)j*KP + k0 + q*8];
        *(uint4*)&Bs[j*40 + q*8] = v;
      }
    }
    __syncthreads();
    short8 af[2], bf[5];
    #pragma unroll
    for (int mf = 0; mf < 2; ++mf)
      af[mf] = *(const short8*)&As[(w*32 + mf*16 + rl)*40 + kq*8];
    #pragma unroll
    for (int nf = 0; nf < 5; ++nf)
      bf[nf] = *(const short8*)&Bs[(nf*16 + rl)*40 + kq*8];
    #pragma unroll
    for (int mf = 0; mf < 2; ++mf)
      #pragma unroll
      for (int nf = 0; nf < 5; ++nf)
        acc[mf][nf] = __builtin_amdgcn_mfma_f32_16x16x32_bf16(af[mf], bf[nf], acc[mf][nf], 0, 0, 0);
  }
  __syncthreads();
  float (*Pl)[84] = (float (*)[84])smem;
  #pragma unroll
  for (int mf = 0; mf < 2; ++mf)
    #pragma unroll
    for (int nf = 0; nf < 5; ++nf)
      #pragma unroll
      for (int r = 0; r < 4; ++r)
        Pl[w*32 + mf*16 + kq*4 + r][nf*16 + rl] = acc[mf][nf][r];
  __syncthreads();
  for (int idx = tid; idx < 128*FO_; idx += 256) {
    int row = idx / FO_, g = idx - row*FO_;
    int n = m0 + row;
    if (n < N_) {
      const float* p = Pl[row];
      float4 sc = *(const float4*)&scal[n*4];
      h[(size_t)n*(T_*FO_) + t*FO_ + g] =
        p[g] + sc.y*p[20+g] + sc.z*p[40+g] + sc.w*p[60+g] + qb[t*FO_+g];
    }
  }
}

// ---------------- batch norm apply (+bf16 copy with stride 104) ----------------
__global__ void k_bnapply(const float* __restrict__ h2, const float* __restrict__ bnsum,
                          const float* __restrict__ gam, const float* __restrict__ bet,
                          float* __restrict__ out, unsigned short* __restrict__ outb) {
  size_t i = (size_t)blockIdx.x * blockDim.x + threadIdx.x;
  if (i >= (size_t)N_*H_) return;
  int c = (int)(i % H_);
  int n = (int)(i / H_);
  const float invn = 1.0f / (float)N_;
  float mu  = bnsum[c] * invn;
  float var = bnsum[H_ + c] * invn - mu*mu;
  float y = (h2[i] - mu) * rsqrtf(var + EPSF) * gam[c] + bet[c];
  y = fmaxf(y, 0.f);
  out[i] = y;
  outb[(size_t)n*104 + c] = f2bf(y);
}

// ---------------- pooling (fused gcnt) + MLP ----------------
__global__ __launch_bounds__(256) void k_pool(const float* __restrict__ xc, const int* __restrict__ batch,
                                              float* __restrict__ gsum, int* __restrict__ gcnt) {
  __shared__ float Pl[B_][H_];
  __shared__ int cl[B_];
  const int tid = threadIdx.x;
  for (int i = tid; i < B_*H_; i += 256) Pl[i / H_][i % H_] = 0.f;
  for (int i = tid; i < B_; i += 256) cl[i] = 0;
  __syncthreads();
  const int r0 = blockIdx.x * PR_;
  const int rend = (r0 + PR_ < N_) ? r0 + PR_ : N_;
  for (int rr = tid; rr < rend - r0; rr += 256) atomicAdd(&cl[batch[r0 + rr]], 1);
  const int nel = (rend - r0) * H_;
  for (int idx = tid; idx < nel; idx += 256) {
    int rr = idx / H_, c = idx - rr*H_;
    int n = r0 + rr;
    atomicAdd(&Pl[batch[n]][c], xc[(size_t)n*H_ + c]);
  }
  __syncthreads();
  const int blo = batch[r0], bhi = batch[rend-1];
  const int nb = (bhi - blo + 1) * H_;
  for (int idx = tid; idx < nb; idx += 256) {
    int b = blo + idx / H_, c = idx % H_;
    atomicAdd(&gsum[(size_t)b*H_ + c], Pl[b][c]);
  }
  for (int b = blo + tid; b <= bhi; b += 256) atomicAdd(&gcnt[b], cl[b]);
}

__global__ __launch_bounds__(512) void k_mlp(
    const float* __restrict__ gsum, const int* __restrict__ gcnt,
    const float* __restrict__ w1, const float* __restrict__ b1,
    const float* __restrict__ w2, const float* __restrict__ b2,
    const float* __restrict__ w3, const float* __restrict__ b3,
    float* __restrict__ out)
{
  __shared__ float G[B_][H_];
  __shared__ float A1[B_][50];
  __shared__ float A2[B_][25];
  const int tid = threadIdx.x;
  for (int i = tid; i < B_*H_; i += 512) {
    int r = i / H_;
    G[r][i - r*H_] = gsum[i] / fmaxf((float)gcnt[r], 1.0f);
  }
  __syncthreads();
  for (int i = tid; i < B_*50; i += 512) {
    int r = i / 50, c = i - r*50;
    float a = b1[c];
    for (int k = 0; k < H_; ++k) a = fmaf(G[r][k], w1[k*50 + c], a);
    A1[r][c] = fmaxf(a, 0.f);
  }
  __syncthreads();
  for (int i = tid; i < B_*25; i += 512) {
    int r = i / 25, c = i - r*25;
    float a = b2[c];
    for (int k = 0; k < 50; ++k) a = fmaf(A1[r][k], w2[k*25 + c], a);
    A2[r][c] = fmaxf(a, 0.f);
  }
  __syncthreads();
  for (int i = tid; i < B_; i += 512) {
    float a = b3[0];
    for (int k = 0; k < 25; ++k) a = fmaf(A2[i][k], w3[k], a);
    out[i] = a;   // float32 output — reference output dtype is f32
  }
}

// ---------------- host ----------------
extern "C" void kernel_launch(void* const* d_in, const int* in_sizes, int n_in,
                              void* d_out, int out_size, void* d_ws, size_t ws_size,
                              hipStream_t stream)
{
  (void)in_sizes; (void)n_in; (void)out_size;
  const float* x0   = (const float*)d_in[0];
  const int*   eidx = (const int*)  d_in[1];
  const float* ea   = (const float*)d_in[2];
  const int*   batch= (const int*)  d_in[3];
  const float* e0w  = (const float*)d_in[4];
  const float* e0b  = (const float*)d_in[5];
  const float* p0w  = (const float*)d_in[6];
  const float* p0b  = (const float*)d_in[7];
  const float* q0w  = (const float*)d_in[8];
  const float* q0b  = (const float*)d_in[9];
  const float* l0w  = (const float*)d_in[10];
  const float* l0b  = (const float*)d_in[11];
  const float* g0   = (const float*)d_in[12];
  const float* b0   = (const float*)d_in[13];
  const float* eLw  = (const float*)d_in[14];
  const float* eLb  = (const float*)d_in[15];
  const float* pLw  = (const float*)d_in[16];
  const float* pLb  = (const float*)d_in[17];
  const float* qLw  = (const float*)d_in[18];
  const float* qLb  = (const float*)d_in[19];
  const float* lLw  = (const float*)d_in[20];
  const float* lLb  = (const float*)d_in[21];
  const float* gL   = (const float*)d_in[22];
  const float* bL   = (const float*)d_in[23];
  const float* w1   = (const float*)d_in[24];
  const float* b1   = (const float*)d_in[25];
  const float* w2   = (const float*)d_in[26];
  const float* b2   = (const float*)d_in[27];
  const float* w3   = (const float*)d_in[28];
  const float* b3   = (const float*)d_in[29];

  const int* src = eidx;
  const int* dst = eidx + E_;

  char* w = (char*)d_ws;
  size_t off = 0;
  auto take = [&](size_t bytes) -> void* {
    void* p = (void*)(w + off);
    off = (off + bytes + 255) & ~(size_t)255;
    return p;
  };
  int*   cnt    = (int*)  take((size_t)N_*4);
  int*   rowptr = (int*)  take((size_t)(N_+1)*4);
  int*   cursor = (int*)  take((size_t)N_*4);
  int*   srcs   = (int*)  take((size_t)E_*4);
  float* eav    = (float*)take((size_t)E_*4);
  float* scal   = (float*)take((size_t)N_*16);
  float* sumlog = (float*)take(256);
  float* bnsum3 = (float*)take((size_t)3*256*4);
  float* vec_e3 = (float*)take((size_t)3*512*4);
  float* cst_e3 = (float*)take((size_t)3*512*4);
  unsigned short* BpreT3 = (unsigned short*)take((size_t)3*131072*2);
  unsigned short* W23    = (unsigned short*)take((size_t)3*204800*2);
  unsigned short* LwT3   = (unsigned short*)take((size_t)3*16384*2);
  unsigned short* x0b    = (unsigned short*)take((size_t)N_*FI_*2);
  unsigned short* xcurb  = (unsigned short*)take((size_t)N_*104*2);    // bf16 activ, stride 104
  unsigned short* XIb    = (unsigned short*)take((size_t)N_*T_*H_*2);
  unsigned short* XJb    = (unsigned short*)take((size_t)N_*T_*H_*2);
  unsigned short* Apost  = (unsigned short*)take((size_t)N_*T_*512*2);
  float* hbuf   = (float*)take((size_t)N_*H_*4);
  float* h2buf  = (float*)take((size_t)N_*H_*4);
  float* xcur   = (float*)take((size_t)N_*H_*4);
  float* gsum   = (float*)take((size_t)B_*H_*4);
  int*   gcnt   = (int*)  take((size_t)B_*4);
  if (off > ws_size) return;   // workspace too small: bail (test fails loudly)

  hipMemsetAsync(cnt,    0, (size_t)N_*4, stream);
  hipMemsetAsync(cursor, 0, (size_t)N_*4, stream);
  hipMemsetAsync(sumlog, 0, 4, stream);
  hipMemsetAsync(bnsum3, 0, (size_t)3*256*4, stream);
  hipMemsetAsync(xcurb,  0, (size_t)N_*104*2, stream);   // pad cols stay zero
  hipMemsetAsync(gsum,   0, (size_t)B_*H_*4, stream);
  hipMemsetAsync(gcnt,   0, (size_t)B_*4, stream);

  // batched weight prep + x0 conversion (independent of graph)
  k_edgevec3 <<<dim3(2, 3),   dim3(256), 0, stream>>>(p0w, pLw, p0b, pLb, e0w, eLw, e0b, eLb, vec_e3, cst_e3);
  k_pack_preT3<<<dim3(512, 3), dim3(256), 0, stream>>>(p0w, pLw, BpreT3);
  k_pack_w23 <<<dim3(800, 3), dim3(256), 0, stream>>>(q0w, qLw, W23);
  k_pack_lin3<<<dim3(64, 3),  dim3(256), 0, stream>>>(l0w, lLw, LwT3);
  k_cvtx     <<<dim3((N_*FI_/2+255)/256), dim3(256), 0, stream>>>(x0, (unsigned int*)x0b);

  k_count <<<dim3((E_+255)/256), dim3(256), 0, stream>>>(dst, cnt);
  k_scan  <<<dim3(1),            dim3(1024),0, stream>>>(cnt, rowptr);
  k_fill  <<<dim3((E_+255)/256), dim3(256), 0, stream>>>(src, dst, ea, rowptr, cursor, srcs, eav);
  k_sumlog<<<dim3((N_+255)/256), dim3(256), 0, stream>>>(cnt, sumlog);
  k_scal  <<<dim3((N_+255)/256), dim3(256), 0, stream>>>(cnt, sumlog, scal);

  auto layer = [&](int l, const unsigned short* xb, int f, int KA,
                   const float* qb, const float* lb, const float* bg, const float* bb) {
    const int C   = T_ * f;
    const int KP  = ((5*f + 31) / 32) * 32;
    const int KPk = ((f + 31) / 32) * 32;
    const int gN  = (2*C + 127) / 128;
    const float* vec_e = vec_e3 + l*512;
    const float* cst_e = cst_e3 + l*512;
    const unsigned short* BpreT = BpreT3 + (size_t)l*131072;
    const unsigned short* W2    = W23    + (size_t)l*204800;
    const unsigned short* LwT   = LwT3   + (size_t)l*16384;
    float* bnsum = bnsum3 + l*256;
    k_mmsplit<<<dim3((N_+127)/128, gN), dim3(256), 0, stream>>>(xb, BpreT, XIb, XJb, N_, KA, KPk, C);
    if (f == FI_)
      k_agg<64><<<dim3(N_), dim3(64), 0, stream>>>(XIb, XJb, rowptr, srcs, eav, vec_e, cst_e, xb, Apost, f, C, KP, KA);
    else
      k_agg<256><<<dim3(N_), dim3(256), 0, stream>>>(XIb, XJb, rowptr, srcs, eav, vec_e, cst_e, xb, Apost, f, C, KP, KA);
    k_postmm<<<dim3((N_+127)/128, T_), dim3(256), 0, stream>>>(Apost, W2, scal, qb, hbuf, KP);
    k_linbn<<<dim3((N_+63)/64), dim3(256), 0, stream>>>(hbuf, LwT, lb, h2buf, bnsum, N_);
    k_bnapply<<<dim3((unsigned)(((size_t)N_*H_+255)/256)), dim3(256), 0, stream>>>(h2buf, bnsum, bg, bb, xcur, xcurb);
  };

  layer(0, x0b,   FI_, 16,  q0b, l0b, g0, b0);
  layer(1, xcurb, H_,  104, qLb, lLb, gL, bL);
  layer(2, xcurb, H_,  104, qLb + T_*FO_, lLb + H_, gL + H_, bL + H_);

  k_pool<<<dim3((N_+PR_-1)/PR_), dim3(256), 0, stream>>>(xcur, batch, gsum, gcnt);
  k_mlp <<<dim3(1), dim3(512), 0, stream>>>(gsum, gcnt, w1, b1, w2, b2, w3, b3, (float*)d_out);
}